// Round 1
// baseline (1724.862 us; speedup 1.0000x reference)
//
#include <hip/hip_runtime.h>
#include <cstdint>
#include <cstddef>

#define B_ 32
#define T_ 1024
#define S_ 512
#define C_ 384
#define NEG_INF (-1000000000.0f)
#define HALF_LOG_2PI 0.91893853320467274178f

// ---------------------------------------------------------------------------
// logaddexp matching jnp.logaddexp for finite "NEG_INF" sentinels.
__device__ __forceinline__ float logaddexp_f(float a, float b) {
    float mx = fmaxf(a, b);
    float mn = fminf(a, b);
    return mx + log1pf(expf(mn - mx));
}

// ---------------------------------------------------------------------------
// K1: Wr_raw[b,t,s] = sum_c eps[b,t,c] * cond[b,s,c]
// f32 vector-ALU GEMM (no fp32 MFMA on CDNA4). 128x128 tile, 256 threads,
// each thread computes 8x8. K-chunk = 8, LDS staged k-major.
__global__ __launch_bounds__(256) void k_gemm(const float* __restrict__ eps,
                                              const float* __restrict__ cond,
                                              float* __restrict__ Wr) {
    __shared__ float As[8][128];
    __shared__ float Bs[8][128];
    const int b  = blockIdx.z;
    const int m0 = blockIdx.y * 128;
    const int n0 = blockIdx.x * 128;
    const int tid = threadIdx.x;
    const float* A  = eps  + (size_t)b * T_ * C_;
    const float* Bm = cond + (size_t)b * S_ * C_;

    const int lr = tid >> 1;        // 0..127 row in tile
    const int lc = (tid & 1) * 4;   // 0 or 4 (k sub-chunk)
    const int ty = tid >> 4;        // 0..15 (m dir)
    const int tx = tid & 15;        // 0..15 (n dir)

    float acc[8][8];
#pragma unroll
    for (int i = 0; i < 8; ++i)
#pragma unroll
        for (int j = 0; j < 8; ++j) acc[i][j] = 0.f;

    for (int k0 = 0; k0 < C_; k0 += 8) {
        float4 av = *(const float4*)(A  + (size_t)(m0 + lr) * C_ + k0 + lc);
        float4 bv = *(const float4*)(Bm + (size_t)(n0 + lr) * C_ + k0 + lc);
        __syncthreads();   // protect previous iteration's LDS reads
        As[lc + 0][lr] = av.x; As[lc + 1][lr] = av.y;
        As[lc + 2][lr] = av.z; As[lc + 3][lr] = av.w;
        Bs[lc + 0][lr] = bv.x; Bs[lc + 1][lr] = bv.y;
        Bs[lc + 2][lr] = bv.z; Bs[lc + 3][lr] = bv.w;
        __syncthreads();
#pragma unroll
        for (int kk = 0; kk < 8; ++kk) {
            float4 a0 = *(const float4*)&As[kk][ty * 8];
            float4 a1 = *(const float4*)&As[kk][ty * 8 + 4];
            float4 b0 = *(const float4*)&Bs[kk][tx * 8];
            float4 b1 = *(const float4*)&Bs[kk][tx * 8 + 4];
            float a[8] = {a0.x, a0.y, a0.z, a0.w, a1.x, a1.y, a1.z, a1.w};
            float bb[8] = {b0.x, b0.y, b0.z, b0.w, b1.x, b1.y, b1.z, b1.w};
#pragma unroll
            for (int i = 0; i < 8; ++i)
#pragma unroll
                for (int j = 0; j < 8; ++j) acc[i][j] += a[i] * bb[j];
        }
    }
#pragma unroll
    for (int i = 0; i < 8; ++i) {
        float* dst = Wr + ((size_t)b * T_ + m0 + ty * 8 + i) * S_ + n0 + tx * 8;
        float4 o0 = make_float4(acc[i][0], acc[i][1], acc[i][2], acc[i][3]);
        float4 o1 = make_float4(acc[i][4], acc[i][5], acc[i][6], acc[i][7]);
        *(float4*)dst = o0;
        *(float4*)(dst + 4) = o1;
    }
}

// ---------------------------------------------------------------------------
// K2: per-(b,s) column stats over t: running max + sum(exp(x-max)).
__global__ __launch_bounds__(256) void k_stats(const float* __restrict__ Wr,
                                               float* __restrict__ cmax,
                                               float* __restrict__ cinv) {
    const int b = blockIdx.x >> 1;
    const int s = ((blockIdx.x & 1) << 8) + threadIdx.x;
    const float* col = Wr + (size_t)b * T_ * S_ + s;
    float m = -3.0e38f, sum = 0.f;
    for (int t = 0; t < T_; ++t) {
        float x = col[(size_t)t * S_];
        float nm = fmaxf(m, x);
        sum = sum * expf(m - nm) + expf(x - nm);
        m = nm;
    }
    cmax[b * S_ + s] = m;
    cinv[b * S_ + s] = 1.0f / sum;
}

// K3: Wr = exp(Wr - max) * inv  (softmax over T axis)
__global__ __launch_bounds__(256) void k_norm(float* __restrict__ Wr,
                                              const float* __restrict__ cmax,
                                              const float* __restrict__ cinv) {
    const size_t total4 = (size_t)B_ * T_ * S_ / 4;
    float4* W4 = (float4*)Wr;
    for (size_t i = (size_t)blockIdx.x * blockDim.x + threadIdx.x; i < total4;
         i += (size_t)gridDim.x * blockDim.x) {
        size_t base = i * 4;
        int s = (int)(base & (S_ - 1));
        int b = (int)(base >> 19);          // T_*S_ = 2^19
        float4 m4 = *(const float4*)(cmax + (size_t)b * S_ + s);
        float4 v4 = *(const float4*)(cinv + (size_t)b * S_ + s);
        float4 x = W4[i];
        x.x = expf(x.x - m4.x) * v4.x;
        x.y = expf(x.y - m4.y) * v4.y;
        x.z = expf(x.z - m4.z) * v4.z;
        x.w = expf(x.w - m4.w) * v4.w;
        W4[i] = x;
    }
}

// ---------------------------------------------------------------------------
// K4: forward (blocks 0..31) and backward (blocks 32..63) DP fused.
// One thread per j, LDS ping-pong for the j+-1 neighbor, 1 barrier / t-step.
__global__ __launch_bounds__(512) void k_dp(const float* __restrict__ Wr,
                                            float* __restrict__ mu,
                                            float* __restrict__ beta) {
    __shared__ float sh[2][S_];
    const int bid = blockIdx.x;
    const int j = threadIdx.x;
    if (bid < B_) {
        const int b = bid;
        const float* E = Wr + (size_t)b * T_ * S_;
        float* M = mu + (size_t)b * T_ * S_;
        float v = E[j] + (j == 0 ? 0.f : NEG_INF);
        M[j] = v;
        sh[0][j] = v;
        __syncthreads();
        int p = 0;
        for (int t = 1; t < T_; ++t) {
            float e = E[(size_t)t * S_ + j];
            float left = (j > 0) ? sh[p][j - 1] : NEG_INF;
            v = e + logaddexp_f(v, left);
            M[(size_t)t * S_ + j] = v;
            sh[p ^ 1][j] = v;
            __syncthreads();
            p ^= 1;
        }
    } else {
        const int b = bid - B_;
        const float* E = Wr + (size_t)b * T_ * S_;
        float* Bt = beta + (size_t)b * T_ * S_;
        float v = (j == S_ - 1) ? 0.f : NEG_INF;
        Bt[(size_t)(T_ - 1) * S_ + j] = v;
        int p = 0;
        for (int t = T_ - 2; t >= 0; --t) {
            float e = E[(size_t)(t + 1) * S_ + j];
            float mj = v + e;
            sh[p][j] = mj;
            __syncthreads();
            float mr = (j < S_ - 1) ? sh[p][j + 1] : NEG_INF;
            v = logaddexp_f(mj, mr);
            Bt[(size_t)t * S_ + j] = v;
            p ^= 1;
        }
    }
}

// ---------------------------------------------------------------------------
// K5: Viterbi forward over logpi = mu + beta - mu_N, move bits packed via
// ballot into global (L2-resident, 64B/row), then in-block backtrace by wave0.
__global__ __launch_bounds__(512) void k_vit(const float* __restrict__ mu,
                                             const float* __restrict__ beta,
                                             unsigned long long* __restrict__ mbg,
                                             int* __restrict__ js) {
    __shared__ float sh[2][S_];
    const int b = blockIdx.x;
    const int j = threadIdx.x;
    const float* M  = mu   + (size_t)b * T_ * S_;
    const float* Bt = beta + (size_t)b * T_ * S_;
    unsigned long long* mb = mbg + (size_t)b * T_ * 8;
    const float mu_N = M[(size_t)(T_ - 1) * S_ + (S_ - 1)];

    float v = (M[j] + Bt[j] - mu_N) + (j == 0 ? 0.f : NEG_INF);
    sh[0][j] = v;
    __syncthreads();
    int p = 0;
    const int wv = j >> 6, ln = j & 63;
    for (int t = 1; t < T_; ++t) {
        float lp = M[(size_t)t * S_ + j] + Bt[(size_t)t * S_ + j] - mu_N;
        float left = (j > 0) ? sh[p][j - 1] : NEG_INF;
        bool mvb = left > v;                    // "came from j-1"
        unsigned long long bal = __ballot(mvb);
        if (ln == 0) mb[(size_t)t * 8 + wv] = bal;
        v = lp + fmaxf(v, left);
        sh[p ^ 1][j] = v;
        __syncthreads();
        p ^= 1;
    }
    // Backtrace: wave 0 only. Row-word loads are j-independent (pipelineable);
    // only the shfl+bit-extract is on the sequential chain.
    if (j < 64) {
        int jj = S_ - 1;
        if (j == 0) js[b * T_ + T_ - 1] = jj;
        for (int t = T_ - 1; t > 0; --t) {
            unsigned long long w = mb[(size_t)t * 8 + (j & 7)];
            unsigned long long word = __shfl(w, jj >> 6);
            int came = (int)((word >> (jj & 63)) & 1ull);
            jj -= came;
            if (j == 0) js[b * T_ + t - 1] = jj;
        }
    }
}

// ---------------------------------------------------------------------------
// K6: one-hot path writer.
__global__ void k_path(const int* __restrict__ js, float* __restrict__ outp) {
    const size_t total4 = (size_t)B_ * T_ * S_ / 4;
    float4* O = (float4*)outp;
    for (size_t i = (size_t)blockIdx.x * blockDim.x + threadIdx.x; i < total4;
         i += (size_t)gridDim.x * blockDim.x) {
        size_t base = i * 4;
        int s = (int)(base & (S_ - 1));
        int row = (int)(base >> 9);
        int jt = js[row];
        float4 o;
        o.x = (s == jt) ? 1.f : 0.f;
        o.y = (s + 1 == jt) ? 1.f : 0.f;
        o.z = (s + 2 == jt) ? 1.f : 0.f;
        o.w = (s + 3 == jt) ? 1.f : 0.f;
        O[i] = o;
    }
}

// ---------------------------------------------------------------------------
// K7: deterministic per-(b,chunk) partial of -0.5*sum(eps^2) with t<len mask.
__global__ __launch_bounds__(256) void k_eps(const float* __restrict__ eps,
                                             const int* __restrict__ tlen,
                                             float* __restrict__ lp_part) {
    const int b = blockIdx.x / 48, chunk = blockIdx.x % 48;
    const int len = tlen[b];
    const float* base = eps + (size_t)b * T_ * C_ + (size_t)chunk * 8192;
    float acc = 0.f;
    for (int i = threadIdx.x; i < 2048; i += 256) {
        float4 v = *(const float4*)(base + i * 4);
        int t = (chunk * 8192 + i * 4) / C_;   // C_ % 4 == 0: no row straddle
        if (t < len) acc += v.x * v.x + v.y * v.y + v.z * v.z + v.w * v.w;
    }
    __shared__ float red[256];
    red[threadIdx.x] = acc;
    __syncthreads();
    for (int o = 128; o > 0; o >>= 1) {
        if (threadIdx.x < o) red[threadIdx.x] += red[threadIdx.x + o];
        __syncthreads();
    }
    if (threadIdx.x == 0) lp_part[blockIdx.x] = -0.5f * red[0];
}

// K8: logprobs[b] = sum(lp_part) - 0.5*log(2pi)*len*C + sum_t Wr[b,t,j_t] - mu_N
__global__ __launch_bounds__(256) void k_final(const float* __restrict__ Wr,
                                               const float* __restrict__ mu,
                                               const int* __restrict__ js,
                                               const float* __restrict__ lp_part,
                                               const int* __restrict__ tlen,
                                               float* __restrict__ out_lp) {
    const int b = blockIdx.x;
    float acc = 0.f;
    for (int t = threadIdx.x; t < T_; t += 256) {
        int jt = js[b * T_ + t];
        acc += Wr[((size_t)b * T_ + t) * S_ + jt];
    }
    __shared__ float red[256];
    red[threadIdx.x] = acc;
    __syncthreads();
    for (int o = 128; o > 0; o >>= 1) {
        if (threadIdx.x < o) red[threadIdx.x] += red[threadIdx.x + o];
        __syncthreads();
    }
    if (threadIdx.x == 0) {
        float basep = 0.f;
        for (int i = 0; i < 48; ++i) basep += lp_part[b * 48 + i];
        float mu_N = mu[((size_t)b * T_ + T_ - 1) * S_ + S_ - 1];
        out_lp[b] = basep - HALF_LOG_2PI * ((float)tlen[b] * C_) + red[0] - mu_N;
    }
}

// ---------------------------------------------------------------------------
extern "C" void kernel_launch(void* const* d_in, const int* in_sizes, int n_in,
                              void* d_out, int out_size, void* d_ws, size_t ws_size,
                              hipStream_t stream) {
    const float* eps  = (const float*)d_in[0];
    const float* cond = (const float*)d_in[1];
    const int* tlen   = (const int*)d_in[2];
    // d_in[3] = condition_lengths: unused by the reference.

    float* out_path = (float*)d_out;                       // B*T*S one-hot
    float* out_lp   = out_path + (size_t)B_ * T_ * S_;     // B logprobs

    const size_t NBTS = (size_t)B_ * T_ * S_;              // 16,777,216
    char* w = (char*)d_ws;
    float* Wr   = (float*)w;                               // 67.1 MB
    float* mu   = Wr + NBTS;                               // 67.1 MB
    float* beta = mu + NBTS;                               // 67.1 MB
    unsigned long long* mbg = (unsigned long long*)(beta + NBTS);   // 2 MB
    float* cmax = (float*)(mbg + (size_t)B_ * T_ * 8);     // 64 KB
    float* cinv = cmax + (size_t)B_ * S_;                  // 64 KB
    float* lp_part = cinv + (size_t)B_ * S_;               // 6 KB
    int* js = (int*)(lp_part + B_ * 48);                   // 128 KB

    k_gemm<<<dim3(S_ / 128, T_ / 128, B_), 256, 0, stream>>>(eps, cond, Wr);
    k_stats<<<B_ * 2, 256, 0, stream>>>(Wr, cmax, cinv);
    k_norm<<<4096, 256, 0, stream>>>(Wr, cmax, cinv);
    k_dp<<<2 * B_, 512, 0, stream>>>(Wr, mu, beta);
    k_vit<<<B_, 512, 0, stream>>>(mu, beta, mbg, js);
    k_path<<<4096, 256, 0, stream>>>(js, out_path);
    k_eps<<<B_ * 48, 256, 0, stream>>>(eps, tlen, lp_part);
    k_final<<<B_, 256, 0, stream>>>(Wr, mu, js, lp_part, tlen, out_lp);
}

// Round 2
// 895.505 us; speedup vs baseline: 1.9261x; 1.9261x over previous
//
#include <hip/hip_runtime.h>
#include <cstdint>
#include <cstddef>

#define B_ 32
#define T_ 1024
#define S_ 512
#define C_ 384
#define NEG_INF (-1000000000.0f)
#define HALF_LOG_2PI 0.91893853320467274178f
#define LN2F 0.69314718055994530942f
#define INV_LN2F 1.44269504088896340736f

// log2-domain logaddexp: log2(2^a + 2^b), using raw HW v_exp_f32 / v_log_f32.
__device__ __forceinline__ float lae2(float a, float b) {
    float mx = fmaxf(a, b);
    float d  = fminf(a, b) - mx;          // <= 0
    return mx + __builtin_amdgcn_logf(1.0f + __builtin_amdgcn_exp2f(d));
}

// ---------------------------------------------------------------------------
// K1: Wr_raw[b,t,s] = sum_c eps[b,t,c] * cond[b,s,c]  (f32 vector GEMM)
__global__ __launch_bounds__(256) void k_gemm(const float* __restrict__ eps,
                                              const float* __restrict__ cond,
                                              float* __restrict__ Wr) {
    __shared__ float As[8][128];
    __shared__ float Bs[8][128];
    const int b  = blockIdx.z;
    const int m0 = blockIdx.y * 128;
    const int n0 = blockIdx.x * 128;
    const int tid = threadIdx.x;
    const float* A  = eps  + (size_t)b * T_ * C_;
    const float* Bm = cond + (size_t)b * S_ * C_;

    const int lr = tid >> 1;
    const int lc = (tid & 1) * 4;
    const int ty = tid >> 4;
    const int tx = tid & 15;

    float acc[8][8];
#pragma unroll
    for (int i = 0; i < 8; ++i)
#pragma unroll
        for (int j = 0; j < 8; ++j) acc[i][j] = 0.f;

    for (int k0 = 0; k0 < C_; k0 += 8) {
        float4 av = *(const float4*)(A  + (size_t)(m0 + lr) * C_ + k0 + lc);
        float4 bv = *(const float4*)(Bm + (size_t)(n0 + lr) * C_ + k0 + lc);
        __syncthreads();
        As[lc + 0][lr] = av.x; As[lc + 1][lr] = av.y;
        As[lc + 2][lr] = av.z; As[lc + 3][lr] = av.w;
        Bs[lc + 0][lr] = bv.x; Bs[lc + 1][lr] = bv.y;
        Bs[lc + 2][lr] = bv.z; Bs[lc + 3][lr] = bv.w;
        __syncthreads();
#pragma unroll
        for (int kk = 0; kk < 8; ++kk) {
            float4 a0 = *(const float4*)&As[kk][ty * 8];
            float4 a1 = *(const float4*)&As[kk][ty * 8 + 4];
            float4 b0 = *(const float4*)&Bs[kk][tx * 8];
            float4 b1 = *(const float4*)&Bs[kk][tx * 8 + 4];
            float a[8] = {a0.x, a0.y, a0.z, a0.w, a1.x, a1.y, a1.z, a1.w};
            float bb[8] = {b0.x, b0.y, b0.z, b0.w, b1.x, b1.y, b1.z, b1.w};
#pragma unroll
            for (int i = 0; i < 8; ++i)
#pragma unroll
                for (int j = 0; j < 8; ++j) acc[i][j] += a[i] * bb[j];
        }
    }
#pragma unroll
    for (int i = 0; i < 8; ++i) {
        float* dst = Wr + ((size_t)b * T_ + m0 + ty * 8 + i) * S_ + n0 + tx * 8;
        *(float4*)dst = make_float4(acc[i][0], acc[i][1], acc[i][2], acc[i][3]);
        *(float4*)(dst + 4) = make_float4(acc[i][4], acc[i][5], acc[i][6], acc[i][7]);
    }
}

// ---------------------------------------------------------------------------
// K2: per-(b,s) column stats over t.
__global__ __launch_bounds__(256) void k_stats(const float* __restrict__ Wr,
                                               float* __restrict__ cmax,
                                               float* __restrict__ cinv) {
    const int b = blockIdx.x >> 1;
    const int s = ((blockIdx.x & 1) << 8) + threadIdx.x;
    const float* col = Wr + (size_t)b * T_ * S_ + s;
    float m = -3.0e38f, sum = 0.f;
    for (int t = 0; t < T_; ++t) {
        float x = col[(size_t)t * S_];
        float nm = fmaxf(m, x);
        sum = sum * expf(m - nm) + expf(x - nm);
        m = nm;
    }
    cmax[b * S_ + s] = m;
    cinv[b * S_ + s] = 1.0f / sum;
}

// K3: E2 = softmax(Wr, axis=T) / ln2  (log2-domain E)
__global__ __launch_bounds__(256) void k_norm(float* __restrict__ Wr,
                                              const float* __restrict__ cmax,
                                              const float* __restrict__ cinv) {
    const size_t total4 = (size_t)B_ * T_ * S_ / 4;
    float4* W4 = (float4*)Wr;
    for (size_t i = (size_t)blockIdx.x * blockDim.x + threadIdx.x; i < total4;
         i += (size_t)gridDim.x * blockDim.x) {
        size_t base = i * 4;
        int s = (int)(base & (S_ - 1));
        int b = (int)(base >> 19);
        float4 m4 = *(const float4*)(cmax + (size_t)b * S_ + s);
        float4 v4 = *(const float4*)(cinv + (size_t)b * S_ + s);
        float4 x = W4[i];
        x.x = expf(x.x - m4.x) * v4.x * INV_LN2F;
        x.y = expf(x.y - m4.y) * v4.y * INV_LN2F;
        x.z = expf(x.z - m4.z) * v4.z * INV_LN2F;
        x.w = expf(x.w - m4.w) * v4.w * INV_LN2F;
        W4[i] = x;
    }
}

// ---------------------------------------------------------------------------
// K4: one wave per (batch, direction). 8 cols/lane in registers, shfl for the
// lane-boundary neighbor, 4-deep register prefetch ring on E rows.
#define FSTEP(tt, BA, BB) do {                                                  \
    float e0=BA.x,e1=BA.y,e2=BA.z,e3=BA.w,e4=BB.x,e5=BB.y,e6=BB.z,e7=BB.w;      \
    if ((tt) + 4 < T_) {                                                        \
        BA = *(const float4*)(ep + (size_t)((tt)+4)*S_);                        \
        BB = *(const float4*)(ep + (size_t)((tt)+4)*S_ + 4);                    \
    }                                                                           \
    float lf = __shfl_up(m7, 1); if (l == 0) lf = NEG_INF;                      \
    float n0 = e0 + lae2(m0, lf);                                               \
    float n1 = e1 + lae2(m1, m0);                                               \
    float n2 = e2 + lae2(m2, m1);                                               \
    float n3 = e3 + lae2(m3, m2);                                               \
    float n4 = e4 + lae2(m4, m3);                                               \
    float n5 = e5 + lae2(m5, m4);                                               \
    float n6 = e6 + lae2(m6, m5);                                               \
    float n7 = e7 + lae2(m7, m6);                                               \
    *(float4*)(mp + (size_t)(tt)*S_)     = make_float4(n0,n1,n2,n3);            \
    *(float4*)(mp + (size_t)(tt)*S_ + 4) = make_float4(n4,n5,n6,n7);            \
    m0=n0;m1=n1;m2=n2;m3=n3;m4=n4;m5=n5;m6=n6;m7=n7;                            \
} while (0)

#define BSTEP(tt, BA, BB) do {                                                  \
    float e0=BA.x,e1=BA.y,e2=BA.z,e3=BA.w,e4=BB.x,e5=BB.y,e6=BB.z,e7=BB.w;      \
    if ((tt) >= 4) {                                                            \
        BA = *(const float4*)(ep + (size_t)((tt)-3)*S_);                        \
        BB = *(const float4*)(ep + (size_t)((tt)-3)*S_ + 4);                    \
    }                                                                           \
    float mj0=m0+e0, mj1=m1+e1, mj2=m2+e2, mj3=m3+e3;                           \
    float mj4=m4+e4, mj5=m5+e5, mj6=m6+e6, mj7=m7+e7;                           \
    float rt = __shfl_down(mj0, 1); if (l == 63) rt = NEG_INF;                  \
    float n0 = lae2(mj0, mj1);                                                  \
    float n1 = lae2(mj1, mj2);                                                  \
    float n2 = lae2(mj2, mj3);                                                  \
    float n3 = lae2(mj3, mj4);                                                  \
    float n4 = lae2(mj4, mj5);                                                  \
    float n5 = lae2(mj5, mj6);                                                  \
    float n6 = lae2(mj6, mj7);                                                  \
    float n7 = lae2(mj7, rt);                                                   \
    *(float4*)(bp + (size_t)(tt)*S_)     = make_float4(n0,n1,n2,n3);            \
    *(float4*)(bp + (size_t)(tt)*S_ + 4) = make_float4(n4,n5,n6,n7);            \
    m0=n0;m1=n1;m2=n2;m3=n3;m4=n4;m5=n5;m6=n6;m7=n7;                            \
} while (0)

__global__ __launch_bounds__(64) void k_dp2(const float* __restrict__ E2,
                                            float* __restrict__ mu,
                                            float* __restrict__ beta) {
    const int bid = blockIdx.x;
    const int l = threadIdx.x;
    float m0,m1,m2,m3,m4,m5,m6,m7;
    float4 p0a,p0b,p1a,p1b,p2a,p2b,p3a,p3b;

    if (bid < B_) {
        const float* ep = E2 + (size_t)bid * T_ * S_ + l * 8;
        float* mp = mu + (size_t)bid * T_ * S_ + l * 8;
        float4 a = *(const float4*)(ep);
        float4 bq = *(const float4*)(ep + 4);
        m0 = a.x + (l == 0 ? 0.f : NEG_INF);
        m1 = a.y + NEG_INF; m2 = a.z + NEG_INF; m3 = a.w + NEG_INF;
        m4 = bq.x + NEG_INF; m5 = bq.y + NEG_INF; m6 = bq.z + NEG_INF; m7 = bq.w + NEG_INF;
        *(float4*)(mp)     = make_float4(m0,m1,m2,m3);
        *(float4*)(mp + 4) = make_float4(m4,m5,m6,m7);
        p1a = *(const float4*)(ep + (size_t)1*S_); p1b = *(const float4*)(ep + (size_t)1*S_ + 4);
        p2a = *(const float4*)(ep + (size_t)2*S_); p2b = *(const float4*)(ep + (size_t)2*S_ + 4);
        p3a = *(const float4*)(ep + (size_t)3*S_); p3b = *(const float4*)(ep + (size_t)3*S_ + 4);
        p0a = *(const float4*)(ep + (size_t)4*S_); p0b = *(const float4*)(ep + (size_t)4*S_ + 4);
        int t = 1;
        for (; t + 3 < T_; t += 4) {
            FSTEP(t,     p1a, p1b);
            FSTEP(t + 1, p2a, p2b);
            FSTEP(t + 2, p3a, p3b);
            FSTEP(t + 3, p0a, p0b);
        }
        FSTEP(1021, p1a, p1b);
        FSTEP(1022, p2a, p2b);
        FSTEP(1023, p3a, p3b);
    } else {
        const int b = bid - B_;
        const float* ep = E2 + (size_t)b * T_ * S_ + l * 8;
        float* bp = beta + (size_t)b * T_ * S_ + l * 8;
        m0 = NEG_INF; m1 = NEG_INF; m2 = NEG_INF; m3 = NEG_INF;
        m4 = NEG_INF; m5 = NEG_INF; m6 = NEG_INF;
        m7 = (l == 63) ? 0.f : NEG_INF;
        *(float4*)(bp + (size_t)1023*S_)     = make_float4(m0,m1,m2,m3);
        *(float4*)(bp + (size_t)1023*S_ + 4) = make_float4(m4,m5,m6,m7);
        p3a = *(const float4*)(ep + (size_t)1023*S_); p3b = *(const float4*)(ep + (size_t)1023*S_ + 4);
        p2a = *(const float4*)(ep + (size_t)1022*S_); p2b = *(const float4*)(ep + (size_t)1022*S_ + 4);
        p1a = *(const float4*)(ep + (size_t)1021*S_); p1b = *(const float4*)(ep + (size_t)1021*S_ + 4);
        p0a = *(const float4*)(ep + (size_t)1020*S_); p0b = *(const float4*)(ep + (size_t)1020*S_ + 4);
        int tt = 1022;
        for (; tt >= 6; tt -= 4) {
            BSTEP(tt,     p3a, p3b);
            BSTEP(tt - 1, p2a, p2b);
            BSTEP(tt - 2, p1a, p1b);
            BSTEP(tt - 3, p0a, p0b);
        }
        BSTEP(2, p3a, p3b);
        BSTEP(1, p2a, p2b);
        BSTEP(0, p1a, p1b);
    }
}

// ---------------------------------------------------------------------------
// K5: Viterbi. One wave per batch; move bits (512/step) packed per-lane into
// u64 per 8 steps -> 64KB LDS; pipelined shfl-select backtrace.
#define VSTEP(tt, MA, MB, BA, BB) do {                                          \
    float lp0=(MA.x-muN)+BA.x, lp1=(MA.y-muN)+BA.y;                             \
    float lp2=(MA.z-muN)+BA.z, lp3=(MA.w-muN)+BA.w;                             \
    float lp4=(MB.x-muN)+BB.x, lp5=(MB.y-muN)+BB.y;                             \
    float lp6=(MB.z-muN)+BB.z, lp7=(MB.w-muN)+BB.w;                             \
    if ((tt) + 4 < T_) {                                                        \
        MA = *(const float4*)(mp2 + (size_t)((tt)+4)*S_);                       \
        MB = *(const float4*)(mp2 + (size_t)((tt)+4)*S_ + 4);                   \
        BA = *(const float4*)(bp2 + (size_t)((tt)+4)*S_);                       \
        BB = *(const float4*)(bp2 + (size_t)((tt)+4)*S_ + 4);                   \
    }                                                                           \
    float lf = __shfl_up(v7, 1); if (l == 0) lf = NEG_INF;                      \
    unsigned int c0 = (lf > v0) ? 1u   : 0u; float w0 = lp0 + fmaxf(v0, lf);    \
    unsigned int c1 = (v0 > v1) ? 2u   : 0u; float w1 = lp1 + fmaxf(v1, v0);    \
    unsigned int c2 = (v1 > v2) ? 4u   : 0u; float w2 = lp2 + fmaxf(v2, v1);    \
    unsigned int c3 = (v2 > v3) ? 8u   : 0u; float w3 = lp3 + fmaxf(v3, v2);    \
    unsigned int c4 = (v3 > v4) ? 16u  : 0u; float w4 = lp4 + fmaxf(v4, v3);    \
    unsigned int c5 = (v4 > v5) ? 32u  : 0u; float w5 = lp5 + fmaxf(v5, v4);    \
    unsigned int c6 = (v5 > v6) ? 64u  : 0u; float w6 = lp6 + fmaxf(v6, v5);    \
    unsigned int c7 = (v6 > v7) ? 128u : 0u; float w7 = lp7 + fmaxf(v7, v6);    \
    unsigned int byte = c0|c1|c2|c3|c4|c5|c6|c7;                                \
    acc |= ((unsigned long long)byte) << (((tt) & 7) * 8);                      \
    if (((tt) & 7) == 7) { mb_lds[(tt) >> 3][l] = acc; acc = 0ULL; }            \
    v0=w0;v1=w1;v2=w2;v3=w3;v4=w4;v5=w5;v6=w6;v7=w7;                            \
} while (0)

__global__ __launch_bounds__(64) void k_vit2(const float* __restrict__ mu,
                                             const float* __restrict__ beta,
                                             int* __restrict__ js) {
    __shared__ unsigned long long mb_lds[128][64];   // 64 KB
    const int b = blockIdx.x;
    const int l = threadIdx.x;
    const float* mp2 = mu   + (size_t)b * T_ * S_ + l * 8;
    const float* bp2 = beta + (size_t)b * T_ * S_ + l * 8;
    const float muN = mu[((size_t)b * T_ + T_ - 1) * S_ + S_ - 1];

    float4 ma0,mb0,ma1,mb1,ma2,mb2,ma3,mb3;
    float4 ba0,bb0,ba1,bb1,ba2,bb2,ba3,bb3;
    float v0,v1,v2,v3,v4,v5,v6,v7;
    unsigned long long acc = 0ULL;

    {
        float4 a  = *(const float4*)(mp2);
        float4 a2 = *(const float4*)(mp2 + 4);
        float4 c  = *(const float4*)(bp2);
        float4 c2 = *(const float4*)(bp2 + 4);
        v0 = (a.x - muN) + c.x + (l == 0 ? 0.f : NEG_INF);
        v1 = (a.y - muN) + c.y + NEG_INF;
        v2 = (a.z - muN) + c.z + NEG_INF;
        v3 = (a.w - muN) + c.w + NEG_INF;
        v4 = (a2.x - muN) + c2.x + NEG_INF;
        v5 = (a2.y - muN) + c2.y + NEG_INF;
        v6 = (a2.z - muN) + c2.z + NEG_INF;
        v7 = (a2.w - muN) + c2.w + NEG_INF;
    }
    ma1 = *(const float4*)(mp2 + (size_t)1*S_); mb1 = *(const float4*)(mp2 + (size_t)1*S_ + 4);
    ba1 = *(const float4*)(bp2 + (size_t)1*S_); bb1 = *(const float4*)(bp2 + (size_t)1*S_ + 4);
    ma2 = *(const float4*)(mp2 + (size_t)2*S_); mb2 = *(const float4*)(mp2 + (size_t)2*S_ + 4);
    ba2 = *(const float4*)(bp2 + (size_t)2*S_); bb2 = *(const float4*)(bp2 + (size_t)2*S_ + 4);
    ma3 = *(const float4*)(mp2 + (size_t)3*S_); mb3 = *(const float4*)(mp2 + (size_t)3*S_ + 4);
    ba3 = *(const float4*)(bp2 + (size_t)3*S_); bb3 = *(const float4*)(bp2 + (size_t)3*S_ + 4);
    ma0 = *(const float4*)(mp2 + (size_t)4*S_); mb0 = *(const float4*)(mp2 + (size_t)4*S_ + 4);
    ba0 = *(const float4*)(bp2 + (size_t)4*S_); bb0 = *(const float4*)(bp2 + (size_t)4*S_ + 4);

    int t = 1;
    for (; t + 3 < T_; t += 4) {
        VSTEP(t,     ma1, mb1, ba1, bb1);
        VSTEP(t + 1, ma2, mb2, ba2, bb2);
        VSTEP(t + 2, ma3, mb3, ba3, bb3);
        VSTEP(t + 3, ma0, mb0, ba0, bb0);
    }
    VSTEP(1021, ma1, mb1, ba1, bb1);
    VSTEP(1022, ma2, mb2, ba2, bb2);
    VSTEP(1023, ma3, mb3, ba3, bb3);

    __syncthreads();

    // Backtrace: all lanes hold word for their column-group; shfl selects.
    int jj = S_ - 1;
    if (l == 0) js[b * T_ + T_ - 1] = jj;
    unsigned long long wcur = mb_lds[127][l];
    for (int tau = 127; tau >= 0; --tau) {
        unsigned long long w = wcur;
        if (tau > 0) wcur = mb_lds[tau - 1][l];
        for (int i = 7; i >= 0; --i) {
            int tt = tau * 8 + i;
            if (tt == 0) break;
            unsigned long long word = __shfl(w, jj >> 3);
            int bit = (int)((word >> (((unsigned)tt & 7) * 8 + (jj & 7))) & 1ULL);
            jj -= bit;
            if (l == 0) js[b * T_ + tt - 1] = jj;
        }
    }
}

// ---------------------------------------------------------------------------
// K6: one-hot path writer.
__global__ void k_path(const int* __restrict__ js, float* __restrict__ outp) {
    const size_t total4 = (size_t)B_ * T_ * S_ / 4;
    float4* O = (float4*)outp;
    for (size_t i = (size_t)blockIdx.x * blockDim.x + threadIdx.x; i < total4;
         i += (size_t)gridDim.x * blockDim.x) {
        size_t base = i * 4;
        int s = (int)(base & (S_ - 1));
        int row = (int)(base >> 9);
        int jt = js[row];
        float4 o;
        o.x = (s == jt) ? 1.f : 0.f;
        o.y = (s + 1 == jt) ? 1.f : 0.f;
        o.z = (s + 2 == jt) ? 1.f : 0.f;
        o.w = (s + 3 == jt) ? 1.f : 0.f;
        O[i] = o;
    }
}

// ---------------------------------------------------------------------------
// K7: deterministic per-(b,chunk) partial of -0.5*sum(eps^2), t<len masked.
__global__ __launch_bounds__(256) void k_eps(const float* __restrict__ eps,
                                             const int* __restrict__ tlen,
                                             float* __restrict__ lp_part) {
    const int b = blockIdx.x / 48, chunk = blockIdx.x % 48;
    const int len = tlen[b];
    const float* base = eps + (size_t)b * T_ * C_ + (size_t)chunk * 8192;
    float acc = 0.f;
    for (int i = threadIdx.x; i < 2048; i += 256) {
        float4 v = *(const float4*)(base + i * 4);
        int t = (chunk * 8192 + i * 4) / C_;
        if (t < len) acc += v.x * v.x + v.y * v.y + v.z * v.z + v.w * v.w;
    }
    __shared__ float red[256];
    red[threadIdx.x] = acc;
    __syncthreads();
    for (int o = 128; o > 0; o >>= 1) {
        if (threadIdx.x < o) red[threadIdx.x] += red[threadIdx.x + o];
        __syncthreads();
    }
    if (threadIdx.x == 0) lp_part[blockIdx.x] = -0.5f * red[0];
}

// K8: final logprobs (E2 and mu are log2-domain -> scale by ln2).
__global__ __launch_bounds__(256) void k_final(const float* __restrict__ Wr,
                                               const float* __restrict__ mu,
                                               const int* __restrict__ js,
                                               const float* __restrict__ lp_part,
                                               const int* __restrict__ tlen,
                                               float* __restrict__ out_lp) {
    const int b = blockIdx.x;
    float acc = 0.f;
    for (int t = threadIdx.x; t < T_; t += 256) {
        int jt = js[b * T_ + t];
        acc += Wr[((size_t)b * T_ + t) * S_ + jt];
    }
    __shared__ float red[256];
    red[threadIdx.x] = acc;
    __syncthreads();
    for (int o = 128; o > 0; o >>= 1) {
        if (threadIdx.x < o) red[threadIdx.x] += red[threadIdx.x + o];
        __syncthreads();
    }
    if (threadIdx.x == 0) {
        float basep = 0.f;
        for (int i = 0; i < 48; ++i) basep += lp_part[b * 48 + i];
        float mu2N = mu[((size_t)b * T_ + T_ - 1) * S_ + S_ - 1];
        out_lp[b] = basep - HALF_LOG_2PI * ((float)tlen[b] * C_)
                    + LN2F * (red[0] - mu2N);
    }
}

// ---------------------------------------------------------------------------
extern "C" void kernel_launch(void* const* d_in, const int* in_sizes, int n_in,
                              void* d_out, int out_size, void* d_ws, size_t ws_size,
                              hipStream_t stream) {
    const float* eps  = (const float*)d_in[0];
    const float* cond = (const float*)d_in[1];
    const int* tlen   = (const int*)d_in[2];

    float* out_path = (float*)d_out;
    float* out_lp   = out_path + (size_t)B_ * T_ * S_;

    const size_t NBTS = (size_t)B_ * T_ * S_;
    char* w = (char*)d_ws;
    float* Wr   = (float*)w;                 // E2 (log2-domain), 67 MB
    float* mu   = Wr + NBTS;                 // mu2, 67 MB
    float* beta = mu + NBTS;                 // beta2, 67 MB
    float* cmax = beta + NBTS;
    float* cinv = cmax + (size_t)B_ * S_;
    float* lp_part = cinv + (size_t)B_ * S_;
    int* js = (int*)(lp_part + B_ * 48);

    k_gemm<<<dim3(S_ / 128, T_ / 128, B_), 256, 0, stream>>>(eps, cond, Wr);
    k_stats<<<B_ * 2, 256, 0, stream>>>(Wr, cmax, cinv);
    k_norm<<<4096, 256, 0, stream>>>(Wr, cmax, cinv);
    k_dp2<<<2 * B_, 64, 0, stream>>>(Wr, mu, beta);
    k_vit2<<<B_, 64, 0, stream>>>(mu, beta, js);
    k_path<<<4096, 256, 0, stream>>>(js, out_path);
    k_eps<<<B_ * 48, 256, 0, stream>>>(eps, tlen, lp_part);
    k_final<<<B_, 256, 0, stream>>>(Wr, mu, js, lp_part, tlen, out_lp);
}

// Round 3
// 874.547 us; speedup vs baseline: 1.9723x; 1.0240x over previous
//
#include <hip/hip_runtime.h>
#include <cstdint>
#include <cstddef>

#define B_ 32
#define T_ 1024
#define S_ 512
#define C_ 384
#define NEG_INF (-1000000000.0f)
#define HALF_LOG_2PI 0.91893853320467274178f
#define LN2F 0.69314718055994530942f
#define INV_LN2F 1.44269504088896340736f

// log2-domain logaddexp: log2(2^a + 2^b), raw HW v_exp_f32 / v_log_f32.
__device__ __forceinline__ float lae2(float a, float b) {
    float mx = fmaxf(a, b);
    float d  = fminf(a, b) - mx;          // <= 0
    return mx + __builtin_amdgcn_logf(1.0f + __builtin_amdgcn_exp2f(d));
}

#define LD(p, r)  (*(const float4*)((p) + (size_t)(r) * S_))
#define LD4(p, r) (*(const float4*)((p) + (size_t)(r) * S_ + 4))

// ---------------------------------------------------------------------------
// K1: Wr_raw[b,t,s] = sum_c eps[b,t,c] * cond[b,s,c]  (f32 vector GEMM)
__global__ __launch_bounds__(256) void k_gemm(const float* __restrict__ eps,
                                              const float* __restrict__ cond,
                                              float* __restrict__ Wr) {
    __shared__ float As[8][128];
    __shared__ float Bs[8][128];
    const int b  = blockIdx.z;
    const int m0 = blockIdx.y * 128;
    const int n0 = blockIdx.x * 128;
    const int tid = threadIdx.x;
    const float* A  = eps  + (size_t)b * T_ * C_;
    const float* Bm = cond + (size_t)b * S_ * C_;

    const int lr = tid >> 1;
    const int lc = (tid & 1) * 4;
    const int ty = tid >> 4;
    const int tx = tid & 15;

    float acc[8][8];
#pragma unroll
    for (int i = 0; i < 8; ++i)
#pragma unroll
        for (int j = 0; j < 8; ++j) acc[i][j] = 0.f;

    for (int k0 = 0; k0 < C_; k0 += 8) {
        float4 av = *(const float4*)(A  + (size_t)(m0 + lr) * C_ + k0 + lc);
        float4 bv = *(const float4*)(Bm + (size_t)(n0 + lr) * C_ + k0 + lc);
        __syncthreads();
        As[lc + 0][lr] = av.x; As[lc + 1][lr] = av.y;
        As[lc + 2][lr] = av.z; As[lc + 3][lr] = av.w;
        Bs[lc + 0][lr] = bv.x; Bs[lc + 1][lr] = bv.y;
        Bs[lc + 2][lr] = bv.z; Bs[lc + 3][lr] = bv.w;
        __syncthreads();
#pragma unroll
        for (int kk = 0; kk < 8; ++kk) {
            float4 a0 = *(const float4*)&As[kk][ty * 8];
            float4 a1 = *(const float4*)&As[kk][ty * 8 + 4];
            float4 b0 = *(const float4*)&Bs[kk][tx * 8];
            float4 b1 = *(const float4*)&Bs[kk][tx * 8 + 4];
            float a[8] = {a0.x, a0.y, a0.z, a0.w, a1.x, a1.y, a1.z, a1.w};
            float bb[8] = {b0.x, b0.y, b0.z, b0.w, b1.x, b1.y, b1.z, b1.w};
#pragma unroll
            for (int i = 0; i < 8; ++i)
#pragma unroll
                for (int j = 0; j < 8; ++j) acc[i][j] += a[i] * bb[j];
        }
    }
#pragma unroll
    for (int i = 0; i < 8; ++i) {
        float* dst = Wr + ((size_t)b * T_ + m0 + ty * 8 + i) * S_ + n0 + tx * 8;
        *(float4*)dst = make_float4(acc[i][0], acc[i][1], acc[i][2], acc[i][3]);
        *(float4*)(dst + 4) = make_float4(acc[i][4], acc[i][5], acc[i][6], acc[i][7]);
    }
}

// ---------------------------------------------------------------------------
// K2a: per-(b,s,chunk) partial column stats over a 256-t range (4 chunks).
__global__ __launch_bounds__(256) void k_stats1(const float* __restrict__ Wr,
                                                float* __restrict__ pmax,
                                                float* __restrict__ psum) {
    const int c  = blockIdx.x & 3;          // t-chunk
    const int bh = blockIdx.x >> 2;         // 0..63: (b, s-half)
    const int b  = bh >> 1;
    const int s  = ((bh & 1) << 8) + threadIdx.x;
    const float* col = Wr + (size_t)b * T_ * S_ + (size_t)c * 256 * S_ + s;
    float m = -3.0e38f, sum = 0.f;
    for (int t = 0; t < 256; t += 4) {
        float x0 = col[(size_t)(t + 0) * S_];
        float x1 = col[(size_t)(t + 1) * S_];
        float x2 = col[(size_t)(t + 2) * S_];
        float x3 = col[(size_t)(t + 3) * S_];
        float nm = fmaxf(fmaxf(fmaxf(fmaxf(m, x0), x1), x2), x3);
        sum = sum * expf(m - nm) + expf(x0 - nm) + expf(x1 - nm)
            + expf(x2 - nm) + expf(x3 - nm);
        m = nm;
    }
    pmax[(size_t)c * B_ * S_ + b * S_ + s] = m;
    psum[(size_t)c * B_ * S_ + b * S_ + s] = sum;
}

// K2b: combine 4 chunk partials -> cmax, cinv.
__global__ __launch_bounds__(256) void k_stats2(const float* __restrict__ pmax,
                                                const float* __restrict__ psum,
                                                float* __restrict__ cmax,
                                                float* __restrict__ cinv) {
    const int i = blockIdx.x * 256 + threadIdx.x;   // 0..B*S-1
    float m0 = pmax[i], m1 = pmax[(size_t)B_ * S_ + i];
    float m2 = pmax[(size_t)2 * B_ * S_ + i], m3 = pmax[(size_t)3 * B_ * S_ + i];
    float m = fmaxf(fmaxf(m0, m1), fmaxf(m2, m3));
    float s = psum[i] * expf(m0 - m)
            + psum[(size_t)B_ * S_ + i] * expf(m1 - m)
            + psum[(size_t)2 * B_ * S_ + i] * expf(m2 - m)
            + psum[(size_t)3 * B_ * S_ + i] * expf(m3 - m);
    cmax[i] = m;
    cinv[i] = 1.0f / s;
}

// ---------------------------------------------------------------------------
// K3: backward DP only. One wave per batch, 8 cols/lane, on-the-fly softmax
// (E2 = log2-domain E), 8-deep register prefetch ring on raw Wr rows.
#define BSTEP8(r, SA, SB) do {                                                  \
    float x0=SA.x,x1=SA.y,x2=SA.z,x3=SA.w,x4=SB.x,x5=SB.y,x6=SB.z,x7=SB.w;      \
    if ((r) >= 9) { SA = LD(ep, (r)-8); SB = LD4(ep, (r)-8); }                  \
    float e0=__builtin_amdgcn_exp2f(fmaf(x0,INV_LN2F,-km0))*ki0;                \
    float e1=__builtin_amdgcn_exp2f(fmaf(x1,INV_LN2F,-km1))*ki1;                \
    float e2=__builtin_amdgcn_exp2f(fmaf(x2,INV_LN2F,-km2))*ki2;                \
    float e3=__builtin_amdgcn_exp2f(fmaf(x3,INV_LN2F,-km3))*ki3;                \
    float e4=__builtin_amdgcn_exp2f(fmaf(x4,INV_LN2F,-km4))*ki4;                \
    float e5=__builtin_amdgcn_exp2f(fmaf(x5,INV_LN2F,-km5))*ki5;                \
    float e6=__builtin_amdgcn_exp2f(fmaf(x6,INV_LN2F,-km6))*ki6;                \
    float e7=__builtin_amdgcn_exp2f(fmaf(x7,INV_LN2F,-km7))*ki7;                \
    float mj0=m0+e0, mj1=m1+e1, mj2=m2+e2, mj3=m3+e3;                           \
    float mj4=m4+e4, mj5=m5+e5, mj6=m6+e6, mj7=m7+e7;                           \
    float rt = __shfl_down(mj0, 1); if (l == 63) rt = NEG_INF;                  \
    float n0 = lae2(mj0, mj1);                                                  \
    float n1 = lae2(mj1, mj2);                                                  \
    float n2 = lae2(mj2, mj3);                                                  \
    float n3 = lae2(mj3, mj4);                                                  \
    float n4 = lae2(mj4, mj5);                                                  \
    float n5 = lae2(mj5, mj6);                                                  \
    float n6 = lae2(mj6, mj7);                                                  \
    float n7 = lae2(mj7, rt);                                                   \
    *(float4*)(bp + (size_t)((r)-1)*S_)     = make_float4(n0,n1,n2,n3);         \
    *(float4*)(bp + (size_t)((r)-1)*S_ + 4) = make_float4(n4,n5,n6,n7);         \
    m0=n0;m1=n1;m2=n2;m3=n3;m4=n4;m5=n5;m6=n6;m7=n7;                            \
} while (0)

__global__ __launch_bounds__(64) void k_beta(const float* __restrict__ Wr,
                                             const float* __restrict__ cmax,
                                             const float* __restrict__ cinv,
                                             float* __restrict__ beta) {
    const int b = blockIdx.x;
    const int l = threadIdx.x;
    const float* ep = Wr + (size_t)b * T_ * S_ + l * 8;
    float* bp = beta + (size_t)b * T_ * S_ + l * 8;
    const float4 cA = *(const float4*)(cmax + b * S_ + l * 8);
    const float4 cB = *(const float4*)(cmax + b * S_ + l * 8 + 4);
    const float4 iA = *(const float4*)(cinv + b * S_ + l * 8);
    const float4 iB = *(const float4*)(cinv + b * S_ + l * 8 + 4);
    const float km0=cA.x*INV_LN2F, km1=cA.y*INV_LN2F, km2=cA.z*INV_LN2F, km3=cA.w*INV_LN2F;
    const float km4=cB.x*INV_LN2F, km5=cB.y*INV_LN2F, km6=cB.z*INV_LN2F, km7=cB.w*INV_LN2F;
    const float ki0=iA.x*INV_LN2F, ki1=iA.y*INV_LN2F, ki2=iA.z*INV_LN2F, ki3=iA.w*INV_LN2F;
    const float ki4=iB.x*INV_LN2F, ki5=iB.y*INV_LN2F, ki6=iB.z*INV_LN2F, ki7=iB.w*INV_LN2F;

    float m0=NEG_INF,m1=NEG_INF,m2=NEG_INF,m3=NEG_INF,m4=NEG_INF,m5=NEG_INF,m6=NEG_INF;
    float m7 = (l == 63) ? 0.f : NEG_INF;
    *(float4*)(bp + (size_t)1023*S_)     = make_float4(m0,m1,m2,m3);
    *(float4*)(bp + (size_t)1023*S_ + 4) = make_float4(m4,m5,m6,m7);

    float4 sA7=LD(ep,1023), sB7=LD4(ep,1023);
    float4 sA6=LD(ep,1022), sB6=LD4(ep,1022);
    float4 sA5=LD(ep,1021), sB5=LD4(ep,1021);
    float4 sA4=LD(ep,1020), sB4=LD4(ep,1020);
    float4 sA3=LD(ep,1019), sB3=LD4(ep,1019);
    float4 sA2=LD(ep,1018), sB2=LD4(ep,1018);
    float4 sA1=LD(ep,1017), sB1=LD4(ep,1017);
    float4 sA0=LD(ep,1016), sB0=LD4(ep,1016);

    for (int r = 1023; r >= 15; r -= 8) {
        BSTEP8(r,     sA7, sB7);
        BSTEP8(r - 1, sA6, sB6);
        BSTEP8(r - 2, sA5, sB5);
        BSTEP8(r - 3, sA4, sB4);
        BSTEP8(r - 4, sA3, sB3);
        BSTEP8(r - 5, sA2, sB2);
        BSTEP8(r - 6, sA1, sB1);
        BSTEP8(r - 7, sA0, sB0);
    }
    BSTEP8(7, sA7, sB7);
    BSTEP8(6, sA6, sB6);
    BSTEP8(5, sA5, sB5);
    BSTEP8(4, sA4, sB4);
    BSTEP8(3, sA3, sB3);
    BSTEP8(2, sA2, sB2);
    BSTEP8(1, sA1, sB1);
}

// ---------------------------------------------------------------------------
// K4: forward mu-DP fused with Viterbi. mu never stored: lp = mu+beta-muN with
// muN = mu[0,0]+beta[0,0] (constant-shift leaves decisions invariant). Move
// bits packed per-lane into u64 per 8 steps -> 64KB LDS; in-kernel backtrace.
#define FVSTEP(tt, EA, EB, QA, QB) do {                                         \
    float x0=EA.x,x1=EA.y,x2=EA.z,x3=EA.w,x4=EB.x,x5=EB.y,x6=EB.z,x7=EB.w;      \
    float q0=QA.x,q1=QA.y,q2=QA.z,q3=QA.w,q4=QB.x,q5=QB.y,q6=QB.z,q7=QB.w;      \
    if ((tt) + 8 < T_) {                                                        \
        EA = LD(ep, (tt)+8); EB = LD4(ep, (tt)+8);                              \
        QA = LD(tp, (tt)+8); QB = LD4(tp, (tt)+8);                              \
    }                                                                           \
    float e0=__builtin_amdgcn_exp2f(fmaf(x0,INV_LN2F,-km0))*ki0;                \
    float e1=__builtin_amdgcn_exp2f(fmaf(x1,INV_LN2F,-km1))*ki1;                \
    float e2=__builtin_amdgcn_exp2f(fmaf(x2,INV_LN2F,-km2))*ki2;                \
    float e3=__builtin_amdgcn_exp2f(fmaf(x3,INV_LN2F,-km3))*ki3;                \
    float e4=__builtin_amdgcn_exp2f(fmaf(x4,INV_LN2F,-km4))*ki4;                \
    float e5=__builtin_amdgcn_exp2f(fmaf(x5,INV_LN2F,-km5))*ki5;                \
    float e6=__builtin_amdgcn_exp2f(fmaf(x6,INV_LN2F,-km6))*ki6;                \
    float e7=__builtin_amdgcn_exp2f(fmaf(x7,INV_LN2F,-km7))*ki7;                \
    float lf = __shfl_up(m7, 1); if (l == 0) lf = NEG_INF;                      \
    float n0 = e0 + lae2(m0, lf);                                               \
    float n1 = e1 + lae2(m1, m0);                                               \
    float n2 = e2 + lae2(m2, m1);                                               \
    float n3 = e3 + lae2(m3, m2);                                               \
    float n4 = e4 + lae2(m4, m3);                                               \
    float n5 = e5 + lae2(m5, m4);                                               \
    float n6 = e6 + lae2(m6, m5);                                               \
    float n7 = e7 + lae2(m7, m6);                                               \
    float lp0=(n0-muN)+q0, lp1=(n1-muN)+q1, lp2=(n2-muN)+q2, lp3=(n3-muN)+q3;   \
    float lp4=(n4-muN)+q4, lp5=(n5-muN)+q5, lp6=(n6-muN)+q6, lp7=(n7-muN)+q7;   \
    float vlf = __shfl_up(v7, 1); if (l == 0) vlf = NEG_INF;                    \
    unsigned int c0=(vlf>v0)?1u:0u;   float w0=lp0+fmaxf(v0,vlf);               \
    unsigned int c1=(v0>v1)?2u:0u;    float w1=lp1+fmaxf(v1,v0);                \
    unsigned int c2=(v1>v2)?4u:0u;    float w2=lp2+fmaxf(v2,v1);                \
    unsigned int c3=(v2>v3)?8u:0u;    float w3=lp3+fmaxf(v3,v2);                \
    unsigned int c4=(v3>v4)?16u:0u;   float w4=lp4+fmaxf(v4,v3);                \
    unsigned int c5=(v4>v5)?32u:0u;   float w5=lp5+fmaxf(v5,v4);                \
    unsigned int c6=(v5>v6)?64u:0u;   float w6=lp6+fmaxf(v6,v5);                \
    unsigned int c7=(v6>v7)?128u:0u;  float w7=lp7+fmaxf(v7,v6);                \
    unsigned int byte = c0|c1|c2|c3|c4|c5|c6|c7;                                \
    acc |= ((unsigned long long)byte) << (((tt) & 7) * 8);                      \
    if (((tt) & 7) == 7) { mb_lds[(tt) >> 3][l] = acc; acc = 0ULL; }            \
    m0=n0;m1=n1;m2=n2;m3=n3;m4=n4;m5=n5;m6=n6;m7=n7;                            \
    v0=w0;v1=w1;v2=w2;v3=w3;v4=w4;v5=w5;v6=w6;v7=w7;                            \
} while (0)

__global__ __launch_bounds__(64) void k_muvit(const float* __restrict__ Wr,
                                              const float* __restrict__ beta,
                                              const float* __restrict__ cmax,
                                              const float* __restrict__ cinv,
                                              int* __restrict__ js,
                                              float* __restrict__ muN_out) {
    __shared__ unsigned long long mb_lds[128][64];   // 64 KB
    const int b = blockIdx.x;
    const int l = threadIdx.x;
    const float* ep = Wr   + (size_t)b * T_ * S_ + l * 8;
    const float* tp = beta + (size_t)b * T_ * S_ + l * 8;
    const float4 cA = *(const float4*)(cmax + b * S_ + l * 8);
    const float4 cB = *(const float4*)(cmax + b * S_ + l * 8 + 4);
    const float4 iA = *(const float4*)(cinv + b * S_ + l * 8);
    const float4 iB = *(const float4*)(cinv + b * S_ + l * 8 + 4);
    const float km0=cA.x*INV_LN2F, km1=cA.y*INV_LN2F, km2=cA.z*INV_LN2F, km3=cA.w*INV_LN2F;
    const float km4=cB.x*INV_LN2F, km5=cB.y*INV_LN2F, km6=cB.z*INV_LN2F, km7=cB.w*INV_LN2F;
    const float ki0=iA.x*INV_LN2F, ki1=iA.y*INV_LN2F, ki2=iA.z*INV_LN2F, ki3=iA.w*INV_LN2F;
    const float ki4=iB.x*INV_LN2F, ki5=iB.y*INV_LN2F, ki6=iB.z*INV_LN2F, ki7=iB.w*INV_LN2F;

    // t = 0 init
    float4 xa = LD(ep, 0), xb = LD4(ep, 0);
    float4 qa = LD(tp, 0), qb = LD4(tp, 0);
    float m0 = __builtin_amdgcn_exp2f(fmaf(xa.x,INV_LN2F,-km0))*ki0 + (l==0?0.f:NEG_INF);
    float m1 = __builtin_amdgcn_exp2f(fmaf(xa.y,INV_LN2F,-km1))*ki1 + NEG_INF;
    float m2 = __builtin_amdgcn_exp2f(fmaf(xa.z,INV_LN2F,-km2))*ki2 + NEG_INF;
    float m3 = __builtin_amdgcn_exp2f(fmaf(xa.w,INV_LN2F,-km3))*ki3 + NEG_INF;
    float m4 = __builtin_amdgcn_exp2f(fmaf(xb.x,INV_LN2F,-km4))*ki4 + NEG_INF;
    float m5 = __builtin_amdgcn_exp2f(fmaf(xb.y,INV_LN2F,-km5))*ki5 + NEG_INF;
    float m6 = __builtin_amdgcn_exp2f(fmaf(xb.z,INV_LN2F,-km6))*ki6 + NEG_INF;
    float m7 = __builtin_amdgcn_exp2f(fmaf(xb.w,INV_LN2F,-km7))*ki7 + NEG_INF;
    const float muN = __shfl(m0 + qa.x, 0);   // mu[0,0]+beta[0,0] == mu_N
    float v0 = (m0 - muN) + qa.x + (l==0?0.f:NEG_INF);
    float v1 = (m1 - muN) + qa.y + NEG_INF;
    float v2 = (m2 - muN) + qa.z + NEG_INF;
    float v3 = (m3 - muN) + qa.w + NEG_INF;
    float v4 = (m4 - muN) + qb.x + NEG_INF;
    float v5 = (m5 - muN) + qb.y + NEG_INF;
    float v6 = (m6 - muN) + qb.z + NEG_INF;
    float v7 = (m7 - muN) + qb.w + NEG_INF;
    unsigned long long acc = 0ULL;

    // ring prologue: rows 1..8 -> slots 1..7,0
    float4 eA1=LD(ep,1), eB1=LD4(ep,1), qA1=LD(tp,1), qB1=LD4(tp,1);
    float4 eA2=LD(ep,2), eB2=LD4(ep,2), qA2=LD(tp,2), qB2=LD4(tp,2);
    float4 eA3=LD(ep,3), eB3=LD4(ep,3), qA3=LD(tp,3), qB3=LD4(tp,3);
    float4 eA4=LD(ep,4), eB4=LD4(ep,4), qA4=LD(tp,4), qB4=LD4(tp,4);
    float4 eA5=LD(ep,5), eB5=LD4(ep,5), qA5=LD(tp,5), qB5=LD4(tp,5);
    float4 eA6=LD(ep,6), eB6=LD4(ep,6), qA6=LD(tp,6), qB6=LD4(tp,6);
    float4 eA7=LD(ep,7), eB7=LD4(ep,7), qA7=LD(tp,7), qB7=LD4(tp,7);
    float4 eA0=LD(ep,8), eB0=LD4(ep,8), qA0=LD(tp,8), qB0=LD4(tp,8);

    for (int t = 1; t + 7 < T_; t += 8) {
        FVSTEP(t,     eA1, eB1, qA1, qB1);
        FVSTEP(t + 1, eA2, eB2, qA2, qB2);
        FVSTEP(t + 2, eA3, eB3, qA3, qB3);
        FVSTEP(t + 3, eA4, eB4, qA4, qB4);
        FVSTEP(t + 4, eA5, eB5, qA5, qB5);
        FVSTEP(t + 5, eA6, eB6, qA6, qB6);
        FVSTEP(t + 6, eA7, eB7, qA7, qB7);
        FVSTEP(t + 7, eA0, eB0, qA0, qB0);
    }
    FVSTEP(1017, eA1, eB1, qA1, qB1);
    FVSTEP(1018, eA2, eB2, qA2, qB2);
    FVSTEP(1019, eA3, eB3, qA3, qB3);
    FVSTEP(1020, eA4, eB4, qA4, qB4);
    FVSTEP(1021, eA5, eB5, qA5, qB5);
    FVSTEP(1022, eA6, eB6, qA6, qB6);
    FVSTEP(1023, eA7, eB7, qA7, qB7);

    if (l == 63) muN_out[b] = m7;   // forward-computed mu2_N
    __syncthreads();

    // Backtrace: lanes hold their own column-group words; shfl selects.
    int jj = S_ - 1;
    if (l == 0) js[b * T_ + T_ - 1] = jj;
    unsigned long long wcur = mb_lds[127][l];
    for (int tau = 127; tau >= 0; --tau) {
        unsigned long long wv = wcur;
        if (tau > 0) wcur = mb_lds[tau - 1][l];
        for (int i = 7; i >= 0; --i) {
            int tt = tau * 8 + i;
            if (tt == 0) break;
            unsigned long long word = __shfl(wv, jj >> 3);
            int bit = (int)((word >> (((unsigned)tt & 7) * 8 + (jj & 7))) & 1ULL);
            jj -= bit;
            if (l == 0) js[b * T_ + tt - 1] = jj;
        }
    }
}

// ---------------------------------------------------------------------------
// K5: one-hot path writer.
__global__ void k_path(const int* __restrict__ js, float* __restrict__ outp) {
    const size_t total4 = (size_t)B_ * T_ * S_ / 4;
    float4* O = (float4*)outp;
    for (size_t i = (size_t)blockIdx.x * blockDim.x + threadIdx.x; i < total4;
         i += (size_t)gridDim.x * blockDim.x) {
        size_t base = i * 4;
        int s = (int)(base & (S_ - 1));
        int row = (int)(base >> 9);
        int jt = js[row];
        float4 o;
        o.x = (s == jt) ? 1.f : 0.f;
        o.y = (s + 1 == jt) ? 1.f : 0.f;
        o.z = (s + 2 == jt) ? 1.f : 0.f;
        o.w = (s + 3 == jt) ? 1.f : 0.f;
        O[i] = o;
    }
}

// ---------------------------------------------------------------------------
// K6: deterministic per-(b,chunk) partial of -0.5*sum(eps^2), t<len masked.
__global__ __launch_bounds__(256) void k_eps(const float* __restrict__ eps,
                                             const int* __restrict__ tlen,
                                             float* __restrict__ lp_part) {
    const int b = blockIdx.x / 48, chunk = blockIdx.x % 48;
    const int len = tlen[b];
    const float* base = eps + (size_t)b * T_ * C_ + (size_t)chunk * 8192;
    float acc = 0.f;
    for (int i = threadIdx.x; i < 2048; i += 256) {
        float4 v = *(const float4*)(base + i * 4);
        int t = (chunk * 8192 + i * 4) / C_;
        if (t < len) acc += v.x * v.x + v.y * v.y + v.z * v.z + v.w * v.w;
    }
    __shared__ float red[256];
    red[threadIdx.x] = acc;
    __syncthreads();
    for (int o = 128; o > 0; o >>= 1) {
        if (threadIdx.x < o) red[threadIdx.x] += red[threadIdx.x + o];
        __syncthreads();
    }
    if (threadIdx.x == 0) lp_part[blockIdx.x] = -0.5f * red[0];
}

// K7: logprobs. Softmax value at path cells recomputed on the fly (e-domain).
__global__ __launch_bounds__(256) void k_final(const float* __restrict__ Wr,
                                               const float* __restrict__ cmax,
                                               const float* __restrict__ cinv,
                                               const int* __restrict__ js,
                                               const float* __restrict__ lp_part,
                                               const int* __restrict__ tlen,
                                               const float* __restrict__ muN,
                                               float* __restrict__ out_lp) {
    const int b = blockIdx.x;
    float acc = 0.f;
    for (int t = threadIdx.x; t < T_; t += 256) {
        int jt = js[b * T_ + t];
        float x  = Wr[((size_t)b * T_ + t) * S_ + jt];
        float cm = cmax[b * S_ + jt];
        float ci = cinv[b * S_ + jt];
        acc += __builtin_amdgcn_exp2f((x - cm) * INV_LN2F) * ci;
    }
    __shared__ float red[256];
    red[threadIdx.x] = acc;
    __syncthreads();
    for (int o = 128; o > 0; o >>= 1) {
        if (threadIdx.x < o) red[threadIdx.x] += red[threadIdx.x + o];
        __syncthreads();
    }
    if (threadIdx.x == 0) {
        float basep = 0.f;
        for (int i = 0; i < 48; ++i) basep += lp_part[b * 48 + i];
        out_lp[b] = basep - HALF_LOG_2PI * ((float)tlen[b] * C_)
                    + red[0] - LN2F * muN[b];
    }
}

// ---------------------------------------------------------------------------
extern "C" void kernel_launch(void* const* d_in, const int* in_sizes, int n_in,
                              void* d_out, int out_size, void* d_ws, size_t ws_size,
                              hipStream_t stream) {
    const float* eps  = (const float*)d_in[0];
    const float* cond = (const float*)d_in[1];
    const int* tlen   = (const int*)d_in[2];

    float* out_path = (float*)d_out;
    float* out_lp   = out_path + (size_t)B_ * T_ * S_;

    const size_t NBTS = (size_t)B_ * T_ * S_;
    char* w = (char*)d_ws;
    float* Wr    = (float*)w;                         // raw logits, 67 MB
    float* beta  = Wr + NBTS;                         // beta2, 67 MB
    float* pmax  = beta + NBTS;                       // 4*B*S
    float* psum  = pmax + (size_t)4 * B_ * S_;        // 4*B*S
    float* cmax  = psum + (size_t)4 * B_ * S_;        // B*S
    float* cinv  = cmax + (size_t)B_ * S_;            // B*S
    float* lp_part = cinv + (size_t)B_ * S_;          // B*48
    float* muN   = lp_part + B_ * 48;                 // B
    int*   js    = (int*)(muN + B_);                  // B*T

    k_gemm<<<dim3(S_ / 128, T_ / 128, B_), 256, 0, stream>>>(eps, cond, Wr);
    k_stats1<<<B_ * 2 * 4, 256, 0, stream>>>(Wr, pmax, psum);
    k_stats2<<<B_ * S_ / 256, 256, 0, stream>>>(pmax, psum, cmax, cinv);
    k_beta<<<B_, 64, 0, stream>>>(Wr, cmax, cinv, beta);
    k_muvit<<<B_, 64, 0, stream>>>(Wr, beta, cmax, cinv, js, muN);
    k_path<<<4096, 256, 0, stream>>>(js, out_path);
    k_eps<<<B_ * 48, 256, 0, stream>>>(eps, tlen, lp_part);
    k_final<<<B_, 256, 0, stream>>>(Wr, cmax, cinv, js, lp_part, tlen, muN, out_lp);
}

// Round 4
// 650.001 us; speedup vs baseline: 2.6536x; 1.3455x over previous
//
#include <hip/hip_runtime.h>
#include <cstdint>
#include <cstddef>

#define B_ 32
#define T_ 1024
#define S_ 512
#define C_ 384
#define NEG_INF (-1000000000.0f)
#define HALF_LOG_2PI 0.91893853320467274178f
#define LN2F 0.69314718055994530942f
#define INV_LN2F 1.44269504088896340736f

typedef unsigned short u16;
typedef unsigned long long u64;

// log2-domain logaddexp: log2(2^a + 2^b), raw HW v_exp_f32 / v_log_f32.
__device__ __forceinline__ float lae2(float a, float b) {
    float mx = fmaxf(a, b);
    float d  = fminf(a, b) - mx;          // <= 0
    return mx + __builtin_amdgcn_logf(1.0f + __builtin_amdgcn_exp2f(d));
}

__device__ __forceinline__ unsigned rne16(float f) {   // f32 -> bf16 bits (RNE)
    unsigned b = __float_as_uint(f);
    return (b + 0x7FFFu + ((b >> 16) & 1u)) >> 16;
}
__device__ __forceinline__ uint4 pack8f(float a0, float a1, float a2, float a3,
                                        float a4, float a5, float a6, float a7) {
    uint4 q;
    q.x = rne16(a0) | (rne16(a1) << 16);
    q.y = rne16(a2) | (rne16(a3) << 16);
    q.z = rne16(a4) | (rne16(a5) << 16);
    q.w = rne16(a6) | (rne16(a7) << 16);
    return q;
}
// unpack 8 bf16 (uint4) -> 8 named floats with prefix p
#define UNPK(q, p)                                                              \
    float p##0 = __uint_as_float((q).x << 16),                                  \
          p##1 = __uint_as_float((q).x & 0xFFFF0000u),                          \
          p##2 = __uint_as_float((q).y << 16),                                  \
          p##3 = __uint_as_float((q).y & 0xFFFF0000u),                          \
          p##4 = __uint_as_float((q).z << 16),                                  \
          p##5 = __uint_as_float((q).z & 0xFFFF0000u),                          \
          p##6 = __uint_as_float((q).w << 16),                                  \
          p##7 = __uint_as_float((q).w & 0xFFFF0000u)

#define PROW(t) (*(const uint4*)(Pb  + (size_t)(t) * S_ + l8))
#define BROW(t) (*(const uint4*)(Btb + (size_t)(t) * S_ + l8))

// ---------------------------------------------------------------------------
// K1: Wr_raw[b,t,s] = sum_c eps[b,t,c] * cond[b,s,c]  (f32 vector GEMM)
__global__ __launch_bounds__(256) void k_gemm(const float* __restrict__ eps,
                                              const float* __restrict__ cond,
                                              float* __restrict__ Wr) {
    __shared__ float As[8][128];
    __shared__ float Bs[8][128];
    const int b  = blockIdx.z;
    const int m0 = blockIdx.y * 128;
    const int n0 = blockIdx.x * 128;
    const int tid = threadIdx.x;
    const float* A  = eps  + (size_t)b * T_ * C_;
    const float* Bm = cond + (size_t)b * S_ * C_;

    const int lr = tid >> 1;
    const int lc = (tid & 1) * 4;
    const int ty = tid >> 4;
    const int tx = tid & 15;

    float acc[8][8];
#pragma unroll
    for (int i = 0; i < 8; ++i)
#pragma unroll
        for (int j = 0; j < 8; ++j) acc[i][j] = 0.f;

    for (int k0 = 0; k0 < C_; k0 += 8) {
        float4 av = *(const float4*)(A  + (size_t)(m0 + lr) * C_ + k0 + lc);
        float4 bv = *(const float4*)(Bm + (size_t)(n0 + lr) * C_ + k0 + lc);
        __syncthreads();
        As[lc + 0][lr] = av.x; As[lc + 1][lr] = av.y;
        As[lc + 2][lr] = av.z; As[lc + 3][lr] = av.w;
        Bs[lc + 0][lr] = bv.x; Bs[lc + 1][lr] = bv.y;
        Bs[lc + 2][lr] = bv.z; Bs[lc + 3][lr] = bv.w;
        __syncthreads();
#pragma unroll
        for (int kk = 0; kk < 8; ++kk) {
            float4 a0 = *(const float4*)&As[kk][ty * 8];
            float4 a1 = *(const float4*)&As[kk][ty * 8 + 4];
            float4 b0 = *(const float4*)&Bs[kk][tx * 8];
            float4 b1 = *(const float4*)&Bs[kk][tx * 8 + 4];
            float a[8] = {a0.x, a0.y, a0.z, a0.w, a1.x, a1.y, a1.z, a1.w};
            float bb[8] = {b0.x, b0.y, b0.z, b0.w, b1.x, b1.y, b1.z, b1.w};
#pragma unroll
            for (int i = 0; i < 8; ++i)
#pragma unroll
                for (int j = 0; j < 8; ++j) acc[i][j] += a[i] * bb[j];
        }
    }
#pragma unroll
    for (int i = 0; i < 8; ++i) {
        float* dst = Wr + ((size_t)b * T_ + m0 + ty * 8 + i) * S_ + n0 + tx * 8;
        *(float4*)dst = make_float4(acc[i][0], acc[i][1], acc[i][2], acc[i][3]);
        *(float4*)(dst + 4) = make_float4(acc[i][4], acc[i][5], acc[i][6], acc[i][7]);
    }
}

// ---------------------------------------------------------------------------
// K2a: per-(b,s,chunk) partial column stats over a 256-t range (4 chunks).
__global__ __launch_bounds__(256) void k_stats1(const float* __restrict__ Wr,
                                                float* __restrict__ pmax,
                                                float* __restrict__ psum) {
    const int c  = blockIdx.x & 3;
    const int bh = blockIdx.x >> 2;
    const int b  = bh >> 1;
    const int s  = ((bh & 1) << 8) + threadIdx.x;
    const float* col = Wr + (size_t)b * T_ * S_ + (size_t)c * 256 * S_ + s;
    float m = -3.0e38f, sum = 0.f;
    for (int t = 0; t < 256; t += 4) {
        float x0 = col[(size_t)(t + 0) * S_];
        float x1 = col[(size_t)(t + 1) * S_];
        float x2 = col[(size_t)(t + 2) * S_];
        float x3 = col[(size_t)(t + 3) * S_];
        float nm = fmaxf(fmaxf(fmaxf(fmaxf(m, x0), x1), x2), x3);
        sum = sum * expf(m - nm) + expf(x0 - nm) + expf(x1 - nm)
            + expf(x2 - nm) + expf(x3 - nm);
        m = nm;
    }
    pmax[(size_t)c * B_ * S_ + b * S_ + s] = m;
    psum[(size_t)c * B_ * S_ + b * S_ + s] = sum;
}

// K2b: combine 4 chunk partials -> cmax, cinv.
__global__ __launch_bounds__(256) void k_stats2(const float* __restrict__ pmax,
                                                const float* __restrict__ psum,
                                                float* __restrict__ cmax,
                                                float* __restrict__ cinv) {
    const int i = blockIdx.x * 256 + threadIdx.x;
    float m0 = pmax[i], m1 = pmax[(size_t)B_ * S_ + i];
    float m2 = pmax[(size_t)2 * B_ * S_ + i], m3 = pmax[(size_t)3 * B_ * S_ + i];
    float m = fmaxf(fmaxf(m0, m1), fmaxf(m2, m3));
    float s = psum[i] * expf(m0 - m)
            + psum[(size_t)B_ * S_ + i] * expf(m1 - m)
            + psum[(size_t)2 * B_ * S_ + i] * expf(m2 - m)
            + psum[(size_t)3 * B_ * S_ + i] * expf(m3 - m);
    cmax[i] = m;
    cinv[i] = 1.0f / s;
}

// ---------------------------------------------------------------------------
// K3: P = softmax(Wr, axis=T) / ln2, stored bf16.
__global__ __launch_bounds__(256) void k_pack(const float* __restrict__ Wr,
                                              const float* __restrict__ cmax,
                                              const float* __restrict__ cinv,
                                              u16* __restrict__ P) {
    const size_t total8 = (size_t)B_ * T_ * S_ / 8;
    for (size_t i = (size_t)blockIdx.x * 256 + threadIdx.x; i < total8;
         i += (size_t)gridDim.x * 256) {
        size_t base = i * 8;
        int s = (int)(base & (S_ - 1));
        int b = (int)(base >> 19);
        float4 xA = *(const float4*)(Wr + base);
        float4 xB = *(const float4*)(Wr + base + 4);
        float4 mA = *(const float4*)(cmax + (size_t)b * S_ + s);
        float4 mB = *(const float4*)(cmax + (size_t)b * S_ + s + 4);
        float4 iA = *(const float4*)(cinv + (size_t)b * S_ + s);
        float4 iB = *(const float4*)(cinv + (size_t)b * S_ + s + 4);
        float p0 = __builtin_amdgcn_exp2f(fmaf(xA.x, INV_LN2F, -mA.x * INV_LN2F)) * iA.x * INV_LN2F;
        float p1 = __builtin_amdgcn_exp2f(fmaf(xA.y, INV_LN2F, -mA.y * INV_LN2F)) * iA.y * INV_LN2F;
        float p2 = __builtin_amdgcn_exp2f(fmaf(xA.z, INV_LN2F, -mA.z * INV_LN2F)) * iA.z * INV_LN2F;
        float p3 = __builtin_amdgcn_exp2f(fmaf(xA.w, INV_LN2F, -mA.w * INV_LN2F)) * iA.w * INV_LN2F;
        float p4 = __builtin_amdgcn_exp2f(fmaf(xB.x, INV_LN2F, -mB.x * INV_LN2F)) * iB.x * INV_LN2F;
        float p5 = __builtin_amdgcn_exp2f(fmaf(xB.y, INV_LN2F, -mB.y * INV_LN2F)) * iB.y * INV_LN2F;
        float p6 = __builtin_amdgcn_exp2f(fmaf(xB.z, INV_LN2F, -mB.z * INV_LN2F)) * iB.z * INV_LN2F;
        float p7 = __builtin_amdgcn_exp2f(fmaf(xB.w, INV_LN2F, -mB.w * INV_LN2F)) * iB.w * INV_LN2F;
        *(uint4*)(P + base) = pack8f(p0, p1, p2, p3, p4, p5, p6, p7);
    }
}

// ---------------------------------------------------------------------------
// K4: fused kernel. Blocks 0..255: chunk-parallel backward DP (beta, bf16 out,
// 128-row window + 256-row zero-init warm-up; per-t constant error cancels in
// Viterbi). Blocks 256..287: exact streaming forward DP for mu_N only.
// One wave per block, 8 cols/lane, ring-8 register prefetch on bf16 rows.

// backward step: consumes E row (tt+1) held in Q; prefetches row (tt-7).
#define BQ(tt, Q, PF) do {                                                      \
    UNPK(Q, eE);                                                                \
    if ((PF) && (tt) - 8 >= w0) Q = PROW((tt) - 7);                             \
    float j0 = m0 + eE0, j1 = m1 + eE1, j2 = m2 + eE2, j3 = m3 + eE3;           \
    float j4 = m4 + eE4, j5 = m5 + eE5, j6 = m6 + eE6, j7 = m7 + eE7;           \
    float rt = __shfl_down(j0, 1); if (l == 63) rt = NEG_INF;                   \
    m0 = lae2(j0, j1); m1 = lae2(j1, j2); m2 = lae2(j2, j3); m3 = lae2(j3, j4); \
    m4 = lae2(j4, j5); m5 = lae2(j5, j6); m6 = lae2(j6, j7); m7 = lae2(j7, rt); \
    if ((tt) < w0 + 128)                                                        \
        *(uint4*)(Bb + (size_t)(tt) * S_ + l8) =                                \
            pack8f(m0, m1, m2, m3, m4, m5, m6, m7);                             \
} while (0)

// forward (mu_N) step: consumes P row tt in Q; prefetches row tt+8.
#define MQ(tt, Q, PF) do {                                                      \
    UNPK(Q, eE);                                                                \
    if ((PF) && (tt) + 8 <= 1023) Q = PROW((tt) + 8);                           \
    float lf = __shfl_up(m7, 1); if (l == 0) lf = NEG_INF;                      \
    float n0 = eE0 + lae2(m0, lf);                                              \
    float n1 = eE1 + lae2(m1, m0);                                              \
    float n2 = eE2 + lae2(m2, m1);                                              \
    float n3 = eE3 + lae2(m3, m2);                                              \
    float n4 = eE4 + lae2(m4, m3);                                              \
    float n5 = eE5 + lae2(m5, m4);                                              \
    float n6 = eE6 + lae2(m6, m5);                                              \
    float n7 = eE7 + lae2(m7, m6);                                              \
    m0 = n0; m1 = n1; m2 = n2; m3 = n3; m4 = n4; m5 = n5; m6 = n6; m7 = n7;     \
} while (0)

__global__ __launch_bounds__(64) void k_bmn(const u16* __restrict__ P,
                                            u16* __restrict__ Bt,
                                            float* __restrict__ mu2N) {
    const int l = threadIdx.x, l8 = l * 8;
    const int blk = blockIdx.x;
    if (blk < 256) {
        const int b = blk >> 3, c = blk & 7, w0 = c * 128;
        const u16* Pb = P  + (size_t)b * T_ * S_;
        u16*      Bb = Bt + (size_t)b * T_ * S_;
        float m0, m1, m2, m3, m4, m5, m6, m7;
        int te = w0 + 383;
        if (te > 1023) te = 1023;
        if (te == 1023) {
            m0 = m1 = m2 = m3 = m4 = m5 = m6 = NEG_INF;
            m7 = (l == 63) ? 0.f : NEG_INF;
            if (1023 < w0 + 128)
                *(uint4*)(Bb + (size_t)1023 * S_ + l8) =
                    pack8f(m0, m1, m2, m3, m4, m5, m6, m7);
        } else {
            m0 = m1 = m2 = m3 = m4 = m5 = m6 = m7 = 0.f;
        }
        const int count = te - w0;
        const int rem = count & 7;
        int tt = te - 1;
        for (int r = 0; r < rem; ++r, --tt) {
            uint4 q = PROW(tt + 1);
            BQ(tt, q, 0);
        }
        uint4 q0 = PROW(tt + 1), q1 = PROW(tt),     q2 = PROW(tt - 1), q3 = PROW(tt - 2);
        uint4 q4 = PROW(tt - 3), q5 = PROW(tt - 4), q6 = PROW(tt - 5), q7 = PROW(tt - 6);
        for (; tt - 7 >= w0; tt -= 8) {
            BQ(tt - 0, q0, 1);
            BQ(tt - 1, q1, 1);
            BQ(tt - 2, q2, 1);
            BQ(tt - 3, q3, 1);
            BQ(tt - 4, q4, 1);
            BQ(tt - 5, q5, 1);
            BQ(tt - 6, q6, 1);
            BQ(tt - 7, q7, 1);
        }
    } else {
        const int b = blk - 256;
        const u16* Pb = P + (size_t)b * T_ * S_;
        float m0, m1, m2, m3, m4, m5, m6, m7;
        {
            uint4 q = PROW(0);
            UNPK(q, eE);
            m0 = eE0 + ((l == 0) ? 0.f : NEG_INF);
            m1 = eE1 + NEG_INF; m2 = eE2 + NEG_INF; m3 = eE3 + NEG_INF;
            m4 = eE4 + NEG_INF; m5 = eE5 + NEG_INF; m6 = eE6 + NEG_INF;
            m7 = eE7 + NEG_INF;
        }
        int tt = 1;
        for (int r = 0; r < 7; ++r, ++tt) {
            uint4 q = PROW(tt);
            MQ(tt, q, 0);
        }
        uint4 q0 = PROW(tt + 0), q1 = PROW(tt + 1), q2 = PROW(tt + 2), q3 = PROW(tt + 3);
        uint4 q4 = PROW(tt + 4), q5 = PROW(tt + 5), q6 = PROW(tt + 6), q7 = PROW(tt + 7);
        for (; tt + 7 <= 1023; tt += 8) {
            MQ(tt + 0, q0, 1);
            MQ(tt + 1, q1, 1);
            MQ(tt + 2, q2, 1);
            MQ(tt + 3, q3, 1);
            MQ(tt + 4, q4, 1);
            MQ(tt + 5, q5, 1);
            MQ(tt + 6, q6, 1);
            MQ(tt + 7, q7, 1);
        }
        if (l == 63) mu2N[b] = m7;
    }
}

// ---------------------------------------------------------------------------
// K5: chunk-parallel Viterbi. Per chunk: mu-warm-up (restart) + v-recurrence
// on lp = mu + beta (constant shifts cancel); emits move bits for its window.
#define VQ(TT, QP, QB, PF) do {                                                 \
    UNPK(QP, eE); UNPK(QB, bB);                                                 \
    if ((PF) && (TT) + 8 <= tend) { QP = PROW((TT) + 8); QB = BROW((TT) + 8); } \
    float lf = __shfl_up(m7, 1); if (l == 0) lf = NEG_INF;                      \
    float n0 = eE0 + lae2(m0, lf);                                              \
    float n1 = eE1 + lae2(m1, m0);                                              \
    float n2 = eE2 + lae2(m2, m1);                                              \
    float n3 = eE3 + lae2(m3, m2);                                              \
    float n4 = eE4 + lae2(m4, m3);                                              \
    float n5 = eE5 + lae2(m5, m4);                                              \
    float n6 = eE6 + lae2(m6, m5);                                              \
    float n7 = eE7 + lae2(m7, m6);                                              \
    float vlf = __shfl_up(v7, 1); if (l == 0) vlf = NEG_INF;                    \
    unsigned c0 = (vlf > v0) ? 1u   : 0u; float w0v = (n0 + bB0) + fmaxf(v0, vlf); \
    unsigned c1 = (v0 > v1) ? 2u    : 0u; float w1v = (n1 + bB1) + fmaxf(v1, v0);  \
    unsigned c2 = (v1 > v2) ? 4u    : 0u; float w2v = (n2 + bB2) + fmaxf(v2, v1);  \
    unsigned c3 = (v2 > v3) ? 8u    : 0u; float w3v = (n3 + bB3) + fmaxf(v3, v2);  \
    unsigned c4 = (v3 > v4) ? 16u   : 0u; float w4v = (n4 + bB4) + fmaxf(v4, v3);  \
    unsigned c5 = (v4 > v5) ? 32u   : 0u; float w5v = (n5 + bB5) + fmaxf(v5, v4);  \
    unsigned c6 = (v5 > v6) ? 64u   : 0u; float w6v = (n6 + bB6) + fmaxf(v6, v5);  \
    unsigned c7 = (v6 > v7) ? 128u  : 0u; float w7v = (n7 + bB7) + fmaxf(v7, v6);  \
    unsigned byte = c0 | c1 | c2 | c3 | c4 | c5 | c6 | c7;                      \
    acc |= ((u64)byte) << (((TT) & 7) * 8);                                     \
    if (((TT) & 7) == 7) {                                                      \
        if ((TT) >= w0) mrow[((TT) >> 3) * 64 + l] = acc;                       \
        acc = 0ULL;                                                             \
    }                                                                           \
    m0 = n0; m1 = n1; m2 = n2; m3 = n3; m4 = n4; m5 = n5; m6 = n6; m7 = n7;     \
    v0 = w0v; v1 = w1v; v2 = w2v; v3 = w3v;                                     \
    v4 = w4v; v5 = w5v; v6 = w6v; v7 = w7v;                                     \
} while (0)

__global__ __launch_bounds__(64) void k_vit(const u16* __restrict__ P,
                                            const u16* __restrict__ Bt,
                                            u64* __restrict__ mbg) {
    const int l = threadIdx.x, l8 = l * 8;
    const int b = blockIdx.x >> 3, c = blockIdx.x & 7;
    const int w0 = c * 128;
    const int tend = w0 + 127;
    const int t0 = (w0 >= 256) ? (w0 - 256) : 0;
    const u16* Pb  = P  + (size_t)b * T_ * S_;
    const u16* Btb = Bt + (size_t)b * T_ * S_;
    u64* mrow = mbg + (size_t)b * 8192;

    float m0, m1, m2, m3, m4, m5, m6, m7;
    float v0, v1, v2, v3, v4, v5, v6, v7;
    {
        uint4 qp = PROW(t0); UNPK(qp, eE);
        uint4 qb = BROW(t0); UNPK(qb, bB);
        if (t0 == 0) {
            m0 = eE0 + ((l == 0) ? 0.f : NEG_INF);
            m1 = eE1 + NEG_INF; m2 = eE2 + NEG_INF; m3 = eE3 + NEG_INF;
            m4 = eE4 + NEG_INF; m5 = eE5 + NEG_INF; m6 = eE6 + NEG_INF;
            m7 = eE7 + NEG_INF;
        } else {
            m0 = eE0; m1 = eE1; m2 = eE2; m3 = eE3;
            m4 = eE4; m5 = eE5; m6 = eE6; m7 = eE7;
        }
        v0 = m0 + bB0; v1 = m1 + bB1; v2 = m2 + bB2; v3 = m3 + bB3;
        v4 = m4 + bB4; v5 = m5 + bB5; v6 = m6 + bB6; v7 = m7 + bB7;
    }
    u64 acc = 0ULL;
    const int count = tend - t0;
    const int rem = count & 7;
    int tt = t0 + 1;
    for (int r = 0; r < rem; ++r, ++tt) {
        uint4 qp = PROW(tt);
        uint4 qb = BROW(tt);
        VQ(tt, qp, qb, 0);
    }
    uint4 p0 = PROW(tt + 0), p1 = PROW(tt + 1), p2 = PROW(tt + 2), p3 = PROW(tt + 3);
    uint4 p4 = PROW(tt + 4), p5 = PROW(tt + 5), p6 = PROW(tt + 6), p7 = PROW(tt + 7);
    uint4 g0 = BROW(tt + 0), g1 = BROW(tt + 1), g2 = BROW(tt + 2), g3 = BROW(tt + 3);
    uint4 g4 = BROW(tt + 4), g5 = BROW(tt + 5), g6 = BROW(tt + 6), g7 = BROW(tt + 7);
    for (; tt + 7 <= tend; tt += 8) {
        VQ(tt + 0, p0, g0, 1);
        VQ(tt + 1, p1, g1, 1);
        VQ(tt + 2, p2, g2, 1);
        VQ(tt + 3, p3, g3, 1);
        VQ(tt + 4, p4, g4, 1);
        VQ(tt + 5, p5, g5, 1);
        VQ(tt + 6, p6, g6, 1);
        VQ(tt + 7, p7, g7, 1);
    }
}

// ---------------------------------------------------------------------------
// K6: backtrace. Stage 64KB of move bits to LDS, lane-pipelined walk.
__global__ __launch_bounds__(256) void k_btr(const u64* __restrict__ mbg,
                                             int* __restrict__ js) {
    __shared__ u64 mb[128][64];
    const int b = blockIdx.x, tid = threadIdx.x;
    const uint4* src = (const uint4*)(mbg + (size_t)b * 8192);
    uint4* dst = (uint4*)&mb[0][0];
    for (int i = tid; i < 4096; i += 256) dst[i] = src[i];
    __syncthreads();
    if (tid >= 64) return;
    const int l = tid;
    int jj = S_ - 1;
    if (l == 0) js[b * T_ + T_ - 1] = jj;
    u64 wcur = mb[127][l];
    for (int tau = 127; tau >= 0; --tau) {
        u64 wv = wcur;
        if (tau > 0) wcur = mb[tau - 1][l];
        for (int i = 7; i >= 0; --i) {
            int t = tau * 8 + i;
            if (t == 0) break;
            u64 word = __shfl(wv, jj >> 3);
            int bit = (int)((word >> ((t & 7) * 8 + (jj & 7))) & 1ULL);
            jj -= bit;
            if (l == 0) js[b * T_ + t - 1] = jj;
        }
    }
}

// ---------------------------------------------------------------------------
// K7: one-hot path writer.
__global__ void k_path(const int* __restrict__ js, float* __restrict__ outp) {
    const size_t total4 = (size_t)B_ * T_ * S_ / 4;
    float4* O = (float4*)outp;
    for (size_t i = (size_t)blockIdx.x * blockDim.x + threadIdx.x; i < total4;
         i += (size_t)gridDim.x * blockDim.x) {
        size_t base = i * 4;
        int s = (int)(base & (S_ - 1));
        int row = (int)(base >> 9);
        int jt = js[row];
        float4 o;
        o.x = (s == jt) ? 1.f : 0.f;
        o.y = (s + 1 == jt) ? 1.f : 0.f;
        o.z = (s + 2 == jt) ? 1.f : 0.f;
        o.w = (s + 3 == jt) ? 1.f : 0.f;
        O[i] = o;
    }
}

// ---------------------------------------------------------------------------
// K8: deterministic per-(b,chunk) partial of -0.5*sum(eps^2), t<len masked.
__global__ __launch_bounds__(256) void k_eps(const float* __restrict__ eps,
                                             const int* __restrict__ tlen,
                                             float* __restrict__ lp_part) {
    const int b = blockIdx.x / 48, chunk = blockIdx.x % 48;
    const int len = tlen[b];
    const float* base = eps + (size_t)b * T_ * C_ + (size_t)chunk * 8192;
    float acc = 0.f;
    for (int i = threadIdx.x; i < 2048; i += 256) {
        float4 v = *(const float4*)(base + i * 4);
        int t = (chunk * 8192 + i * 4) / C_;
        if (t < len) acc += v.x * v.x + v.y * v.y + v.z * v.z + v.w * v.w;
    }
    __shared__ float red[256];
    red[threadIdx.x] = acc;
    __syncthreads();
    for (int o = 128; o > 0; o >>= 1) {
        if (threadIdx.x < o) red[threadIdx.x] += red[threadIdx.x + o];
        __syncthreads();
    }
    if (threadIdx.x == 0) lp_part[blockIdx.x] = -0.5f * red[0];
}

// K9: logprobs[b] = sum(lp_part) - 0.5*log(2pi)*len*C + ln2*(sum_t P[t,j_t] - mu2N)
__global__ __launch_bounds__(256) void k_final(const u16* __restrict__ P,
                                               const int* __restrict__ js,
                                               const float* __restrict__ lp_part,
                                               const int* __restrict__ tlen,
                                               const float* __restrict__ mu2N,
                                               float* __restrict__ out_lp) {
    const int b = blockIdx.x;
    float acc = 0.f;
    for (int t = threadIdx.x; t < T_; t += 256) {
        int jt = js[b * T_ + t];
        unsigned u = P[((size_t)b * T_ + t) * S_ + jt];
        acc += __uint_as_float(u << 16);
    }
    __shared__ float red[256];
    red[threadIdx.x] = acc;
    __syncthreads();
    for (int o = 128; o > 0; o >>= 1) {
        if (threadIdx.x < o) red[threadIdx.x] += red[threadIdx.x + o];
        __syncthreads();
    }
    if (threadIdx.x == 0) {
        float basep = 0.f;
        for (int i = 0; i < 48; ++i) basep += lp_part[b * 48 + i];
        out_lp[b] = basep - HALF_LOG_2PI * ((float)tlen[b] * C_)
                    + LN2F * (red[0] - mu2N[b]);
    }
}

// ---------------------------------------------------------------------------
extern "C" void kernel_launch(void* const* d_in, const int* in_sizes, int n_in,
                              void* d_out, int out_size, void* d_ws, size_t ws_size,
                              hipStream_t stream) {
    const float* eps  = (const float*)d_in[0];
    const float* cond = (const float*)d_in[1];
    const int* tlen   = (const int*)d_in[2];

    float* out_path = (float*)d_out;
    float* out_lp   = out_path + (size_t)B_ * T_ * S_;

    const size_t NBTS = (size_t)B_ * T_ * S_;
    char* w = (char*)d_ws;
    float* Wr   = (float*)w;                          // 67 MB raw logits
    u16*   P    = (u16*)(Wr + NBTS);                  // 34 MB bf16 softmax/ln2
    u16*   Bt   = P + NBTS;                           // 34 MB bf16 beta (log2)
    u64*   mbg  = (u64*)(Bt + NBTS);                  // 2 MB move bits
    float* pmax = (float*)(mbg + (size_t)B_ * 8192);
    float* psum = pmax + (size_t)4 * B_ * S_;
    float* cmax = psum + (size_t)4 * B_ * S_;
    float* cinv = cmax + (size_t)B_ * S_;
    float* lp_part = cinv + (size_t)B_ * S_;
    float* mu2N = lp_part + B_ * 48;
    int*   js   = (int*)(mu2N + B_);

    k_gemm<<<dim3(S_ / 128, T_ / 128, B_), 256, 0, stream>>>(eps, cond, Wr);
    k_stats1<<<B_ * 2 * 4, 256, 0, stream>>>(Wr, pmax, psum);
    k_stats2<<<B_ * S_ / 256, 256, 0, stream>>>(pmax, psum, cmax, cinv);
    k_pack<<<2048, 256, 0, stream>>>(Wr, cmax, cinv, P);
    k_bmn<<<288, 64, 0, stream>>>(P, Bt, mu2N);
    k_vit<<<256, 64, 0, stream>>>(P, Bt, mbg);
    k_btr<<<B_, 256, 0, stream>>>(mbg, js);
    k_path<<<4096, 256, 0, stream>>>(js, out_path);
    k_eps<<<B_ * 48, 256, 0, stream>>>(eps, tlen, lp_part);
    k_final<<<B_, 256, 0, stream>>>(P, js, lp_part, tlen, mu2N, out_lp);
}

// Round 5
// 537.981 us; speedup vs baseline: 3.2062x; 1.2082x over previous
//
#include <hip/hip_runtime.h>
#include <cstdint>
#include <cstddef>

#define B_ 32
#define T_ 1024
#define S_ 512
#define C_ 384
#define HALF_LOG_2PI 0.91893853320467274178f
#define LN2F 0.69314718055994530942f
#define INV_LN2F 1.44269504088896340736f

typedef unsigned short u16;
typedef unsigned long long u64;

__device__ __forceinline__ unsigned rne16(float f) {   // f32 -> bf16 bits (RNE)
    unsigned b = __float_as_uint(f);
    return (b + 0x7FFFu + ((b >> 16) & 1u)) >> 16;
}
__device__ __forceinline__ uint4 pack8f(float a0, float a1, float a2, float a3,
                                        float a4, float a5, float a6, float a7) {
    uint4 q;
    q.x = rne16(a0) | (rne16(a1) << 16);
    q.y = rne16(a2) | (rne16(a3) << 16);
    q.z = rne16(a4) | (rne16(a5) << 16);
    q.w = rne16(a6) | (rne16(a7) << 16);
    return q;
}
// unpack 8 bf16 (uint4) -> 8 named floats with prefix p (low half = even col)
#define UNPK(q, p)                                                              \
    float p##0 = __uint_as_float((q).x << 16),                                  \
          p##1 = __uint_as_float((q).x & 0xFFFF0000u),                          \
          p##2 = __uint_as_float((q).y << 16),                                  \
          p##3 = __uint_as_float((q).y & 0xFFFF0000u),                          \
          p##4 = __uint_as_float((q).z << 16),                                  \
          p##5 = __uint_as_float((q).z & 0xFFFF0000u),                          \
          p##6 = __uint_as_float((q).w << 16),                                  \
          p##7 = __uint_as_float((q).w & 0xFFFF0000u)

#define PROW(t) (*(const uint4*)(Pb  + (size_t)(t) * S_ + l8))
#define BROW(t) (*(const uint4*)(Btb + (size_t)(t) * S_ + l8))

// wave-uniform power-of-2 renorm of 8 regs (scale-up small maxes); no offset
#define RENORM8(r0,r1,r2,r3,r4,r5,r6,r7) do {                                   \
    float mx_ = fmaxf(fmaxf(fmaxf(r0,r1),fmaxf(r2,r3)),                         \
                      fmaxf(fmaxf(r4,r5),fmaxf(r6,r7)));                        \
    mx_ = fmaxf(mx_, __shfl_xor(mx_, 1));  mx_ = fmaxf(mx_, __shfl_xor(mx_, 2));\
    mx_ = fmaxf(mx_, __shfl_xor(mx_, 4));  mx_ = fmaxf(mx_, __shfl_xor(mx_, 8));\
    mx_ = fmaxf(mx_, __shfl_xor(mx_, 16)); mx_ = fmaxf(mx_, __shfl_xor(mx_, 32));\
    int eb_ = (__float_as_int(mx_) >> 23) & 255;                                \
    float sc_ = (eb_ > 0) ? __int_as_float((254 - eb_) << 23) : 1.0f;           \
    r0*=sc_; r1*=sc_; r2*=sc_; r3*=sc_; r4*=sc_; r5*=sc_; r6*=sc_; r7*=sc_;     \
} while (0)

// ---------------------------------------------------------------------------
// K1: Wr_raw[b,t,s] = sum_c eps[b,t,c] * cond[b,s,c]  (f32 vector GEMM)
__global__ __launch_bounds__(256) void k_gemm(const float* __restrict__ eps,
                                              const float* __restrict__ cond,
                                              float* __restrict__ Wr) {
    __shared__ float As[8][128];
    __shared__ float Bs[8][128];
    const int b  = blockIdx.z;
    const int m0 = blockIdx.y * 128;
    const int n0 = blockIdx.x * 128;
    const int tid = threadIdx.x;
    const float* A  = eps  + (size_t)b * T_ * C_;
    const float* Bm = cond + (size_t)b * S_ * C_;

    const int lr = tid >> 1;
    const int lc = (tid & 1) * 4;
    const int ty = tid >> 4;
    const int tx = tid & 15;

    float acc[8][8];
#pragma unroll
    for (int i = 0; i < 8; ++i)
#pragma unroll
        for (int j = 0; j < 8; ++j) acc[i][j] = 0.f;

    for (int k0 = 0; k0 < C_; k0 += 8) {
        float4 av = *(const float4*)(A  + (size_t)(m0 + lr) * C_ + k0 + lc);
        float4 bv = *(const float4*)(Bm + (size_t)(n0 + lr) * C_ + k0 + lc);
        __syncthreads();
        As[lc + 0][lr] = av.x; As[lc + 1][lr] = av.y;
        As[lc + 2][lr] = av.z; As[lc + 3][lr] = av.w;
        Bs[lc + 0][lr] = bv.x; Bs[lc + 1][lr] = bv.y;
        Bs[lc + 2][lr] = bv.z; Bs[lc + 3][lr] = bv.w;
        __syncthreads();
#pragma unroll
        for (int kk = 0; kk < 8; ++kk) {
            float4 a0 = *(const float4*)&As[kk][ty * 8];
            float4 a1 = *(const float4*)&As[kk][ty * 8 + 4];
            float4 b0 = *(const float4*)&Bs[kk][tx * 8];
            float4 b1 = *(const float4*)&Bs[kk][tx * 8 + 4];
            float a[8] = {a0.x, a0.y, a0.z, a0.w, a1.x, a1.y, a1.z, a1.w};
            float bb[8] = {b0.x, b0.y, b0.z, b0.w, b1.x, b1.y, b1.z, b1.w};
#pragma unroll
            for (int i = 0; i < 8; ++i)
#pragma unroll
                for (int j = 0; j < 8; ++j) acc[i][j] += a[i] * bb[j];
        }
    }
#pragma unroll
    for (int i = 0; i < 8; ++i) {
        float* dst = Wr + ((size_t)b * T_ + m0 + ty * 8 + i) * S_ + n0 + tx * 8;
        *(float4*)dst = make_float4(acc[i][0], acc[i][1], acc[i][2], acc[i][3]);
        *(float4*)(dst + 4) = make_float4(acc[i][4], acc[i][5], acc[i][6], acc[i][7]);
    }
}

// ---------------------------------------------------------------------------
// K2a/K2b: column softmax stats over t (4 t-chunks, then combine).
__global__ __launch_bounds__(256) void k_stats1(const float* __restrict__ Wr,
                                                float* __restrict__ pmax,
                                                float* __restrict__ psum) {
    const int c  = blockIdx.x & 3;
    const int bh = blockIdx.x >> 2;
    const int b  = bh >> 1;
    const int s  = ((bh & 1) << 8) + threadIdx.x;
    const float* col = Wr + (size_t)b * T_ * S_ + (size_t)c * 256 * S_ + s;
    float m = -3.0e38f, sum = 0.f;
    for (int t = 0; t < 256; t += 4) {
        float x0 = col[(size_t)(t + 0) * S_];
        float x1 = col[(size_t)(t + 1) * S_];
        float x2 = col[(size_t)(t + 2) * S_];
        float x3 = col[(size_t)(t + 3) * S_];
        float nm = fmaxf(fmaxf(fmaxf(fmaxf(m, x0), x1), x2), x3);
        sum = sum * expf(m - nm) + expf(x0 - nm) + expf(x1 - nm)
            + expf(x2 - nm) + expf(x3 - nm);
        m = nm;
    }
    pmax[(size_t)c * B_ * S_ + b * S_ + s] = m;
    psum[(size_t)c * B_ * S_ + b * S_ + s] = sum;
}

__global__ __launch_bounds__(256) void k_stats2(const float* __restrict__ pmax,
                                                const float* __restrict__ psum,
                                                float* __restrict__ cmax,
                                                float* __restrict__ cinv) {
    const int i = blockIdx.x * 256 + threadIdx.x;
    float m0 = pmax[i], m1 = pmax[(size_t)B_ * S_ + i];
    float m2 = pmax[(size_t)2 * B_ * S_ + i], m3 = pmax[(size_t)3 * B_ * S_ + i];
    float m = fmaxf(fmaxf(m0, m1), fmaxf(m2, m3));
    float s = psum[i] * expf(m0 - m)
            + psum[(size_t)B_ * S_ + i] * expf(m1 - m)
            + psum[(size_t)2 * B_ * S_ + i] * expf(m2 - m)
            + psum[(size_t)3 * B_ * S_ + i] * expf(m3 - m);
    cmax[i] = m;
    cinv[i] = 1.0f / s;
}

// ---------------------------------------------------------------------------
// K3: P_hat = exp(softmax(Wr,axis=T)) / 4, stored bf16.  (in [0.25, 0.68])
__global__ __launch_bounds__(256) void k_pack(const float* __restrict__ Wr,
                                              const float* __restrict__ cmax,
                                              const float* __restrict__ cinv,
                                              u16* __restrict__ P) {
    const size_t total8 = (size_t)B_ * T_ * S_ / 8;
    for (size_t i = (size_t)blockIdx.x * 256 + threadIdx.x; i < total8;
         i += (size_t)gridDim.x * 256) {
        size_t base = i * 8;
        int s = (int)(base & (S_ - 1));
        int b = (int)(base >> 19);
        float4 xA = *(const float4*)(Wr + base);
        float4 xB = *(const float4*)(Wr + base + 4);
        float4 mA = *(const float4*)(cmax + (size_t)b * S_ + s);
        float4 mB = *(const float4*)(cmax + (size_t)b * S_ + s + 4);
        float4 iA = *(const float4*)(cinv + (size_t)b * S_ + s);
        float4 iB = *(const float4*)(cinv + (size_t)b * S_ + s + 4);
        float w0 = __builtin_amdgcn_exp2f(fmaf(xA.x, INV_LN2F, -mA.x * INV_LN2F)) * iA.x;
        float w1 = __builtin_amdgcn_exp2f(fmaf(xA.y, INV_LN2F, -mA.y * INV_LN2F)) * iA.y;
        float w2 = __builtin_amdgcn_exp2f(fmaf(xA.z, INV_LN2F, -mA.z * INV_LN2F)) * iA.z;
        float w3 = __builtin_amdgcn_exp2f(fmaf(xA.w, INV_LN2F, -mA.w * INV_LN2F)) * iA.w;
        float w4 = __builtin_amdgcn_exp2f(fmaf(xB.x, INV_LN2F, -mB.x * INV_LN2F)) * iB.x;
        float w5 = __builtin_amdgcn_exp2f(fmaf(xB.y, INV_LN2F, -mB.y * INV_LN2F)) * iB.y;
        float w6 = __builtin_amdgcn_exp2f(fmaf(xB.z, INV_LN2F, -mB.z * INV_LN2F)) * iB.z;
        float w7 = __builtin_amdgcn_exp2f(fmaf(xB.w, INV_LN2F, -mB.w * INV_LN2F)) * iB.w;
        float p0 = __builtin_amdgcn_exp2f(fmaf(w0, INV_LN2F, -2.0f));
        float p1 = __builtin_amdgcn_exp2f(fmaf(w1, INV_LN2F, -2.0f));
        float p2 = __builtin_amdgcn_exp2f(fmaf(w2, INV_LN2F, -2.0f));
        float p3 = __builtin_amdgcn_exp2f(fmaf(w3, INV_LN2F, -2.0f));
        float p4 = __builtin_amdgcn_exp2f(fmaf(w4, INV_LN2F, -2.0f));
        float p5 = __builtin_amdgcn_exp2f(fmaf(w5, INV_LN2F, -2.0f));
        float p6 = __builtin_amdgcn_exp2f(fmaf(w6, INV_LN2F, -2.0f));
        float p7 = __builtin_amdgcn_exp2f(fmaf(w7, INV_LN2F, -2.0f));
        *(uint4*)(P + base) = pack8f(p0, p1, p2, p3, p4, p5, p6, p7);
    }
}

// ---------------------------------------------------------------------------
// K4: chunk-parallel backward DP, LINEAR domain.
// B_t[j] = B_{t+1}[j]*P[t+1][j] + B_{t+1}[j+1]*P[t+1][j+1]; renorm every 8.
#define BSTEPL(tt, Q, PF) do {                                                  \
    UNPK(Q, eP);                                                                \
    if ((PF) && (tt) >= w0 + 8) Q = PROW((tt) - 7);                             \
    float z0=m0*eP0, z1=m1*eP1, z2=m2*eP2, z3=m3*eP3;                           \
    float z4=m4*eP4, z5=m5*eP5, z6=m6*eP6, z7=m7*eP7;                           \
    float rt = __shfl_down(z0, 1); if (l == 63) rt = 0.f;                       \
    m0=z0+z1; m1=z1+z2; m2=z2+z3; m3=z3+z4;                                     \
    m4=z4+z5; m5=z5+z6; m6=z6+z7; m7=z7+rt;                                     \
    if ((tt) < w0 + 128) {                                                      \
        uint4 st;                                                               \
        asm("v_cvt_pk_bf16_f32 %0, %1, %2" : "=v"(st.x) : "v"(m0), "v"(m1));    \
        asm("v_cvt_pk_bf16_f32 %0, %1, %2" : "=v"(st.y) : "v"(m2), "v"(m3));    \
        asm("v_cvt_pk_bf16_f32 %0, %1, %2" : "=v"(st.z) : "v"(m4), "v"(m5));    \
        asm("v_cvt_pk_bf16_f32 %0, %1, %2" : "=v"(st.w) : "v"(m6), "v"(m7));    \
        *(uint4*)(Bb + (size_t)(tt) * S_ + l8) = st;                            \
    }                                                                           \
} while (0)

__global__ __launch_bounds__(64) void k_beta(const u16* __restrict__ P,
                                             u16* __restrict__ Bt) {
    const int l = threadIdx.x, l8 = l * 8;
    const int b = blockIdx.x >> 3, c = blockIdx.x & 7;
    const int w0 = c * 128;
    const u16* Pb = P  + (size_t)b * T_ * S_;
    u16*      Bb = Bt + (size_t)b * T_ * S_;
    float m0, m1, m2, m3, m4, m5, m6, m7;
    int te = w0 + 383;
    if (te > 1023) te = 1023;
    if (te == 1023) {   // exact boundary init: B[1023][j] = (j==511)
        m0 = m1 = m2 = m3 = m4 = m5 = m6 = 0.f;
        m7 = (l == 63) ? 1.f : 0.f;
        if (1023 < w0 + 128) {   // only c==7 stores the init row
            uint4 st;
            asm("v_cvt_pk_bf16_f32 %0, %1, %2" : "=v"(st.x) : "v"(m0), "v"(m1));
            asm("v_cvt_pk_bf16_f32 %0, %1, %2" : "=v"(st.y) : "v"(m2), "v"(m3));
            asm("v_cvt_pk_bf16_f32 %0, %1, %2" : "=v"(st.z) : "v"(m4), "v"(m5));
            asm("v_cvt_pk_bf16_f32 %0, %1, %2" : "=v"(st.w) : "v"(m6), "v"(m7));
            *(uint4*)(Bb + (size_t)1023 * S_ + l8) = st;
        }
    } else {            // uniform restart (per-t constant error; decisions invariant)
        m0 = m1 = m2 = m3 = m4 = m5 = m6 = m7 = 1.f;
    }
    const int count = te - w0;
    const int rem = count & 7;
    int tt = te - 1;
    for (int r = 0; r < rem; ++r, --tt) {
        uint4 q = PROW(tt + 1);
        BSTEPL(tt, q, 0);
    }
    uint4 q0 = PROW(tt + 1), q1 = PROW(tt),     q2 = PROW(tt - 1), q3 = PROW(tt - 2);
    uint4 q4 = PROW(tt - 3), q5 = PROW(tt - 4), q6 = PROW(tt - 5), q7 = PROW(tt - 6);
    for (; tt - 7 >= w0; tt -= 8) {
        BSTEPL(tt - 0, q0, 1);
        BSTEPL(tt - 1, q1, 1);
        BSTEPL(tt - 2, q2, 1);
        BSTEPL(tt - 3, q3, 1);
        BSTEPL(tt - 4, q4, 1);
        BSTEPL(tt - 5, q5, 1);
        BSTEPL(tt - 6, q6, 1);
        BSTEPL(tt - 7, q7, 1);
        RENORM8(m0, m1, m2, m3, m4, m5, m6, m7);
    }
}

// ---------------------------------------------------------------------------
// K5: chunk-parallel fused mu-forward + Viterbi, LINEAR domain.
// M_t[j] = P[t][j]*(M[j]+M[j-1]); LP = M*B; V_t = LP * max(V[j], V[j-1]).
// Exports chunk log-values for the mu_N delta chain.
#define VSTEPL(TT, QP, QB, PF) do {                                             \
    UNPK(QP, eP); UNPK(QB, eB);                                                 \
    if ((PF) && (TT) + 8 <= tend) { QP = PROW((TT)+8); QB = BROW((TT)+8); }     \
    float lf = __shfl_up(m7, 1); if (l == 0) lf = 0.f;                          \
    float n0 = eP0*(m0+lf); float n1 = eP1*(m1+m0);                             \
    float n2 = eP2*(m2+m1); float n3 = eP3*(m3+m2);                             \
    float n4 = eP4*(m4+m3); float n5 = eP5*(m5+m4);                             \
    float n6 = eP6*(m6+m5); float n7 = eP7*(m7+m6);                             \
    float vlf = __shfl_up(v7, 1); if (l == 0) vlf = 0.f;                        \
    if ((TT) >= w0) {                                                           \
        unsigned cc0=(vlf>v0)?1u:0u, cc1=(v0>v1)?2u:0u, cc2=(v1>v2)?4u:0u,      \
                 cc3=(v2>v3)?8u:0u,  cc4=(v3>v4)?16u:0u, cc5=(v4>v5)?32u:0u,    \
                 cc6=(v5>v6)?64u:0u, cc7=(v6>v7)?128u:0u;                       \
        acc |= ((u64)(cc0|cc1|cc2|cc3|cc4|cc5|cc6|cc7)) << (((TT)&7)*8);        \
        if (((TT)&7) == 7) { mrow[((TT)>>3)*64 + l] = acc; acc = 0ULL; }        \
    }                                                                           \
    float w0v=(n0*eB0)*fmaxf(v0,vlf); float w1v=(n1*eB1)*fmaxf(v1,v0);          \
    float w2v=(n2*eB2)*fmaxf(v2,v1);  float w3v=(n3*eB3)*fmaxf(v3,v2);          \
    float w4v=(n4*eB4)*fmaxf(v4,v3);  float w5v=(n5*eB5)*fmaxf(v5,v4);          \
    float w6v=(n6*eB6)*fmaxf(v6,v5);  float w7v=(n7*eB7)*fmaxf(v7,v6);          \
    m0=n0;m1=n1;m2=n2;m3=n3;m4=n4;m5=n5;m6=n6;m7=n7;                            \
    v0=w0v;v1=w1v;v2=w2v;v3=w3v;v4=w4v;v5=w5v;v6=w6v;v7=w7v;                    \
    if ((TT) == wexp) { wex = __shfl(m0, 8 * c); wio = ioffM; }                 \
} while (0)

#define RENORM_MI() do {                                                        \
    float mx_ = fmaxf(fmaxf(fmaxf(m0,m1),fmaxf(m2,m3)),                         \
                      fmaxf(fmaxf(m4,m5),fmaxf(m6,m7)));                        \
    mx_ = fmaxf(mx_, __shfl_xor(mx_, 1));  mx_ = fmaxf(mx_, __shfl_xor(mx_, 2));\
    mx_ = fmaxf(mx_, __shfl_xor(mx_, 4));  mx_ = fmaxf(mx_, __shfl_xor(mx_, 8));\
    mx_ = fmaxf(mx_, __shfl_xor(mx_, 16)); mx_ = fmaxf(mx_, __shfl_xor(mx_, 32));\
    int eb_ = (__float_as_int(mx_) >> 23) & 255;                                \
    float sc_ = (eb_ > 0) ? __int_as_float((254 - eb_) << 23) : 1.0f;           \
    if (eb_ > 0) ioffM += eb_ - 127;                                            \
    m0*=sc_; m1*=sc_; m2*=sc_; m3*=sc_; m4*=sc_; m5*=sc_; m6*=sc_; m7*=sc_;     \
} while (0)

#define RENORM_VR() do {                                                        \
    float mx_ = fmaxf(fmaxf(fmaxf(v0,v1),fmaxf(v2,v3)),                         \
                      fmaxf(fmaxf(v4,v5),fmaxf(v6,v7)));                        \
    mx_ = fmaxf(mx_, __shfl_xor(mx_, 1));  mx_ = fmaxf(mx_, __shfl_xor(mx_, 2));\
    mx_ = fmaxf(mx_, __shfl_xor(mx_, 4));  mx_ = fmaxf(mx_, __shfl_xor(mx_, 8));\
    mx_ = fmaxf(mx_, __shfl_xor(mx_, 16)); mx_ = fmaxf(mx_, __shfl_xor(mx_, 32));\
    int eb_ = (__float_as_int(mx_) >> 23) & 255;                                \
    float sc_ = (eb_ > 0) ? __int_as_float((254 - eb_) << 23) : 0.0f;           \
    float ad_ = (eb_ > 0) ? 0.f : 1.f;                                          \
    v0=fmaf(v0,sc_,ad_); v1=fmaf(v1,sc_,ad_); v2=fmaf(v2,sc_,ad_);              \
    v3=fmaf(v3,sc_,ad_); v4=fmaf(v4,sc_,ad_); v5=fmaf(v5,sc_,ad_);              \
    v6=fmaf(v6,sc_,ad_); v7=fmaf(v7,sc_,ad_);                                   \
} while (0)

__global__ __launch_bounds__(64) void k_vit(const u16* __restrict__ P,
                                            const u16* __restrict__ Bt,
                                            u64* __restrict__ mbg,
                                            float* __restrict__ elog,
                                            float* __restrict__ wlg) {
    const int l = threadIdx.x, l8 = l * 8;
    const int b = blockIdx.x >> 3, c = blockIdx.x & 7;
    const int w0 = c * 128, tend = w0 + 127;
    const int t0 = (w0 >= 256) ? (w0 - 256) : 0;
    const int wexp = w0 - 1;
    const u16* Pb  = P  + (size_t)b * T_ * S_;
    const u16* Btb = Bt + (size_t)b * T_ * S_;
    u64* mrow = mbg + (size_t)b * 8192;

    float m0,m1,m2,m3,m4,m5,m6,m7, v0,v1,v2,v3,v4,v5,v6,v7;
    int ioffM = 0;
    float wex = 1.f; int wio = 0;
    {
        uint4 qp = PROW(t0); UNPK(qp, eP);
        uint4 qb = BROW(t0); UNPK(qb, eB);
        if (t0 == 0) {   // exact: M[0][j] = P[0][j] * [j==0]
            m0 = (l == 0) ? eP0 : 0.f;
            m1 = 0.f; m2 = 0.f; m3 = 0.f; m4 = 0.f; m5 = 0.f; m6 = 0.f; m7 = 0.f;
        } else {         // uniform restart
            m0 = eP0; m1 = eP1; m2 = eP2; m3 = eP3;
            m4 = eP4; m5 = eP5; m6 = eP6; m7 = eP7;
        }
        v0 = m0*eB0; v1 = m1*eB1; v2 = m2*eB2; v3 = m3*eB3;
        v4 = m4*eB4; v5 = m5*eB5; v6 = m6*eB6; v7 = m7*eB7;
    }
    u64 acc = 0ULL;
    int t = t0 + 1;
    const int cnt = tend - t0;     // 127 (c=0), 255 (c=1), 383 (c>=2)
    const int rem = cnt & 7;
    for (int r = 0; r < rem; ++r, ++t) {
        uint4 qp = PROW(t), qb = BROW(t);
        VSTEPL(t, qp, qb, 0);
    }
    uint4 p0=PROW(t+0), p1=PROW(t+1), p2=PROW(t+2), p3=PROW(t+3);
    uint4 p4=PROW(t+4), p5=PROW(t+5), p6=PROW(t+6), p7=PROW(t+7);
    uint4 g0=BROW(t+0), g1=BROW(t+1), g2=BROW(t+2), g3=BROW(t+3);
    uint4 g4=BROW(t+4), g5=BROW(t+5), g6=BROW(t+6), g7=BROW(t+7);
    for (; t + 7 <= tend; t += 8) {
        VSTEPL(t + 0, p0, g0, 1);
        VSTEPL(t + 1, p1, g1, 1);
        VSTEPL(t + 2, p2, g2, 1);
        VSTEPL(t + 3, p3, g3, 1);
        VSTEPL(t + 4, p4, g4, 1);
        VSTEPL(t + 5, p5, g5, 1);
        VSTEPL(t + 6, p6, g6, 1);
        VSTEPL(t + 7, p7, g7, 1);
        RENORM_MI();
        RENORM_VR();
    }
    // exports for the mu_N delta chain (columns on the active diagonal)
    float eex = (c == 7) ? __shfl(m7, 63) : __shfl(m0, 8 * (c + 1));
    if (l == 0) {
        elog[b * 8 + c] = __builtin_amdgcn_logf(fmaxf(eex, 1e-35f)) + (float)ioffM;
        if (c >= 1)
            wlg[b * 8 + c] = __builtin_amdgcn_logf(fmaxf(wex, 1e-35f)) + (float)wio;
    }
}

// ---------------------------------------------------------------------------
// K6: backtrace. Stage 64KB of move bits to LDS, lane-pipelined walk.
__global__ __launch_bounds__(256) void k_btr(const u64* __restrict__ mbg,
                                             int* __restrict__ js) {
    __shared__ u64 mb[128][64];
    const int b = blockIdx.x, tid = threadIdx.x;
    const uint4* src = (const uint4*)(mbg + (size_t)b * 8192);
    uint4* dst = (uint4*)&mb[0][0];
    for (int i = tid; i < 4096; i += 256) dst[i] = src[i];
    __syncthreads();
    if (tid >= 64) return;
    const int l = tid;
    int jj = S_ - 1;
    if (l == 0) js[b * T_ + T_ - 1] = jj;
    u64 wcur = mb[127][l];
    for (int tau = 127; tau >= 0; --tau) {
        u64 wv = wcur;
        if (tau > 0) wcur = mb[tau - 1][l];
        for (int i = 7; i >= 0; --i) {
            int t = tau * 8 + i;
            if (t == 0) break;
            u64 word = __shfl(wv, jj >> 3);
            int bit = (int)((word >> ((t & 7) * 8 + (jj & 7))) & 1ULL);
            jj -= bit;
            if (l == 0) js[b * T_ + t - 1] = jj;
        }
    }
}

// ---------------------------------------------------------------------------
// K7: one-hot path writer.
__global__ void k_path(const int* __restrict__ js, float* __restrict__ outp) {
    const size_t total4 = (size_t)B_ * T_ * S_ / 4;
    float4* O = (float4*)outp;
    for (size_t i = (size_t)blockIdx.x * blockDim.x + threadIdx.x; i < total4;
         i += (size_t)gridDim.x * blockDim.x) {
        size_t base = i * 4;
        int s = (int)(base & (S_ - 1));
        int row = (int)(base >> 9);
        int jt = js[row];
        float4 o;
        o.x = (s == jt) ? 1.f : 0.f;
        o.y = (s + 1 == jt) ? 1.f : 0.f;
        o.z = (s + 2 == jt) ? 1.f : 0.f;
        o.w = (s + 3 == jt) ? 1.f : 0.f;
        O[i] = o;
    }
}

// ---------------------------------------------------------------------------
// K8: deterministic per-(b,chunk) partial of -0.5*sum(eps^2), t<len masked.
__global__ __launch_bounds__(256) void k_eps(const float* __restrict__ eps,
                                             const int* __restrict__ tlen,
                                             float* __restrict__ lp_part) {
    const int b = blockIdx.x / 48, chunk = blockIdx.x % 48;
    const int len = tlen[b];
    const float* base = eps + (size_t)b * T_ * C_ + (size_t)chunk * 8192;
    float acc = 0.f;
    for (int i = threadIdx.x; i < 2048; i += 256) {
        float4 v = *(const float4*)(base + i * 4);
        int t = (chunk * 8192 + i * 4) / C_;
        if (t < len) acc += v.x * v.x + v.y * v.y + v.z * v.z + v.w * v.w;
    }
    __shared__ float red[256];
    red[threadIdx.x] = acc;
    __syncthreads();
    for (int o = 128; o > 0; o >>= 1) {
        if (threadIdx.x < o) red[threadIdx.x] += red[threadIdx.x + o];
        __syncthreads();
    }
    if (threadIdx.x == 0) lp_part[blockIdx.x] = -0.5f * red[0];
}

// K9: logprobs. W = ln(P_hat)+ln4 = LN2*(log2(P_hat)+2); mu_N via delta chain.
// The +2 per-cell and the path-length 2048 in mu2N cancel exactly.
__global__ __launch_bounds__(256) void k_final(const u16* __restrict__ P,
                                               const int* __restrict__ js,
                                               const float* __restrict__ lp_part,
                                               const int* __restrict__ tlen,
                                               const float* __restrict__ elog,
                                               const float* __restrict__ wlg,
                                               float* __restrict__ out_lp) {
    const int b = blockIdx.x;
    float acc = 0.f;
    for (int t = threadIdx.x; t < T_; t += 256) {
        int jt = js[b * T_ + t];
        unsigned u = P[((size_t)b * T_ + t) * S_ + jt];
        acc += __builtin_amdgcn_logf(__uint_as_float(u << 16));   // log2(P_hat)
    }
    __shared__ float red[256];
    red[threadIdx.x] = acc;
    __syncthreads();
    for (int o = 128; o > 0; o >>= 1) {
        if (threadIdx.x < o) red[threadIdx.x] += red[threadIdx.x + o];
        __syncthreads();
    }
    if (threadIdx.x == 0) {
        float basep = 0.f;
        for (int i = 0; i < 48; ++i) basep += lp_part[b * 48 + i];
        float mu2n = elog[b * 8 + 7];
        for (int cc = 1; cc < 8; ++cc)
            mu2n += elog[b * 8 + cc - 1] - wlg[b * 8 + cc];
        out_lp[b] = basep - HALF_LOG_2PI * ((float)tlen[b] * C_)
                    + LN2F * (red[0] - mu2n);
    }
}

// ---------------------------------------------------------------------------
extern "C" void kernel_launch(void* const* d_in, const int* in_sizes, int n_in,
                              void* d_out, int out_size, void* d_ws, size_t ws_size,
                              hipStream_t stream) {
    const float* eps  = (const float*)d_in[0];
    const float* cond = (const float*)d_in[1];
    const int* tlen   = (const int*)d_in[2];

    float* out_path = (float*)d_out;
    float* out_lp   = out_path + (size_t)B_ * T_ * S_;

    const size_t NBTS = (size_t)B_ * T_ * S_;
    char* w = (char*)d_ws;
    float* Wr   = (float*)w;                          // 67 MB raw logits
    u16*   P    = (u16*)(Wr + NBTS);                  // 34 MB bf16 exp(W)/4
    u16*   Bt   = P + NBTS;                           // 34 MB bf16 linear beta
    u64*   mbg  = (u64*)(Bt + NBTS);                  // 2 MB move bits
    float* pmax = (float*)(mbg + (size_t)B_ * 8192);
    float* psum = pmax + (size_t)4 * B_ * S_;
    float* cmax = psum + (size_t)4 * B_ * S_;
    float* cinv = cmax + (size_t)B_ * S_;
    float* lp_part = cinv + (size_t)B_ * S_;
    float* elog = lp_part + B_ * 48;                  // B*8 chunk end logs
    float* wlg  = elog + B_ * 8;                      // B*8 chunk warm logs
    int*   js   = (int*)(wlg + B_ * 8);

    k_gemm<<<dim3(S_ / 128, T_ / 128, B_), 256, 0, stream>>>(eps, cond, Wr);
    k_stats1<<<B_ * 2 * 4, 256, 0, stream>>>(Wr, pmax, psum);
    k_stats2<<<B_ * S_ / 256, 256, 0, stream>>>(pmax, psum, cmax, cinv);
    k_pack<<<2048, 256, 0, stream>>>(Wr, cmax, cinv, P);
    k_beta<<<256, 64, 0, stream>>>(P, Bt);
    k_vit<<<256, 64, 0, stream>>>(P, Bt, mbg, elog, wlg);
    k_btr<<<B_, 256, 0, stream>>>(mbg, js);
    k_path<<<4096, 256, 0, stream>>>(js, out_path);
    k_eps<<<B_ * 48, 256, 0, stream>>>(eps, tlen, lp_part);
    k_final<<<B_, 256, 0, stream>>>(P, js, lp_part, tlen, elog, wlg, out_lp);
}

// Round 6
// 295.806 us; speedup vs baseline: 5.8311x; 1.8187x over previous
//
#include <hip/hip_runtime.h>
#include <cstdint>
#include <cstddef>

#define B_ 32
#define T_ 1024
#define S_ 512
#define C_ 384
#define HALF_LOG_2PI 0.91893853320467274178f
#define LN2F 0.69314718055994530942f
#define INV_LN2F 1.44269504088896340736f

typedef unsigned short u16;
typedef unsigned long long u64;
typedef __attribute__((ext_vector_type(8))) short bf16x8;
typedef __attribute__((ext_vector_type(4))) float f32x4;

__device__ __forceinline__ unsigned rne16(float f) {   // f32 -> bf16 bits (RNE)
    unsigned b = __float_as_uint(f);
    return (b + 0x7FFFu + ((b >> 16) & 1u)) >> 16;
}
__device__ __forceinline__ uint4 pack8f(float a0, float a1, float a2, float a3,
                                        float a4, float a5, float a6, float a7) {
    uint4 q;
    q.x = rne16(a0) | (rne16(a1) << 16);
    q.y = rne16(a2) | (rne16(a3) << 16);
    q.z = rne16(a4) | (rne16(a5) << 16);
    q.w = rne16(a6) | (rne16(a7) << 16);
    return q;
}
#define UNPK(q, p)                                                              \
    float p##0 = __uint_as_float((q).x << 16),                                  \
          p##1 = __uint_as_float((q).x & 0xFFFF0000u),                          \
          p##2 = __uint_as_float((q).y << 16),                                  \
          p##3 = __uint_as_float((q).y & 0xFFFF0000u),                          \
          p##4 = __uint_as_float((q).z << 16),                                  \
          p##5 = __uint_as_float((q).z & 0xFFFF0000u),                          \
          p##6 = __uint_as_float((q).w << 16),                                  \
          p##7 = __uint_as_float((q).w & 0xFFFF0000u)

#define PROW(t) (*(const uint4*)(Pb  + (size_t)(t) * S_ + l8))
#define BROW(t) (*(const uint4*)(Btb + (size_t)(t) * S_ + l8))

#define RENORM8(r0,r1,r2,r3,r4,r5,r6,r7) do {                                   \
    float mx_ = fmaxf(fmaxf(fmaxf(r0,r1),fmaxf(r2,r3)),                         \
                      fmaxf(fmaxf(r4,r5),fmaxf(r6,r7)));                        \
    mx_ = fmaxf(mx_, __shfl_xor(mx_, 1));  mx_ = fmaxf(mx_, __shfl_xor(mx_, 2));\
    mx_ = fmaxf(mx_, __shfl_xor(mx_, 4));  mx_ = fmaxf(mx_, __shfl_xor(mx_, 8));\
    mx_ = fmaxf(mx_, __shfl_xor(mx_, 16)); mx_ = fmaxf(mx_, __shfl_xor(mx_, 32));\
    int eb_ = (__float_as_int(mx_) >> 23) & 255;                                \
    float sc_ = (eb_ > 0) ? __int_as_float((254 - eb_) << 23) : 1.0f;           \
    r0*=sc_; r1*=sc_; r2*=sc_; r3*=sc_; r4*=sc_; r5*=sc_; r6*=sc_; r7*=sc_;     \
} while (0)

// ---------------------------------------------------------------------------
// K0a: eps -> bf16 (unmasked) + masked -0.5*sum(eps^2) partials.
__global__ __launch_bounds__(256) void k_eps(const float* __restrict__ eps,
                                             const int* __restrict__ tlen,
                                             float* __restrict__ lp_part,
                                             u16* __restrict__ Abf) {
    const int b = blockIdx.x / 48, chunk = blockIdx.x % 48;
    const int len = tlen[b];
    const float* base = eps + (size_t)b * T_ * C_ + (size_t)chunk * 8192;
    u16* obase = Abf + (size_t)b * T_ * C_ + (size_t)chunk * 8192;
    float acc = 0.f;
    for (int g = threadIdx.x; g < 1024; g += 256) {
        float4 v0 = *(const float4*)(base + g * 8);
        float4 v1 = *(const float4*)(base + g * 8 + 4);
        int t = (chunk * 8192 + g * 8) / C_;     // C_%8==0: no row straddle
        if (t < len)
            acc += v0.x*v0.x + v0.y*v0.y + v0.z*v0.z + v0.w*v0.w
                 + v1.x*v1.x + v1.y*v1.y + v1.z*v1.z + v1.w*v1.w;
        *(uint4*)(obase + g * 8) = pack8f(v0.x, v0.y, v0.z, v0.w,
                                          v1.x, v1.y, v1.z, v1.w);
    }
    __shared__ float red[256];
    red[threadIdx.x] = acc;
    __syncthreads();
    for (int o = 128; o > 0; o >>= 1) {
        if (threadIdx.x < o) red[threadIdx.x] += red[threadIdx.x + o];
        __syncthreads();
    }
    if (threadIdx.x == 0) lp_part[blockIdx.x] = -0.5f * red[0];
}

// K0b: cond -> bf16.
__global__ __launch_bounds__(256) void k_cvt(const float* __restrict__ src,
                                             u16* __restrict__ dst) {
    const size_t n8 = (size_t)B_ * S_ * C_ / 8;
    for (size_t i = (size_t)blockIdx.x * 256 + threadIdx.x; i < n8;
         i += (size_t)gridDim.x * 256) {
        float4 v0 = *(const float4*)(src + i * 8);
        float4 v1 = *(const float4*)(src + i * 8 + 4);
        *(uint4*)(dst + i * 8) = pack8f(v0.x, v0.y, v0.z, v0.w,
                                        v1.x, v1.y, v1.z, v1.w);
    }
}

// ---------------------------------------------------------------------------
// K1: bf16 MFMA GEMM. Wr[b,t,s] = sum_c A[b,t,c]*Bc[b,s,c]. 128x128 tile,
// 4 waves (2x2 of 64x64), BK=32, LDS XOR-swizzled (2-way = free).
__global__ __launch_bounds__(256) void k_gemm(const u16* __restrict__ A,
                                              const u16* __restrict__ Bc,
                                              float* __restrict__ Wr) {
    __shared__ u16 Al[4096];    // 128 rows x 32 bf16 (64B), swizzled
    __shared__ u16 Bl[4096];
    const int b  = blockIdx.z;
    const int m0 = blockIdx.y * 128;
    const int n0 = blockIdx.x * 128;
    const int tid = threadIdx.x;
    const int lane = tid & 63, wid = tid >> 6;
    const int wy = wid >> 1, wx = wid & 1;
    const int r15 = lane & 15, kg = lane >> 4;
    const u16* Ab = A  + (size_t)b * T_ * C_;
    const u16* Bb = Bc + (size_t)b * S_ * C_;

    f32x4 acc[4][4];
#pragma unroll
    for (int i = 0; i < 4; ++i)
#pragma unroll
        for (int j = 0; j < 4; ++j) acc[i][j] = (f32x4){0.f, 0.f, 0.f, 0.f};

    const int g1 = tid + 256;
    const int row0 = tid >> 2, o0 = tid & 3;
    const int row1 = g1 >> 2,  o1 = g1 & 3;
    const int wb0 = (row0 * 64 + o0 * 16) ^ (((row0 >> 1) & 7) << 4);
    const int wb1 = (row1 * 64 + o1 * 16) ^ (((row1 >> 1) & 7) << 4);
    const int rswz = ((r15 >> 1) & 7) << 4;

    for (int k0 = 0; k0 < C_; k0 += 32) {
        uint4 a0 = *(const uint4*)(Ab + (size_t)(m0 + row0) * C_ + k0 + o0 * 8);
        uint4 a1 = *(const uint4*)(Ab + (size_t)(m0 + row1) * C_ + k0 + o1 * 8);
        uint4 c0 = *(const uint4*)(Bb + (size_t)(n0 + row0) * C_ + k0 + o0 * 8);
        uint4 c1 = *(const uint4*)(Bb + (size_t)(n0 + row1) * C_ + k0 + o1 * 8);
        __syncthreads();          // previous iteration's LDS reads done
        *(uint4*)((char*)Al + wb0) = a0;
        *(uint4*)((char*)Al + wb1) = a1;
        *(uint4*)((char*)Bl + wb0) = c0;
        *(uint4*)((char*)Bl + wb1) = c1;
        __syncthreads();
        bf16x8 af[4], bfb[4];
#pragma unroll
        for (int ar = 0; ar < 4; ++ar) {
            int row = wy * 64 + ar * 16 + r15;
            af[ar] = *(const bf16x8*)((const char*)Al + ((row * 64 + kg * 16) ^ rswz));
        }
#pragma unroll
        for (int bc = 0; bc < 4; ++bc) {
            int row = wx * 64 + bc * 16 + r15;
            bfb[bc] = *(const bf16x8*)((const char*)Bl + ((row * 64 + kg * 16) ^ rswz));
        }
#pragma unroll
        for (int ar = 0; ar < 4; ++ar)
#pragma unroll
            for (int bc = 0; bc < 4; ++bc)
                acc[ar][bc] = __builtin_amdgcn_mfma_f32_16x16x32_bf16(
                    af[ar], bfb[bc], acc[ar][bc], 0, 0, 0);
    }
    // C/D: col = lane&15 (s), row = (lane>>4)*4 + reg (t)
#pragma unroll
    for (int ar = 0; ar < 4; ++ar) {
        int t = m0 + wy * 64 + ar * 16 + kg * 4;
#pragma unroll
        for (int bc = 0; bc < 4; ++bc) {
            int s = n0 + wx * 64 + bc * 16 + r15;
            float* dst = Wr + ((size_t)b * T_ + t) * S_ + s;
#pragma unroll
            for (int r = 0; r < 4; ++r) dst[(size_t)r * S_] = acc[ar][bc][r];
        }
    }
}

// ---------------------------------------------------------------------------
// K2a/K2b: column softmax stats over t.
__global__ __launch_bounds__(256) void k_stats1(const float* __restrict__ Wr,
                                                float* __restrict__ pmax,
                                                float* __restrict__ psum) {
    const int c  = blockIdx.x & 3;
    const int bh = blockIdx.x >> 2;
    const int b  = bh >> 1;
    const int s  = ((bh & 1) << 8) + threadIdx.x;
    const float* col = Wr + (size_t)b * T_ * S_ + (size_t)c * 256 * S_ + s;
    float m = -3.0e38f, sum = 0.f;
    for (int t = 0; t < 256; t += 4) {
        float x0 = col[(size_t)(t + 0) * S_];
        float x1 = col[(size_t)(t + 1) * S_];
        float x2 = col[(size_t)(t + 2) * S_];
        float x3 = col[(size_t)(t + 3) * S_];
        float nm = fmaxf(fmaxf(fmaxf(fmaxf(m, x0), x1), x2), x3);
        sum = sum * expf(m - nm) + expf(x0 - nm) + expf(x1 - nm)
            + expf(x2 - nm) + expf(x3 - nm);
        m = nm;
    }
    pmax[(size_t)c * B_ * S_ + b * S_ + s] = m;
    psum[(size_t)c * B_ * S_ + b * S_ + s] = sum;
}

__global__ __launch_bounds__(256) void k_stats2(const float* __restrict__ pmax,
                                                const float* __restrict__ psum,
                                                float* __restrict__ cmax,
                                                float* __restrict__ cinv) {
    const int i = blockIdx.x * 256 + threadIdx.x;
    float m0 = pmax[i], m1 = pmax[(size_t)B_ * S_ + i];
    float m2 = pmax[(size_t)2 * B_ * S_ + i], m3 = pmax[(size_t)3 * B_ * S_ + i];
    float m = fmaxf(fmaxf(m0, m1), fmaxf(m2, m3));
    float s = psum[i] * expf(m0 - m)
            + psum[(size_t)B_ * S_ + i] * expf(m1 - m)
            + psum[(size_t)2 * B_ * S_ + i] * expf(m2 - m)
            + psum[(size_t)3 * B_ * S_ + i] * expf(m3 - m);
    cmax[i] = m;
    cinv[i] = 1.0f / s;
}

// ---------------------------------------------------------------------------
// K3: P_hat = exp(softmax(Wr,axis=T)) / 4, bf16.
__global__ __launch_bounds__(256) void k_pack(const float* __restrict__ Wr,
                                              const float* __restrict__ cmax,
                                              const float* __restrict__ cinv,
                                              u16* __restrict__ P) {
    const size_t total8 = (size_t)B_ * T_ * S_ / 8;
    for (size_t i = (size_t)blockIdx.x * 256 + threadIdx.x; i < total8;
         i += (size_t)gridDim.x * 256) {
        size_t base = i * 8;
        int s = (int)(base & (S_ - 1));
        int b = (int)(base >> 19);
        float4 xA = *(const float4*)(Wr + base);
        float4 xB = *(const float4*)(Wr + base + 4);
        float4 mA = *(const float4*)(cmax + (size_t)b * S_ + s);
        float4 mB = *(const float4*)(cmax + (size_t)b * S_ + s + 4);
        float4 iA = *(const float4*)(cinv + (size_t)b * S_ + s);
        float4 iB = *(const float4*)(cinv + (size_t)b * S_ + s + 4);
        float w0 = __builtin_amdgcn_exp2f(fmaf(xA.x, INV_LN2F, -mA.x * INV_LN2F)) * iA.x;
        float w1 = __builtin_amdgcn_exp2f(fmaf(xA.y, INV_LN2F, -mA.y * INV_LN2F)) * iA.y;
        float w2 = __builtin_amdgcn_exp2f(fmaf(xA.z, INV_LN2F, -mA.z * INV_LN2F)) * iA.z;
        float w3 = __builtin_amdgcn_exp2f(fmaf(xA.w, INV_LN2F, -mA.w * INV_LN2F)) * iA.w;
        float w4 = __builtin_amdgcn_exp2f(fmaf(xB.x, INV_LN2F, -mB.x * INV_LN2F)) * iB.x;
        float w5 = __builtin_amdgcn_exp2f(fmaf(xB.y, INV_LN2F, -mB.y * INV_LN2F)) * iB.y;
        float w6 = __builtin_amdgcn_exp2f(fmaf(xB.z, INV_LN2F, -mB.z * INV_LN2F)) * iB.z;
        float w7 = __builtin_amdgcn_exp2f(fmaf(xB.w, INV_LN2F, -mB.w * INV_LN2F)) * iB.w;
        float p0 = __builtin_amdgcn_exp2f(fmaf(w0, INV_LN2F, -2.0f));
        float p1 = __builtin_amdgcn_exp2f(fmaf(w1, INV_LN2F, -2.0f));
        float p2 = __builtin_amdgcn_exp2f(fmaf(w2, INV_LN2F, -2.0f));
        float p3 = __builtin_amdgcn_exp2f(fmaf(w3, INV_LN2F, -2.0f));
        float p4 = __builtin_amdgcn_exp2f(fmaf(w4, INV_LN2F, -2.0f));
        float p5 = __builtin_amdgcn_exp2f(fmaf(w5, INV_LN2F, -2.0f));
        float p6 = __builtin_amdgcn_exp2f(fmaf(w6, INV_LN2F, -2.0f));
        float p7 = __builtin_amdgcn_exp2f(fmaf(w7, INV_LN2F, -2.0f));
        *(uint4*)(P + base) = pack8f(p0, p1, p2, p3, p4, p5, p6, p7);
    }
}

// ---------------------------------------------------------------------------
// K4: backward DP, linear domain. 16 chunks of 64 (warm 128), 16-deep ring,
// prologue-filled, guarded prefetch, tail consumes preloaded slots.
#define BSTEPL(tt, Q) do {                                                      \
    UNPK(Q, eP);                                                                \
    if ((tt) >= w0 + 16) Q = PROW((tt) - 15);                                   \
    float z0=m0*eP0, z1=m1*eP1, z2=m2*eP2, z3=m3*eP3;                           \
    float z4=m4*eP4, z5=m5*eP5, z6=m6*eP6, z7=m7*eP7;                           \
    float rt = __shfl_down(z0, 1); if (l == 63) rt = 0.f;                       \
    m0=z0+z1; m1=z1+z2; m2=z2+z3; m3=z3+z4;                                     \
    m4=z4+z5; m5=z5+z6; m6=z6+z7; m7=z7+rt;                                     \
    if ((tt) < w0 + 64) {                                                       \
        uint4 st;                                                               \
        asm("v_cvt_pk_bf16_f32 %0, %1, %2" : "=v"(st.x) : "v"(m0), "v"(m1));    \
        asm("v_cvt_pk_bf16_f32 %0, %1, %2" : "=v"(st.y) : "v"(m2), "v"(m3));    \
        asm("v_cvt_pk_bf16_f32 %0, %1, %2" : "=v"(st.z) : "v"(m4), "v"(m5));    \
        asm("v_cvt_pk_bf16_f32 %0, %1, %2" : "=v"(st.w) : "v"(m6), "v"(m7));    \
        *(uint4*)(Bb + (size_t)(tt) * S_ + l8) = st;                            \
    }                                                                           \
} while (0)

__global__ __launch_bounds__(64) void k_beta(const u16* __restrict__ P,
                                             u16* __restrict__ Bt) {
    const int l = threadIdx.x, l8 = l * 8;
    const int b = blockIdx.x >> 4, c = blockIdx.x & 15;
    const int w0 = c * 64;
    const u16* Pb = P  + (size_t)b * T_ * S_;
    u16*      Bb = Bt + (size_t)b * T_ * S_;
    float m0, m1, m2, m3, m4, m5, m6, m7;
    int te = w0 + 191;
    if (te > 1023) te = 1023;
    if (te == 1023) {    // exact init (c >= 13)
        m0 = m1 = m2 = m3 = m4 = m5 = m6 = 0.f;
        m7 = (l == 63) ? 1.f : 0.f;
        if (1023 < w0 + 64) {   // c == 15 stores init row
            uint4 st;
            asm("v_cvt_pk_bf16_f32 %0, %1, %2" : "=v"(st.x) : "v"(m0), "v"(m1));
            asm("v_cvt_pk_bf16_f32 %0, %1, %2" : "=v"(st.y) : "v"(m2), "v"(m3));
            asm("v_cvt_pk_bf16_f32 %0, %1, %2" : "=v"(st.z) : "v"(m4), "v"(m5));
            asm("v_cvt_pk_bf16_f32 %0, %1, %2" : "=v"(st.w) : "v"(m6), "v"(m7));
            *(uint4*)(Bb + (size_t)1023 * S_ + l8) = st;
        }
    } else {
        m0 = m1 = m2 = m3 = m4 = m5 = m6 = m7 = 1.f;
    }
    const int cnt = te - w0;          // 191 / 127 / 63  -> tail always 15
    uint4 q0 = PROW(te),      q1 = PROW(te - 1),  q2 = PROW(te - 2),  q3 = PROW(te - 3);
    uint4 q4 = PROW(te - 4),  q5 = PROW(te - 5),  q6 = PROW(te - 6),  q7 = PROW(te - 7);
    uint4 q8 = PROW(te - 8),  q9 = PROW(te - 9),  qA = PROW(te - 10), qB = PROW(te - 11);
    uint4 qC = PROW(te - 12), qD = PROW(te - 13), qE = PROW(te - 14), qF = PROW(te - 15);
    int tt = te - 1;
    const int nb = cnt >> 4;
    for (int blk = 0; blk < nb; ++blk, tt -= 16) {
        BSTEPL(tt - 0, q0); BSTEPL(tt - 1, q1); BSTEPL(tt - 2, q2); BSTEPL(tt - 3, q3);
        BSTEPL(tt - 4, q4); BSTEPL(tt - 5, q5); BSTEPL(tt - 6, q6); BSTEPL(tt - 7, q7);
        RENORM8(m0, m1, m2, m3, m4, m5, m6, m7);
        BSTEPL(tt - 8, q8);  BSTEPL(tt - 9, q9);  BSTEPL(tt - 10, qA); BSTEPL(tt - 11, qB);
        BSTEPL(tt - 12, qC); BSTEPL(tt - 13, qD); BSTEPL(tt - 14, qE); BSTEPL(tt - 15, qF);
        RENORM8(m0, m1, m2, m3, m4, m5, m6, m7);
    }
    // tail = 15 steps, slots already loaded
    BSTEPL(tt - 0, q0); BSTEPL(tt - 1, q1); BSTEPL(tt - 2, q2); BSTEPL(tt - 3, q3);
    BSTEPL(tt - 4, q4); BSTEPL(tt - 5, q5); BSTEPL(tt - 6, q6); BSTEPL(tt - 7, q7);
    RENORM8(m0, m1, m2, m3, m4, m5, m6, m7);
    BSTEPL(tt - 8, q8);  BSTEPL(tt - 9, q9);  BSTEPL(tt - 10, qA); BSTEPL(tt - 11, qB);
    BSTEPL(tt - 12, qC); BSTEPL(tt - 13, qD); BSTEPL(tt - 14, qE);
}

// ---------------------------------------------------------------------------
// K5: fused mu-forward + Viterbi, linear domain, 16 chunks of 64 (warm 128).
#define VSTEPL(TT, QP, QB) do {                                                 \
    UNPK(QP, eP); UNPK(QB, eB);                                                 \
    if ((TT) + 8 <= tend) { QP = PROW((TT) + 8); QB = BROW((TT) + 8); }         \
    float lf = __shfl_up(m7, 1); if (l == 0) lf = 0.f;                          \
    float n0 = eP0*(m0+lf); float n1 = eP1*(m1+m0);                             \
    float n2 = eP2*(m2+m1); float n3 = eP3*(m3+m2);                             \
    float n4 = eP4*(m4+m3); float n5 = eP5*(m5+m4);                             \
    float n6 = eP6*(m6+m5); float n7 = eP7*(m7+m6);                             \
    float vlf = __shfl_up(v7, 1); if (l == 0) vlf = 0.f;                        \
    if ((TT) >= w0) {                                                           \
        unsigned cc0=(vlf>v0)?1u:0u, cc1=(v0>v1)?2u:0u, cc2=(v1>v2)?4u:0u,      \
                 cc3=(v2>v3)?8u:0u,  cc4=(v3>v4)?16u:0u, cc5=(v4>v5)?32u:0u,    \
                 cc6=(v5>v6)?64u:0u, cc7=(v6>v7)?128u:0u;                       \
        acc |= ((u64)(cc0|cc1|cc2|cc3|cc4|cc5|cc6|cc7)) << (((TT)&7)*8);        \
        if (((TT)&7) == 7) { mrow[((TT)>>3)*64 + l] = acc; acc = 0ULL; }        \
    }                                                                           \
    float w0v=(n0*eB0)*fmaxf(v0,vlf); float w1v=(n1*eB1)*fmaxf(v1,v0);          \
    float w2v=(n2*eB2)*fmaxf(v2,v1);  float w3v=(n3*eB3)*fmaxf(v3,v2);          \
    float w4v=(n4*eB4)*fmaxf(v4,v3);  float w5v=(n5*eB5)*fmaxf(v5,v4);          \
    float w6v=(n6*eB6)*fmaxf(v6,v5);  float w7v=(n7*eB7)*fmaxf(v7,v6);          \
    m0=n0;m1=n1;m2=n2;m3=n3;m4=n4;m5=n5;m6=n6;m7=n7;                            \
    v0=w0v;v1=w1v;v2=w2v;v3=w3v;v4=w4v;v5=w5v;v6=w6v;v7=w7v;                    \
    if ((TT) == wexp) { wex = __shfl(m0, 4 * c); wio = ioffM; }                 \
} while (0)

#define RENORM_MI() do {                                                        \
    float mx_ = fmaxf(fmaxf(fmaxf(m0,m1),fmaxf(m2,m3)),                         \
                      fmaxf(fmaxf(m4,m5),fmaxf(m6,m7)));                        \
    mx_ = fmaxf(mx_, __shfl_xor(mx_, 1));  mx_ = fmaxf(mx_, __shfl_xor(mx_, 2));\
    mx_ = fmaxf(mx_, __shfl_xor(mx_, 4));  mx_ = fmaxf(mx_, __shfl_xor(mx_, 8));\
    mx_ = fmaxf(mx_, __shfl_xor(mx_, 16)); mx_ = fmaxf(mx_, __shfl_xor(mx_, 32));\
    int eb_ = (__float_as_int(mx_) >> 23) & 255;                                \
    float sc_ = (eb_ > 0) ? __int_as_float((254 - eb_) << 23) : 1.0f;           \
    if (eb_ > 0) ioffM += eb_ - 127;                                            \
    m0*=sc_; m1*=sc_; m2*=sc_; m3*=sc_; m4*=sc_; m5*=sc_; m6*=sc_; m7*=sc_;     \
} while (0)

#define RENORM_VR() do {                                                        \
    float mx_ = fmaxf(fmaxf(fmaxf(v0,v1),fmaxf(v2,v3)),                         \
                      fmaxf(fmaxf(v4,v5),fmaxf(v6,v7)));                        \
    mx_ = fmaxf(mx_, __shfl_xor(mx_, 1));  mx_ = fmaxf(mx_, __shfl_xor(mx_, 2));\
    mx_ = fmaxf(mx_, __shfl_xor(mx_, 4));  mx_ = fmaxf(mx_, __shfl_xor(mx_, 8));\
    mx_ = fmaxf(mx_, __shfl_xor(mx_, 16)); mx_ = fmaxf(mx_, __shfl_xor(mx_, 32));\
    int eb_ = (__float_as_int(mx_) >> 23) & 255;                                \
    float sc_ = (eb_ > 0) ? __int_as_float((254 - eb_) << 23) : 0.0f;           \
    float ad_ = (eb_ > 0) ? 0.f : 1.f;                                          \
    v0=fmaf(v0,sc_,ad_); v1=fmaf(v1,sc_,ad_); v2=fmaf(v2,sc_,ad_);              \
    v3=fmaf(v3,sc_,ad_); v4=fmaf(v4,sc_,ad_); v5=fmaf(v5,sc_,ad_);              \
    v6=fmaf(v6,sc_,ad_); v7=fmaf(v7,sc_,ad_);                                   \
} while (0)

__global__ __launch_bounds__(64) void k_vit(const u16* __restrict__ P,
                                            const u16* __restrict__ Bt,
                                            u64* __restrict__ mbg,
                                            float* __restrict__ elog,
                                            float* __restrict__ wlg) {
    const int l = threadIdx.x, l8 = l * 8;
    const int b = blockIdx.x >> 4, c = blockIdx.x & 15;
    const int w0 = c * 64, tend = w0 + 63;
    const int t0 = (w0 >= 128) ? (w0 - 128) : 0;
    const int wexp = w0 - 1;
    const u16* Pb  = P  + (size_t)b * T_ * S_;
    const u16* Btb = Bt + (size_t)b * T_ * S_;
    u64* mrow = mbg + (size_t)b * 8192;

    float m0,m1,m2,m3,m4,m5,m6,m7, v0,v1,v2,v3,v4,v5,v6,v7;
    int ioffM = 0;
    float wex = 1.f; int wio = 0;
    {
        uint4 qp = PROW(t0); UNPK(qp, eP);
        uint4 qb = BROW(t0); UNPK(qb, eB);
        if (t0 == 0) {   // exact init (c <= 2)
            m0 = (l == 0) ? eP0 : 0.f;
            m1 = 0.f; m2 = 0.f; m3 = 0.f; m4 = 0.f; m5 = 0.f; m6 = 0.f; m7 = 0.f;
        } else {
            m0 = eP0; m1 = eP1; m2 = eP2; m3 = eP3;
            m4 = eP4; m5 = eP5; m6 = eP6; m7 = eP7;
        }
        v0 = m0*eB0; v1 = m1*eB1; v2 = m2*eB2; v3 = m3*eB3;
        v4 = m4*eB4; v5 = m5*eB5; v6 = m6*eB6; v7 = m7*eB7;
    }
    u64 acc = 0ULL;
    const int cnt = tend - t0;        // 191 / 127 / 63 -> tail always 7
    int t = t0 + 1;
    uint4 p0=PROW(t+0), p1=PROW(t+1), p2=PROW(t+2), p3=PROW(t+3);
    uint4 p4=PROW(t+4), p5=PROW(t+5), p6=PROW(t+6), p7=PROW(t+7);
    uint4 g0=BROW(t+0), g1=BROW(t+1), g2=BROW(t+2), g3=BROW(t+3);
    uint4 g4=BROW(t+4), g5=BROW(t+5), g6=BROW(t+6), g7=BROW(t+7);
    const int nb = cnt >> 3;
    for (int blk = 0; blk < nb; ++blk, t += 8) {
        VSTEPL(t + 0, p0, g0);
        VSTEPL(t + 1, p1, g1);
        VSTEPL(t + 2, p2, g2);
        VSTEPL(t + 3, p3, g3);
        VSTEPL(t + 4, p4, g4);
        VSTEPL(t + 5, p5, g5);
        VSTEPL(t + 6, p6, g6);
        VSTEPL(t + 7, p7, g7);
        RENORM_MI();
        RENORM_VR();
    }
    // tail = 7 steps (slots preloaded)
    VSTEPL(t + 0, p0, g0);
    VSTEPL(t + 1, p1, g1);
    VSTEPL(t + 2, p2, g2);
    VSTEPL(t + 3, p3, g3);
    VSTEPL(t + 4, p4, g4);
    VSTEPL(t + 5, p5, g5);
    VSTEPL(t + 6, p6, g6);

    float eex = (c == 15) ? __shfl(m7, 63) : __shfl(m0, 4 * (c + 1));
    if (l == 0) {
        elog[b * 16 + c] = __builtin_amdgcn_logf(fmaxf(eex, 1e-35f)) + (float)ioffM;
        if (c >= 1)
            wlg[b * 16 + c] = __builtin_amdgcn_logf(fmaxf(wex, 1e-35f)) + (float)wio;
    }
}

// ---------------------------------------------------------------------------
// K6: backtrace.
__global__ __launch_bounds__(256) void k_btr(const u64* __restrict__ mbg,
                                             int* __restrict__ js) {
    __shared__ u64 mb[128][64];
    const int b = blockIdx.x, tid = threadIdx.x;
    const uint4* src = (const uint4*)(mbg + (size_t)b * 8192);
    uint4* dst = (uint4*)&mb[0][0];
    for (int i = tid; i < 4096; i += 256) dst[i] = src[i];
    __syncthreads();
    if (tid >= 64) return;
    const int l = tid;
    int jj = S_ - 1;
    if (l == 0) js[b * T_ + T_ - 1] = jj;
    u64 wcur = mb[127][l];
    for (int tau = 127; tau >= 0; --tau) {
        u64 wv = wcur;
        if (tau > 0) wcur = mb[tau - 1][l];
        for (int i = 7; i >= 0; --i) {
            int t = tau * 8 + i;
            if (t == 0) break;
            u64 word = __shfl(wv, jj >> 3);
            int bit = (int)((word >> ((t & 7) * 8 + (jj & 7))) & 1ULL);
            jj -= bit;
            if (l == 0) js[b * T_ + t - 1] = jj;
        }
    }
}

// ---------------------------------------------------------------------------
// K7: one-hot path writer.
__global__ void k_path(const int* __restrict__ js, float* __restrict__ outp) {
    const size_t total4 = (size_t)B_ * T_ * S_ / 4;
    float4* O = (float4*)outp;
    for (size_t i = (size_t)blockIdx.x * blockDim.x + threadIdx.x; i < total4;
         i += (size_t)gridDim.x * blockDim.x) {
        size_t base = i * 4;
        int s = (int)(base & (S_ - 1));
        int row = (int)(base >> 9);
        int jt = js[row];
        float4 o;
        o.x = (s == jt) ? 1.f : 0.f;
        o.y = (s + 1 == jt) ? 1.f : 0.f;
        o.z = (s + 2 == jt) ? 1.f : 0.f;
        o.w = (s + 3 == jt) ? 1.f : 0.f;
        O[i] = o;
    }
}

// ---------------------------------------------------------------------------
// K8: logprobs (mu_N via 16-chunk delta chain; 4^-t prefactors cancel).
__global__ __launch_bounds__(256) void k_final(const u16* __restrict__ P,
                                               const int* __restrict__ js,
                                               const float* __restrict__ lp_part,
                                               const int* __restrict__ tlen,
                                               const float* __restrict__ elog,
                                               const float* __restrict__ wlg,
                                               float* __restrict__ out_lp) {
    const int b = blockIdx.x;
    float acc = 0.f;
    for (int t = threadIdx.x; t < T_; t += 256) {
        int jt = js[b * T_ + t];
        unsigned u = P[((size_t)b * T_ + t) * S_ + jt];
        acc += __builtin_amdgcn_logf(__uint_as_float(u << 16));   // log2(P_hat)
    }
    __shared__ float red[256];
    red[threadIdx.x] = acc;
    __syncthreads();
    for (int o = 128; o > 0; o >>= 1) {
        if (threadIdx.x < o) red[threadIdx.x] += red[threadIdx.x + o];
        __syncthreads();
    }
    if (threadIdx.x == 0) {
        float basep = 0.f;
        for (int i = 0; i < 48; ++i) basep += lp_part[b * 48 + i];
        float mu2n = elog[b * 16 + 15];
        for (int cc = 1; cc < 16; ++cc)
            mu2n += elog[b * 16 + cc - 1] - wlg[b * 16 + cc];
        out_lp[b] = basep - HALF_LOG_2PI * ((float)tlen[b] * C_)
                    + LN2F * (red[0] - mu2n);
    }
}

// ---------------------------------------------------------------------------
extern "C" void kernel_launch(void* const* d_in, const int* in_sizes, int n_in,
                              void* d_out, int out_size, void* d_ws, size_t ws_size,
                              hipStream_t stream) {
    const float* eps  = (const float*)d_in[0];
    const float* cond = (const float*)d_in[1];
    const int* tlen   = (const int*)d_in[2];

    float* out_path = (float*)d_out;
    float* out_lp   = out_path + (size_t)B_ * T_ * S_;

    const size_t NBTS = (size_t)B_ * T_ * S_;
    char* w = (char*)d_ws;
    float* Wr   = (float*)w;                          // 67 MB f32 logits
    u16*   P    = (u16*)(Wr + NBTS);                  // 34 MB bf16 exp(W)/4
    u16*   Bt   = P + NBTS;                           // 34 MB bf16 linear beta
    u16*   Abf  = Bt + NBTS;                          // 25 MB bf16 eps
    u16*   Bbf  = Abf + (size_t)B_ * T_ * C_;         // 13 MB bf16 cond
    u64*   mbg  = (u64*)(Bbf + (size_t)B_ * S_ * C_); // 2 MB move bits
    float* pmax = (float*)(mbg + (size_t)B_ * 8192);
    float* psum = pmax + (size_t)4 * B_ * S_;
    float* cmax = psum + (size_t)4 * B_ * S_;
    float* cinv = cmax + (size_t)B_ * S_;
    float* lp_part = cinv + (size_t)B_ * S_;
    float* elog = lp_part + B_ * 48;                  // B*16
    float* wlg  = elog + B_ * 16;                     // B*16
    int*   js   = (int*)(wlg + B_ * 16);

    k_eps<<<B_ * 48, 256, 0, stream>>>(eps, tlen, lp_part, Abf);
    k_cvt<<<1024, 256, 0, stream>>>(cond, Bbf);
    k_gemm<<<dim3(S_ / 128, T_ / 128, B_), 256, 0, stream>>>(Abf, Bbf, Wr);
    k_stats1<<<B_ * 2 * 4, 256, 0, stream>>>(Wr, pmax, psum);
    k_stats2<<<B_ * S_ / 256, 256, 0, stream>>>(pmax, psum, cmax, cinv);
    k_pack<<<2048, 256, 0, stream>>>(Wr, cmax, cinv, P);
    k_beta<<<B_ * 16, 64, 0, stream>>>(P, Bt);
    k_vit<<<B_ * 16, 64, 0, stream>>>(P, Bt, mbg, elog, wlg);
    k_btr<<<B_, 256, 0, stream>>>(mbg, js);
    k_path<<<4096, 256, 0, stream>>>(js, out_path);
    k_final<<<B_, 256, 0, stream>>>(P, js, lp_part, tlen, elog, wlg, out_lp);
}

// Round 7
// 269.837 us; speedup vs baseline: 6.3922x; 1.0962x over previous
//
#include <hip/hip_runtime.h>
#include <cstdint>
#include <cstddef>

#define B_ 32
#define T_ 1024
#define S_ 512
#define C_ 384
#define HALF_LOG_2PI 0.91893853320467274178f
#define LN2F 0.69314718055994530942f
#define INV_LN2F 1.44269504088896340736f

typedef unsigned short u16;
typedef unsigned long long u64;
typedef __attribute__((ext_vector_type(8))) short bf16x8;
typedef __attribute__((ext_vector_type(4))) float f32x4;

__device__ __forceinline__ unsigned rne16(float f) {   // f32 -> bf16 bits (RNE)
    unsigned b = __float_as_uint(f);
    return (b + 0x7FFFu + ((b >> 16) & 1u)) >> 16;
}
__device__ __forceinline__ uint4 pack8f(float a0, float a1, float a2, float a3,
                                        float a4, float a5, float a6, float a7) {
    uint4 q;
    q.x = rne16(a0) | (rne16(a1) << 16);
    q.y = rne16(a2) | (rne16(a3) << 16);
    q.z = rne16(a4) | (rne16(a5) << 16);
    q.w = rne16(a6) | (rne16(a7) << 16);
    return q;
}
#define UNPK(q, p)                                                              \
    float p##0 = __uint_as_float((q).x << 16),                                  \
          p##1 = __uint_as_float((q).x & 0xFFFF0000u),                          \
          p##2 = __uint_as_float((q).y << 16),                                  \
          p##3 = __uint_as_float((q).y & 0xFFFF0000u),                          \
          p##4 = __uint_as_float((q).z << 16),                                  \
          p##5 = __uint_as_float((q).z & 0xFFFF0000u),                          \
          p##6 = __uint_as_float((q).w << 16),                                  \
          p##7 = __uint_as_float((q).w & 0xFFFF0000u)

#define PROW(t) (*(const uint4*)(Pb  + (size_t)(t) * S_ + l8))
#define BROW(t) (*(const uint4*)(Btb + (size_t)(t) * S_ + l8))

#define RENORM8(r0,r1,r2,r3,r4,r5,r6,r7) do {                                   \
    float mx_ = fmaxf(fmaxf(fmaxf(r0,r1),fmaxf(r2,r3)),                         \
                      fmaxf(fmaxf(r4,r5),fmaxf(r6,r7)));                        \
    mx_ = fmaxf(mx_, __shfl_xor(mx_, 1));  mx_ = fmaxf(mx_, __shfl_xor(mx_, 2));\
    mx_ = fmaxf(mx_, __shfl_xor(mx_, 4));  mx_ = fmaxf(mx_, __shfl_xor(mx_, 8));\
    mx_ = fmaxf(mx_, __shfl_xor(mx_, 16)); mx_ = fmaxf(mx_, __shfl_xor(mx_, 32));\
    int eb_ = (__float_as_int(mx_) >> 23) & 255;                                \
    float sc_ = (eb_ > 0) ? __int_as_float((254 - eb_) << 23) : 1.0f;           \
    r0*=sc_; r1*=sc_; r2*=sc_; r3*=sc_; r4*=sc_; r5*=sc_; r6*=sc_; r7*=sc_;     \
} while (0)

// ---------------------------------------------------------------------------
// K0a: eps -> bf16 (unmasked) + masked -0.5*sum(eps^2) partials.
__global__ __launch_bounds__(256) void k_eps(const float* __restrict__ eps,
                                             const int* __restrict__ tlen,
                                             float* __restrict__ lp_part,
                                             u16* __restrict__ Abf) {
    const int b = blockIdx.x / 48, chunk = blockIdx.x % 48;
    const int len = tlen[b];
    const float* base = eps + (size_t)b * T_ * C_ + (size_t)chunk * 8192;
    u16* obase = Abf + (size_t)b * T_ * C_ + (size_t)chunk * 8192;
    float acc = 0.f;
    for (int g = threadIdx.x; g < 1024; g += 256) {
        float4 v0 = *(const float4*)(base + g * 8);
        float4 v1 = *(const float4*)(base + g * 8 + 4);
        int t = (chunk * 8192 + g * 8) / C_;
        if (t < len)
            acc += v0.x*v0.x + v0.y*v0.y + v0.z*v0.z + v0.w*v0.w
                 + v1.x*v1.x + v1.y*v1.y + v1.z*v1.z + v1.w*v1.w;
        *(uint4*)(obase + g * 8) = pack8f(v0.x, v0.y, v0.z, v0.w,
                                          v1.x, v1.y, v1.z, v1.w);
    }
    __shared__ float red[256];
    red[threadIdx.x] = acc;
    __syncthreads();
    for (int o = 128; o > 0; o >>= 1) {
        if (threadIdx.x < o) red[threadIdx.x] += red[threadIdx.x + o];
        __syncthreads();
    }
    if (threadIdx.x == 0) lp_part[blockIdx.x] = -0.5f * red[0];
}

// K0b: cond -> bf16.
__global__ __launch_bounds__(256) void k_cvt(const float* __restrict__ src,
                                             u16* __restrict__ dst) {
    const size_t n8 = (size_t)B_ * S_ * C_ / 8;
    for (size_t i = (size_t)blockIdx.x * 256 + threadIdx.x; i < n8;
         i += (size_t)gridDim.x * 256) {
        float4 v0 = *(const float4*)(src + i * 8);
        float4 v1 = *(const float4*)(src + i * 8 + 4);
        *(uint4*)(dst + i * 8) = pack8f(v0.x, v0.y, v0.z, v0.w,
                                        v1.x, v1.y, v1.z, v1.w);
    }
}

// ---------------------------------------------------------------------------
// K1: bf16 MFMA GEMM -> bf16 logits Wb. 128x128 tile, 4 waves, BK=32.
__global__ __launch_bounds__(256) void k_gemm(const u16* __restrict__ A,
                                              const u16* __restrict__ Bc,
                                              u16* __restrict__ Wb) {
    __shared__ u16 Al[4096];
    __shared__ u16 Bl[4096];
    const int b  = blockIdx.z;
    const int m0 = blockIdx.y * 128;
    const int n0 = blockIdx.x * 128;
    const int tid = threadIdx.x;
    const int lane = tid & 63, wid = tid >> 6;
    const int wy = wid >> 1, wx = wid & 1;
    const int r15 = lane & 15, kg = lane >> 4;
    const u16* Ab = A  + (size_t)b * T_ * C_;
    const u16* Bb = Bc + (size_t)b * S_ * C_;

    f32x4 acc[4][4];
#pragma unroll
    for (int i = 0; i < 4; ++i)
#pragma unroll
        for (int j = 0; j < 4; ++j) acc[i][j] = (f32x4){0.f, 0.f, 0.f, 0.f};

    const int g1 = tid + 256;
    const int row0 = tid >> 2, o0 = tid & 3;
    const int row1 = g1 >> 2,  o1 = g1 & 3;
    const int wb0 = (row0 * 64 + o0 * 16) ^ (((row0 >> 1) & 7) << 4);
    const int wb1 = (row1 * 64 + o1 * 16) ^ (((row1 >> 1) & 7) << 4);
    const int rswz = ((r15 >> 1) & 7) << 4;

    for (int k0 = 0; k0 < C_; k0 += 32) {
        uint4 a0 = *(const uint4*)(Ab + (size_t)(m0 + row0) * C_ + k0 + o0 * 8);
        uint4 a1 = *(const uint4*)(Ab + (size_t)(m0 + row1) * C_ + k0 + o1 * 8);
        uint4 c0 = *(const uint4*)(Bb + (size_t)(n0 + row0) * C_ + k0 + o0 * 8);
        uint4 c1 = *(const uint4*)(Bb + (size_t)(n0 + row1) * C_ + k0 + o1 * 8);
        __syncthreads();
        *(uint4*)((char*)Al + wb0) = a0;
        *(uint4*)((char*)Al + wb1) = a1;
        *(uint4*)((char*)Bl + wb0) = c0;
        *(uint4*)((char*)Bl + wb1) = c1;
        __syncthreads();
        bf16x8 af[4], bfb[4];
#pragma unroll
        for (int ar = 0; ar < 4; ++ar) {
            int row = wy * 64 + ar * 16 + r15;
            af[ar] = *(const bf16x8*)((const char*)Al + ((row * 64 + kg * 16) ^ rswz));
        }
#pragma unroll
        for (int bc = 0; bc < 4; ++bc) {
            int row = wx * 64 + bc * 16 + r15;
            bfb[bc] = *(const bf16x8*)((const char*)Bl + ((row * 64 + kg * 16) ^ rswz));
        }
#pragma unroll
        for (int ar = 0; ar < 4; ++ar)
#pragma unroll
            for (int bc = 0; bc < 4; ++bc)
                acc[ar][bc] = __builtin_amdgcn_mfma_f32_16x16x32_bf16(
                    af[ar], bfb[bc], acc[ar][bc], 0, 0, 0);
    }
#pragma unroll
    for (int ar = 0; ar < 4; ++ar) {
        int t = m0 + wy * 64 + ar * 16 + kg * 4;
#pragma unroll
        for (int bc = 0; bc < 4; ++bc) {
            int s = n0 + wx * 64 + bc * 16 + r15;
            u16* dst = Wb + ((size_t)b * T_ + t) * S_ + s;
#pragma unroll
            for (int r = 0; r < 4; ++r) dst[(size_t)r * S_] = (u16)rne16(acc[ar][bc][r]);
        }
    }
}

// ---------------------------------------------------------------------------
// K2a/K2b: column softmax stats over t (bf16 logits in).
__global__ __launch_bounds__(256) void k_stats1(const u16* __restrict__ Wb,
                                                float* __restrict__ pmax,
                                                float* __restrict__ psum) {
    const int c  = blockIdx.x & 3;
    const int bh = blockIdx.x >> 2;
    const int b  = bh >> 1;
    const int s  = ((bh & 1) << 8) + threadIdx.x;
    const u16* col = Wb + (size_t)b * T_ * S_ + (size_t)c * 256 * S_ + s;
    float m = -3.0e38f, sum = 0.f;
    for (int t = 0; t < 256; t += 4) {
        float x0 = __uint_as_float((unsigned)col[(size_t)(t + 0) * S_] << 16);
        float x1 = __uint_as_float((unsigned)col[(size_t)(t + 1) * S_] << 16);
        float x2 = __uint_as_float((unsigned)col[(size_t)(t + 2) * S_] << 16);
        float x3 = __uint_as_float((unsigned)col[(size_t)(t + 3) * S_] << 16);
        float nm = fmaxf(fmaxf(fmaxf(fmaxf(m, x0), x1), x2), x3);
        sum = sum * expf(m - nm) + expf(x0 - nm) + expf(x1 - nm)
            + expf(x2 - nm) + expf(x3 - nm);
        m = nm;
    }
    pmax[(size_t)c * B_ * S_ + b * S_ + s] = m;
    psum[(size_t)c * B_ * S_ + b * S_ + s] = sum;
}

__global__ __launch_bounds__(256) void k_stats2(const float* __restrict__ pmax,
                                                const float* __restrict__ psum,
                                                float* __restrict__ cmax,
                                                float* __restrict__ cinv) {
    const int i = blockIdx.x * 256 + threadIdx.x;
    float m0 = pmax[i], m1 = pmax[(size_t)B_ * S_ + i];
    float m2 = pmax[(size_t)2 * B_ * S_ + i], m3 = pmax[(size_t)3 * B_ * S_ + i];
    float m = fmaxf(fmaxf(m0, m1), fmaxf(m2, m3));
    float s = psum[i] * expf(m0 - m)
            + psum[(size_t)B_ * S_ + i] * expf(m1 - m)
            + psum[(size_t)2 * B_ * S_ + i] * expf(m2 - m)
            + psum[(size_t)3 * B_ * S_ + i] * expf(m3 - m);
    cmax[i] = m;
    cinv[i] = 1.0f / s;
}

// ---------------------------------------------------------------------------
// K3: P_hat = exp(softmax(Wb,axis=T)) / 4, bf16.
__global__ __launch_bounds__(256) void k_pack(const u16* __restrict__ Wb,
                                              const float* __restrict__ cmax,
                                              const float* __restrict__ cinv,
                                              u16* __restrict__ P) {
    const size_t total8 = (size_t)B_ * T_ * S_ / 8;
    for (size_t i = (size_t)blockIdx.x * 256 + threadIdx.x; i < total8;
         i += (size_t)gridDim.x * 256) {
        size_t base = i * 8;
        int s = (int)(base & (S_ - 1));
        int b = (int)(base >> 19);
        uint4 xq = *(const uint4*)(Wb + base);
        UNPK(xq, x);
        float4 mA = *(const float4*)(cmax + (size_t)b * S_ + s);
        float4 mB = *(const float4*)(cmax + (size_t)b * S_ + s + 4);
        float4 iA = *(const float4*)(cinv + (size_t)b * S_ + s);
        float4 iB = *(const float4*)(cinv + (size_t)b * S_ + s + 4);
        float w0 = __builtin_amdgcn_exp2f(fmaf(x0, INV_LN2F, -mA.x * INV_LN2F)) * iA.x;
        float w1 = __builtin_amdgcn_exp2f(fmaf(x1, INV_LN2F, -mA.y * INV_LN2F)) * iA.y;
        float w2 = __builtin_amdgcn_exp2f(fmaf(x2, INV_LN2F, -mA.z * INV_LN2F)) * iA.z;
        float w3 = __builtin_amdgcn_exp2f(fmaf(x3, INV_LN2F, -mA.w * INV_LN2F)) * iA.w;
        float w4 = __builtin_amdgcn_exp2f(fmaf(x4, INV_LN2F, -mB.x * INV_LN2F)) * iB.x;
        float w5 = __builtin_amdgcn_exp2f(fmaf(x5, INV_LN2F, -mB.y * INV_LN2F)) * iB.y;
        float w6 = __builtin_amdgcn_exp2f(fmaf(x6, INV_LN2F, -mB.z * INV_LN2F)) * iB.z;
        float w7 = __builtin_amdgcn_exp2f(fmaf(x7, INV_LN2F, -mB.w * INV_LN2F)) * iB.w;
        float p0 = __builtin_amdgcn_exp2f(fmaf(w0, INV_LN2F, -2.0f));
        float p1 = __builtin_amdgcn_exp2f(fmaf(w1, INV_LN2F, -2.0f));
        float p2 = __builtin_amdgcn_exp2f(fmaf(w2, INV_LN2F, -2.0f));
        float p3 = __builtin_amdgcn_exp2f(fmaf(w3, INV_LN2F, -2.0f));
        float p4 = __builtin_amdgcn_exp2f(fmaf(w4, INV_LN2F, -2.0f));
        float p5 = __builtin_amdgcn_exp2f(fmaf(w5, INV_LN2F, -2.0f));
        float p6 = __builtin_amdgcn_exp2f(fmaf(w6, INV_LN2F, -2.0f));
        float p7 = __builtin_amdgcn_exp2f(fmaf(w7, INV_LN2F, -2.0f));
        *(uint4*)(P + base) = pack8f(p0, p1, p2, p3, p4, p5, p6, p7);
    }
}

// ---------------------------------------------------------------------------
// K4: backward DP, linear domain, 16 chunks of 64 (warm 128), ring-32.
#define BSTEPL(tt, Q) do {                                                      \
    UNPK(Q, eP);                                                                \
    if ((tt) >= w0 + 32) Q = PROW((tt) - 31);                                   \
    float z0=m0*eP0, z1=m1*eP1, z2=m2*eP2, z3=m3*eP3;                           \
    float z4=m4*eP4, z5=m5*eP5, z6=m6*eP6, z7=m7*eP7;                           \
    float rt = __shfl_down(z0, 1); if (l == 63) rt = 0.f;                       \
    m0=z0+z1; m1=z1+z2; m2=z2+z3; m3=z3+z4;                                     \
    m4=z4+z5; m5=z5+z6; m6=z6+z7; m7=z7+rt;                                     \
    if ((tt) < w0 + 64) {                                                       \
        uint4 st;                                                               \
        asm("v_cvt_pk_bf16_f32 %0, %1, %2" : "=v"(st.x) : "v"(m0), "v"(m1));    \
        asm("v_cvt_pk_bf16_f32 %0, %1, %2" : "=v"(st.y) : "v"(m2), "v"(m3));    \
        asm("v_cvt_pk_bf16_f32 %0, %1, %2" : "=v"(st.z) : "v"(m4), "v"(m5));    \
        asm("v_cvt_pk_bf16_f32 %0, %1, %2" : "=v"(st.w) : "v"(m6), "v"(m7));    \
        *(uint4*)(Bb + (size_t)(tt) * S_ + l8) = st;                            \
    }                                                                           \
} while (0)

__global__ __launch_bounds__(64) void k_beta(const u16* __restrict__ P,
                                             u16* __restrict__ Bt) {
    const int l = threadIdx.x, l8 = l * 8;
    const int b = blockIdx.x >> 4, c = blockIdx.x & 15;
    const int w0 = c * 64;
    const u16* Pb = P  + (size_t)b * T_ * S_;
    u16*      Bb = Bt + (size_t)b * T_ * S_;
    float m0, m1, m2, m3, m4, m5, m6, m7;
    int te = w0 + 191;
    if (te > 1023) te = 1023;
    if (te == 1023) {
        m0 = m1 = m2 = m3 = m4 = m5 = m6 = 0.f;
        m7 = (l == 63) ? 1.f : 0.f;
        if (1023 < w0 + 64) {
            uint4 st;
            asm("v_cvt_pk_bf16_f32 %0, %1, %2" : "=v"(st.x) : "v"(m0), "v"(m1));
            asm("v_cvt_pk_bf16_f32 %0, %1, %2" : "=v"(st.y) : "v"(m2), "v"(m3));
            asm("v_cvt_pk_bf16_f32 %0, %1, %2" : "=v"(st.z) : "v"(m4), "v"(m5));
            asm("v_cvt_pk_bf16_f32 %0, %1, %2" : "=v"(st.w) : "v"(m6), "v"(m7));
            *(uint4*)(Bb + (size_t)1023 * S_ + l8) = st;
        }
    } else {
        m0 = m1 = m2 = m3 = m4 = m5 = m6 = m7 = 1.f;
    }
    const int cnt = te - w0;          // 191/127/63 -> tail 31
    uint4 q00=PROW(te-0),  q01=PROW(te-1),  q02=PROW(te-2),  q03=PROW(te-3);
    uint4 q04=PROW(te-4),  q05=PROW(te-5),  q06=PROW(te-6),  q07=PROW(te-7);
    uint4 q08=PROW(te-8),  q09=PROW(te-9),  q10=PROW(te-10), q11=PROW(te-11);
    uint4 q12=PROW(te-12), q13=PROW(te-13), q14=PROW(te-14), q15=PROW(te-15);
    uint4 q16=PROW(te-16), q17=PROW(te-17), q18=PROW(te-18), q19=PROW(te-19);
    uint4 q20=PROW(te-20), q21=PROW(te-21), q22=PROW(te-22), q23=PROW(te-23);
    uint4 q24=PROW(te-24), q25=PROW(te-25), q26=PROW(te-26), q27=PROW(te-27);
    uint4 q28=PROW(te-28), q29=PROW(te-29), q30=PROW(te-30), q31=PROW(te-31);
    int tt = te - 1;
    const int nb = cnt >> 5;
    for (int blk = 0; blk < nb; ++blk, tt -= 32) {
        BSTEPL(tt-0,  q00); BSTEPL(tt-1,  q01); BSTEPL(tt-2,  q02); BSTEPL(tt-3,  q03);
        BSTEPL(tt-4,  q04); BSTEPL(tt-5,  q05); BSTEPL(tt-6,  q06); BSTEPL(tt-7,  q07);
        RENORM8(m0, m1, m2, m3, m4, m5, m6, m7);
        BSTEPL(tt-8,  q08); BSTEPL(tt-9,  q09); BSTEPL(tt-10, q10); BSTEPL(tt-11, q11);
        BSTEPL(tt-12, q12); BSTEPL(tt-13, q13); BSTEPL(tt-14, q14); BSTEPL(tt-15, q15);
        RENORM8(m0, m1, m2, m3, m4, m5, m6, m7);
        BSTEPL(tt-16, q16); BSTEPL(tt-17, q17); BSTEPL(tt-18, q18); BSTEPL(tt-19, q19);
        BSTEPL(tt-20, q20); BSTEPL(tt-21, q21); BSTEPL(tt-22, q22); BSTEPL(tt-23, q23);
        RENORM8(m0, m1, m2, m3, m4, m5, m6, m7);
        BSTEPL(tt-24, q24); BSTEPL(tt-25, q25); BSTEPL(tt-26, q26); BSTEPL(tt-27, q27);
        BSTEPL(tt-28, q28); BSTEPL(tt-29, q29); BSTEPL(tt-30, q30); BSTEPL(tt-31, q31);
        RENORM8(m0, m1, m2, m3, m4, m5, m6, m7);
    }
    // tail = 31 steps (slots preloaded)
    BSTEPL(tt-0,  q00); BSTEPL(tt-1,  q01); BSTEPL(tt-2,  q02); BSTEPL(tt-3,  q03);
    BSTEPL(tt-4,  q04); BSTEPL(tt-5,  q05); BSTEPL(tt-6,  q06); BSTEPL(tt-7,  q07);
    RENORM8(m0, m1, m2, m3, m4, m5, m6, m7);
    BSTEPL(tt-8,  q08); BSTEPL(tt-9,  q09); BSTEPL(tt-10, q10); BSTEPL(tt-11, q11);
    BSTEPL(tt-12, q12); BSTEPL(tt-13, q13); BSTEPL(tt-14, q14); BSTEPL(tt-15, q15);
    RENORM8(m0, m1, m2, m3, m4, m5, m6, m7);
    BSTEPL(tt-16, q16); BSTEPL(tt-17, q17); BSTEPL(tt-18, q18); BSTEPL(tt-19, q19);
    BSTEPL(tt-20, q20); BSTEPL(tt-21, q21); BSTEPL(tt-22, q22); BSTEPL(tt-23, q23);
    RENORM8(m0, m1, m2, m3, m4, m5, m6, m7);
    BSTEPL(tt-24, q24); BSTEPL(tt-25, q25); BSTEPL(tt-26, q26); BSTEPL(tt-27, q27);
    BSTEPL(tt-28, q28); BSTEPL(tt-29, q29); BSTEPL(tt-30, q30);
}

// ---------------------------------------------------------------------------
// K5: fused mu-forward + Viterbi, linear domain, ring-16 x 2 streams.
#define VSTEPL(TT, QP, QB) do {                                                 \
    UNPK(QP, eP); UNPK(QB, eB);                                                 \
    if ((TT) + 16 <= tend) { QP = PROW((TT) + 16); QB = BROW((TT) + 16); }      \
    float lf = __shfl_up(m7, 1); if (l == 0) lf = 0.f;                          \
    float n0 = eP0*(m0+lf); float n1 = eP1*(m1+m0);                             \
    float n2 = eP2*(m2+m1); float n3 = eP3*(m3+m2);                             \
    float n4 = eP4*(m4+m3); float n5 = eP5*(m5+m4);                             \
    float n6 = eP6*(m6+m5); float n7 = eP7*(m7+m6);                             \
    float vlf = __shfl_up(v7, 1); if (l == 0) vlf = 0.f;                        \
    if ((TT) >= w0) {                                                           \
        unsigned cc0=(vlf>v0)?1u:0u, cc1=(v0>v1)?2u:0u, cc2=(v1>v2)?4u:0u,      \
                 cc3=(v2>v3)?8u:0u,  cc4=(v3>v4)?16u:0u, cc5=(v4>v5)?32u:0u,    \
                 cc6=(v5>v6)?64u:0u, cc7=(v6>v7)?128u:0u;                       \
        acc |= ((u64)(cc0|cc1|cc2|cc3|cc4|cc5|cc6|cc7)) << (((TT)&7)*8);        \
        if (((TT)&7) == 7) { mrow[((TT)>>3)*64 + l] = acc; acc = 0ULL; }        \
    }                                                                           \
    float w0v=(n0*eB0)*fmaxf(v0,vlf); float w1v=(n1*eB1)*fmaxf(v1,v0);          \
    float w2v=(n2*eB2)*fmaxf(v2,v1);  float w3v=(n3*eB3)*fmaxf(v3,v2);          \
    float w4v=(n4*eB4)*fmaxf(v4,v3);  float w5v=(n5*eB5)*fmaxf(v5,v4);          \
    float w6v=(n6*eB6)*fmaxf(v6,v5);  float w7v=(n7*eB7)*fmaxf(v7,v6);          \
    m0=n0;m1=n1;m2=n2;m3=n3;m4=n4;m5=n5;m6=n6;m7=n7;                            \
    v0=w0v;v1=w1v;v2=w2v;v3=w3v;v4=w4v;v5=w5v;v6=w6v;v7=w7v;                    \
    if ((TT) == wexp) { wex = __shfl(m0, 4 * c); wio = ioffM; }                 \
} while (0)

#define RENORM_MI() do {                                                        \
    float mx_ = fmaxf(fmaxf(fmaxf(m0,m1),fmaxf(m2,m3)),                         \
                      fmaxf(fmaxf(m4,m5),fmaxf(m6,m7)));                        \
    mx_ = fmaxf(mx_, __shfl_xor(mx_, 1));  mx_ = fmaxf(mx_, __shfl_xor(mx_, 2));\
    mx_ = fmaxf(mx_, __shfl_xor(mx_, 4));  mx_ = fmaxf(mx_, __shfl_xor(mx_, 8));\
    mx_ = fmaxf(mx_, __shfl_xor(mx_, 16)); mx_ = fmaxf(mx_, __shfl_xor(mx_, 32));\
    int eb_ = (__float_as_int(mx_) >> 23) & 255;                                \
    float sc_ = (eb_ > 0) ? __int_as_float((254 - eb_) << 23) : 1.0f;           \
    if (eb_ > 0) ioffM += eb_ - 127;                                            \
    m0*=sc_; m1*=sc_; m2*=sc_; m3*=sc_; m4*=sc_; m5*=sc_; m6*=sc_; m7*=sc_;     \
} while (0)

#define RENORM_VR() do {                                                        \
    float mx_ = fmaxf(fmaxf(fmaxf(v0,v1),fmaxf(v2,v3)),                         \
                      fmaxf(fmaxf(v4,v5),fmaxf(v6,v7)));                        \
    mx_ = fmaxf(mx_, __shfl_xor(mx_, 1));  mx_ = fmaxf(mx_, __shfl_xor(mx_, 2));\
    mx_ = fmaxf(mx_, __shfl_xor(mx_, 4));  mx_ = fmaxf(mx_, __shfl_xor(mx_, 8));\
    mx_ = fmaxf(mx_, __shfl_xor(mx_, 16)); mx_ = fmaxf(mx_, __shfl_xor(mx_, 32));\
    int eb_ = (__float_as_int(mx_) >> 23) & 255;                                \
    float sc_ = (eb_ > 0) ? __int_as_float((254 - eb_) << 23) : 0.0f;           \
    float ad_ = (eb_ > 0) ? 0.f : 1.f;                                          \
    v0=fmaf(v0,sc_,ad_); v1=fmaf(v1,sc_,ad_); v2=fmaf(v2,sc_,ad_);              \
    v3=fmaf(v3,sc_,ad_); v4=fmaf(v4,sc_,ad_); v5=fmaf(v5,sc_,ad_);              \
    v6=fmaf(v6,sc_,ad_); v7=fmaf(v7,sc_,ad_);                                   \
} while (0)

__global__ __launch_bounds__(64) void k_vit(const u16* __restrict__ P,
                                            const u16* __restrict__ Bt,
                                            u64* __restrict__ mbg,
                                            float* __restrict__ elog,
                                            float* __restrict__ wlg) {
    const int l = threadIdx.x, l8 = l * 8;
    const int b = blockIdx.x >> 4, c = blockIdx.x & 15;
    const int w0 = c * 64, tend = w0 + 63;
    const int t0 = (w0 >= 128) ? (w0 - 128) : 0;
    const int wexp = w0 - 1;
    const u16* Pb  = P  + (size_t)b * T_ * S_;
    const u16* Btb = Bt + (size_t)b * T_ * S_;
    u64* mrow = mbg + (size_t)b * 8192;

    float m0,m1,m2,m3,m4,m5,m6,m7, v0,v1,v2,v3,v4,v5,v6,v7;
    int ioffM = 0;
    float wex = 1.f; int wio = 0;
    {
        uint4 qp = PROW(t0); UNPK(qp, eP);
        uint4 qb = BROW(t0); UNPK(qb, eB);
        if (t0 == 0) {
            m0 = (l == 0) ? eP0 : 0.f;
            m1 = 0.f; m2 = 0.f; m3 = 0.f; m4 = 0.f; m5 = 0.f; m6 = 0.f; m7 = 0.f;
        } else {
            m0 = eP0; m1 = eP1; m2 = eP2; m3 = eP3;
            m4 = eP4; m5 = eP5; m6 = eP6; m7 = eP7;
        }
        v0 = m0*eB0; v1 = m1*eB1; v2 = m2*eB2; v3 = m3*eB3;
        v4 = m4*eB4; v5 = m5*eB5; v6 = m6*eB6; v7 = m7*eB7;
    }
    u64 acc = 0ULL;
    const int cnt = tend - t0;        // 191/127/63 -> tail 15
    int t = t0 + 1;
    uint4 p00=PROW(t+0),  p01=PROW(t+1),  p02=PROW(t+2),  p03=PROW(t+3);
    uint4 p04=PROW(t+4),  p05=PROW(t+5),  p06=PROW(t+6),  p07=PROW(t+7);
    uint4 p08=PROW(t+8),  p09=PROW(t+9),  p10=PROW(t+10), p11=PROW(t+11);
    uint4 p12=PROW(t+12), p13=PROW(t+13), p14=PROW(t+14), p15=PROW(t+15);
    uint4 g00=BROW(t+0),  g01=BROW(t+1),  g02=BROW(t+2),  g03=BROW(t+3);
    uint4 g04=BROW(t+4),  g05=BROW(t+5),  g06=BROW(t+6),  g07=BROW(t+7);
    uint4 g08=BROW(t+8),  g09=BROW(t+9),  g10=BROW(t+10), g11=BROW(t+11);
    uint4 g12=BROW(t+12), g13=BROW(t+13), g14=BROW(t+14), g15=BROW(t+15);
    const int nb = cnt >> 4;
    for (int blk = 0; blk < nb; ++blk, t += 16) {
        VSTEPL(t + 0,  p00, g00); VSTEPL(t + 1,  p01, g01);
        VSTEPL(t + 2,  p02, g02); VSTEPL(t + 3,  p03, g03);
        VSTEPL(t + 4,  p04, g04); VSTEPL(t + 5,  p05, g05);
        VSTEPL(t + 6,  p06, g06); VSTEPL(t + 7,  p07, g07);
        RENORM_MI();
        RENORM_VR();
        VSTEPL(t + 8,  p08, g08); VSTEPL(t + 9,  p09, g09);
        VSTEPL(t + 10, p10, g10); VSTEPL(t + 11, p11, g11);
        VSTEPL(t + 12, p12, g12); VSTEPL(t + 13, p13, g13);
        VSTEPL(t + 14, p14, g14); VSTEPL(t + 15, p15, g15);
        RENORM_MI();
        RENORM_VR();
    }
    // tail = 15 steps (slots preloaded)
    VSTEPL(t + 0,  p00, g00); VSTEPL(t + 1,  p01, g01);
    VSTEPL(t + 2,  p02, g02); VSTEPL(t + 3,  p03, g03);
    VSTEPL(t + 4,  p04, g04); VSTEPL(t + 5,  p05, g05);
    VSTEPL(t + 6,  p06, g06); VSTEPL(t + 7,  p07, g07);
    RENORM_MI();
    RENORM_VR();
    VSTEPL(t + 8,  p08, g08); VSTEPL(t + 9,  p09, g09);
    VSTEPL(t + 10, p10, g10); VSTEPL(t + 11, p11, g11);
    VSTEPL(t + 12, p12, g12); VSTEPL(t + 13, p13, g13);
    VSTEPL(t + 14, p14, g14);

    float eex = (c == 15) ? __shfl(m7, 63) : __shfl(m0, 4 * (c + 1));
    if (l == 0) {
        elog[b * 16 + c] = __builtin_amdgcn_logf(fmaxf(eex, 1e-35f)) + (float)ioffM;
        if (c >= 1)
            wlg[b * 16 + c] = __builtin_amdgcn_logf(fmaxf(wex, 1e-35f)) + (float)wio;
    }
}

// ---------------------------------------------------------------------------
// K6: backtrace. 2 shfls per 8 steps (owner lane can only be hi or hi-1).
__global__ __launch_bounds__(256) void k_btr(const u64* __restrict__ mbg,
                                             int* __restrict__ js) {
    __shared__ u64 mb[128][64];
    const int b = blockIdx.x, tid = threadIdx.x;
    const uint4* src = (const uint4*)(mbg + (size_t)b * 8192);
    uint4* dst = (uint4*)&mb[0][0];
    for (int i = tid; i < 4096; i += 256) dst[i] = src[i];
    __syncthreads();
    if (tid >= 64) return;
    const int l = tid;
    int jj = S_ - 1;
    if (l == 0) js[b * T_ + T_ - 1] = jj;
    u64 wcur = mb[127][l];
    for (int tau = 127; tau >= 0; --tau) {
        u64 wv = wcur;
        if (tau > 0) wcur = mb[tau - 1][l];
        const int hi = jj >> 3;
        u64 whi = __shfl(wv, hi);
        u64 wlo = __shfl(wv, (hi > 0) ? hi - 1 : 0);
        for (int i = 7; i >= 0; --i) {
            int t = tau * 8 + i;
            if (t == 0) break;
            u64 word = ((jj >> 3) == hi) ? whi : wlo;
            int bit = (int)((word >> ((t & 7) * 8 + (jj & 7))) & 1ULL);
            jj -= bit;
            if (l == 0) js[b * T_ + t - 1] = jj;
        }
    }
}

// ---------------------------------------------------------------------------
// K7: one-hot path writer.
__global__ void k_path(const int* __restrict__ js, float* __restrict__ outp) {
    const size_t total4 = (size_t)B_ * T_ * S_ / 4;
    float4* O = (float4*)outp;
    for (size_t i = (size_t)blockIdx.x * blockDim.x + threadIdx.x; i < total4;
         i += (size_t)gridDim.x * blockDim.x) {
        size_t base = i * 4;
        int s = (int)(base & (S_ - 1));
        int row = (int)(base >> 9);
        int jt = js[row];
        float4 o;
        o.x = (s == jt) ? 1.f : 0.f;
        o.y = (s + 1 == jt) ? 1.f : 0.f;
        o.z = (s + 2 == jt) ? 1.f : 0.f;
        o.w = (s + 3 == jt) ? 1.f : 0.f;
        O[i] = o;
    }
}

// ---------------------------------------------------------------------------
// K8: logprobs (mu_N via 16-chunk delta chain).
__global__ __launch_bounds__(256) void k_final(const u16* __restrict__ P,
                                               const int* __restrict__ js,
                                               const float* __restrict__ lp_part,
                                               const int* __restrict__ tlen,
                                               const float* __restrict__ elog,
                                               const float* __restrict__ wlg,
                                               float* __restrict__ out_lp) {
    const int b = blockIdx.x;
    float acc = 0.f;
    for (int t = threadIdx.x; t < T_; t += 256) {
        int jt = js[b * T_ + t];
        unsigned u = P[((size_t)b * T_ + t) * S_ + jt];
        acc += __builtin_amdgcn_logf(__uint_as_float(u << 16));   // log2(P_hat)
    }
    __shared__ float red[256];
    red[threadIdx.x] = acc;
    __syncthreads();
    for (int o = 128; o > 0; o >>= 1) {
        if (threadIdx.x < o) red[threadIdx.x] += red[threadIdx.x + o];
        __syncthreads();
    }
    if (threadIdx.x == 0) {
        float basep = 0.f;
        for (int i = 0; i < 48; ++i) basep += lp_part[b * 48 + i];
        float mu2n = elog[b * 16 + 15];
        for (int cc = 1; cc < 16; ++cc)
            mu2n += elog[b * 16 + cc - 1] - wlg[b * 16 + cc];
        out_lp[b] = basep - HALF_LOG_2PI * ((float)tlen[b] * C_)
                    + LN2F * (red[0] - mu2n);
    }
}

// ---------------------------------------------------------------------------
extern "C" void kernel_launch(void* const* d_in, const int* in_sizes, int n_in,
                              void* d_out, int out_size, void* d_ws, size_t ws_size,
                              hipStream_t stream) {
    const float* eps  = (const float*)d_in[0];
    const float* cond = (const float*)d_in[1];
    const int* tlen   = (const int*)d_in[2];

    float* out_path = (float*)d_out;
    float* out_lp   = out_path + (size_t)B_ * T_ * S_;

    const size_t NBTS = (size_t)B_ * T_ * S_;
    char* w = (char*)d_ws;
    u16*   Wb   = (u16*)w;                            // 34 MB bf16 logits
    u16*   P    = Wb + NBTS;                          // 34 MB bf16 exp(W)/4
    u16*   Bt   = P + NBTS;                           // 34 MB bf16 linear beta
    u16*   Abf  = Bt + NBTS;                          // 25 MB bf16 eps
    u16*   Bbf  = Abf + (size_t)B_ * T_ * C_;         // 13 MB bf16 cond
    u64*   mbg  = (u64*)(Bbf + (size_t)B_ * S_ * C_); // 2 MB move bits
    float* pmax = (float*)(mbg + (size_t)B_ * 8192);
    float* psum = pmax + (size_t)4 * B_ * S_;
    float* cmax = psum + (size_t)4 * B_ * S_;
    float* cinv = cmax + (size_t)B_ * S_;
    float* lp_part = cinv + (size_t)B_ * S_;
    float* elog = lp_part + B_ * 48;                  // B*16
    float* wlg  = elog + B_ * 16;                     // B*16
    int*   js   = (int*)(wlg + B_ * 16);

    k_eps<<<B_ * 48, 256, 0, stream>>>(eps, tlen, lp_part, Abf);
    k_cvt<<<1024, 256, 0, stream>>>(cond, Bbf);
    k_gemm<<<dim3(S_ / 128, T_ / 128, B_), 256, 0, stream>>>(Abf, Bbf, Wb);
    k_stats1<<<B_ * 2 * 4, 256, 0, stream>>>(Wb, pmax, psum);
    k_stats2<<<B_ * S_ / 256, 256, 0, stream>>>(pmax, psum, cmax, cinv);
    k_pack<<<2048, 256, 0, stream>>>(Wb, cmax, cinv, P);
    k_beta<<<B_ * 16, 64, 0, stream>>>(P, Bt);
    k_vit<<<B_ * 16, 64, 0, stream>>>(P, Bt, mbg, elog, wlg);
    k_btr<<<B_, 256, 0, stream>>>(mbg, js);
    k_path<<<4096, 256, 0, stream>>>(js, out_path);
    k_final<<<B_, 256, 0, stream>>>(P, js, lp_part, tlen, elog, wlg, out_lp);
}

// Round 8
// 240.320 us; speedup vs baseline: 7.1774x; 1.1228x over previous
//
#include <hip/hip_runtime.h>
#include <cstdint>
#include <cstddef>

#define B_ 32
#define T_ 1024
#define S_ 512
#define C_ 384
#define HALF_LOG_2PI 0.91893853320467274178f
#define LN2F 0.69314718055994530942f
#define INV_LN2F 1.44269504088896340736f

typedef unsigned short u16;
typedef unsigned long long u64;
typedef __attribute__((ext_vector_type(8))) short bf16x8;
typedef __attribute__((ext_vector_type(4))) float f32x4;

__device__ __forceinline__ unsigned rne16(float f) {   // f32 -> bf16 bits (RNE)
    unsigned b = __float_as_uint(f);
    return (b + 0x7FFFu + ((b >> 16) & 1u)) >> 16;
}
__device__ __forceinline__ uint4 pack8f(float a0, float a1, float a2, float a3,
                                        float a4, float a5, float a6, float a7) {
    uint4 q;
    q.x = rne16(a0) | (rne16(a1) << 16);
    q.y = rne16(a2) | (rne16(a3) << 16);
    q.z = rne16(a4) | (rne16(a5) << 16);
    q.w = rne16(a6) | (rne16(a7) << 16);
    return q;
}
#define UNPK(q, p)                                                              \
    float p##0 = __uint_as_float((q).x << 16),                                  \
          p##1 = __uint_as_float((q).x & 0xFFFF0000u),                          \
          p##2 = __uint_as_float((q).y << 16),                                  \
          p##3 = __uint_as_float((q).y & 0xFFFF0000u),                          \
          p##4 = __uint_as_float((q).z << 16),                                  \
          p##5 = __uint_as_float((q).z & 0xFFFF0000u),                          \
          p##6 = __uint_as_float((q).w << 16),                                  \
          p##7 = __uint_as_float((q).w & 0xFFFF0000u)

#define PROW(t) (*(const uint4*)(Pb  + (size_t)(t) * S_ + l8))
#define BROW(t) (*(const uint4*)(Btb + (size_t)(t) * S_ + l8))

// ---------------------------------------------------------------------------
// DPP helpers: VALU-only cross-lane (no lgkmcnt on the DP critical path).
template <int CTRL>
__device__ __forceinline__ float fdpp0(float x) {     // invalid src lanes -> 0
    return __uint_as_float((unsigned)__builtin_amdgcn_update_dpp(
        0, (int)__float_as_uint(x), CTRL, 0xF, 0xF, true));
}
// wave_shr:1 = 0x138 (lane l <- l-1, lane0 -> 0); wave_shl:1 = 0x130 (lane l <- l+1, lane63 -> 0)
__device__ __forceinline__ float wave_fmax(float x) { // uniform full-wave max
    x = fmaxf(x, fdpp0<0x121>(x));   // row_ror:1
    x = fmaxf(x, fdpp0<0x122>(x));   // row_ror:2
    x = fmaxf(x, fdpp0<0x124>(x));   // row_ror:4
    x = fmaxf(x, fdpp0<0x128>(x));   // row_ror:8  -> row max in all lanes
    float a = __uint_as_float((unsigned)__builtin_amdgcn_readlane((int)__float_as_uint(x), 0));
    float b = __uint_as_float((unsigned)__builtin_amdgcn_readlane((int)__float_as_uint(x), 16));
    float c = __uint_as_float((unsigned)__builtin_amdgcn_readlane((int)__float_as_uint(x), 32));
    float d = __uint_as_float((unsigned)__builtin_amdgcn_readlane((int)__float_as_uint(x), 48));
    return fmaxf(fmaxf(a, b), fmaxf(c, d));
}

// async global->LDS: 16B/lane, LDS dest = uniform base + lane*16.
__device__ __forceinline__ void gll16(const u16* g, u16* l) {
    __builtin_amdgcn_global_load_lds(
        (const __attribute__((address_space(1))) void*)g,
        (__attribute__((address_space(3))) void*)l, 16, 0, 0);
}
#define WAITV(N) do { asm volatile("s_waitcnt vmcnt(" #N ")" ::: "memory");     \
                      __builtin_amdgcn_sched_barrier(0); } while (0)
#define FENCE_LGKM() do { asm volatile("s_waitcnt lgkmcnt(0)" ::: "memory");    \
                          __builtin_amdgcn_sched_barrier(0); } while (0)

// ---------------------------------------------------------------------------
// K0a: eps -> bf16 (unmasked) + masked -0.5*sum(eps^2) partials.
__global__ __launch_bounds__(256) void k_eps(const float* __restrict__ eps,
                                             const int* __restrict__ tlen,
                                             float* __restrict__ lp_part,
                                             u16* __restrict__ Abf) {
    const int b = blockIdx.x / 48, chunk = blockIdx.x % 48;
    const int len = tlen[b];
    const float* base = eps + (size_t)b * T_ * C_ + (size_t)chunk * 8192;
    u16* obase = Abf + (size_t)b * T_ * C_ + (size_t)chunk * 8192;
    float acc = 0.f;
    for (int g = threadIdx.x; g < 1024; g += 256) {
        float4 v0 = *(const float4*)(base + g * 8);
        float4 v1 = *(const float4*)(base + g * 8 + 4);
        int t = (chunk * 8192 + g * 8) / C_;
        if (t < len)
            acc += v0.x*v0.x + v0.y*v0.y + v0.z*v0.z + v0.w*v0.w
                 + v1.x*v1.x + v1.y*v1.y + v1.z*v1.z + v1.w*v1.w;
        *(uint4*)(obase + g * 8) = pack8f(v0.x, v0.y, v0.z, v0.w,
                                          v1.x, v1.y, v1.z, v1.w);
    }
    __shared__ float red[256];
    red[threadIdx.x] = acc;
    __syncthreads();
    for (int o = 128; o > 0; o >>= 1) {
        if (threadIdx.x < o) red[threadIdx.x] += red[threadIdx.x + o];
        __syncthreads();
    }
    if (threadIdx.x == 0) lp_part[blockIdx.x] = -0.5f * red[0];
}

// K0b: cond -> bf16.
__global__ __launch_bounds__(256) void k_cvt(const float* __restrict__ src,
                                             u16* __restrict__ dst) {
    const size_t n8 = (size_t)B_ * S_ * C_ / 8;
    for (size_t i = (size_t)blockIdx.x * 256 + threadIdx.x; i < n8;
         i += (size_t)gridDim.x * 256) {
        float4 v0 = *(const float4*)(src + i * 8);
        float4 v1 = *(const float4*)(src + i * 8 + 4);
        *(uint4*)(dst + i * 8) = pack8f(v0.x, v0.y, v0.z, v0.w,
                                        v1.x, v1.y, v1.z, v1.w);
    }
}

// ---------------------------------------------------------------------------
// K1: bf16 MFMA GEMM -> bf16 logits Wb. 128x128 tile, 4 waves, BK=32.
__global__ __launch_bounds__(256) void k_gemm(const u16* __restrict__ A,
                                              const u16* __restrict__ Bc,
                                              u16* __restrict__ Wb) {
    __shared__ u16 Al[4096];
    __shared__ u16 Bl[4096];
    const int b  = blockIdx.z;
    const int m0 = blockIdx.y * 128;
    const int n0 = blockIdx.x * 128;
    const int tid = threadIdx.x;
    const int lane = tid & 63, wid = tid >> 6;
    const int wy = wid >> 1, wx = wid & 1;
    const int r15 = lane & 15, kg = lane >> 4;
    const u16* Ab = A  + (size_t)b * T_ * C_;
    const u16* Bb = Bc + (size_t)b * S_ * C_;

    f32x4 acc[4][4];
#pragma unroll
    for (int i = 0; i < 4; ++i)
#pragma unroll
        for (int j = 0; j < 4; ++j) acc[i][j] = (f32x4){0.f, 0.f, 0.f, 0.f};

    const int g1 = tid + 256;
    const int row0 = tid >> 2, o0 = tid & 3;
    const int row1 = g1 >> 2,  o1 = g1 & 3;
    const int wb0 = (row0 * 64 + o0 * 16) ^ (((row0 >> 1) & 7) << 4);
    const int wb1 = (row1 * 64 + o1 * 16) ^ (((row1 >> 1) & 7) << 4);
    const int rswz = ((r15 >> 1) & 7) << 4;

    for (int k0 = 0; k0 < C_; k0 += 32) {
        uint4 a0 = *(const uint4*)(Ab + (size_t)(m0 + row0) * C_ + k0 + o0 * 8);
        uint4 a1 = *(const uint4*)(Ab + (size_t)(m0 + row1) * C_ + k0 + o1 * 8);
        uint4 c0 = *(const uint4*)(Bb + (size_t)(n0 + row0) * C_ + k0 + o0 * 8);
        uint4 c1 = *(const uint4*)(Bb + (size_t)(n0 + row1) * C_ + k0 + o1 * 8);
        __syncthreads();
        *(uint4*)((char*)Al + wb0) = a0;
        *(uint4*)((char*)Al + wb1) = a1;
        *(uint4*)((char*)Bl + wb0) = c0;
        *(uint4*)((char*)Bl + wb1) = c1;
        __syncthreads();
        bf16x8 af[4], bfb[4];
#pragma unroll
        for (int ar = 0; ar < 4; ++ar) {
            int row = wy * 64 + ar * 16 + r15;
            af[ar] = *(const bf16x8*)((const char*)Al + ((row * 64 + kg * 16) ^ rswz));
        }
#pragma unroll
        for (int bc = 0; bc < 4; ++bc) {
            int row = wx * 64 + bc * 16 + r15;
            bfb[bc] = *(const bf16x8*)((const char*)Bl + ((row * 64 + kg * 16) ^ rswz));
        }
#pragma unroll
        for (int ar = 0; ar < 4; ++ar)
#pragma unroll
            for (int bc = 0; bc < 4; ++bc)
                acc[ar][bc] = __builtin_amdgcn_mfma_f32_16x16x32_bf16(
                    af[ar], bfb[bc], acc[ar][bc], 0, 0, 0);
    }
#pragma unroll
    for (int ar = 0; ar < 4; ++ar) {
        int t = m0 + wy * 64 + ar * 16 + kg * 4;
#pragma unroll
        for (int bc = 0; bc < 4; ++bc) {
            int s = n0 + wx * 64 + bc * 16 + r15;
            u16* dst = Wb + ((size_t)b * T_ + t) * S_ + s;
#pragma unroll
            for (int r = 0; r < 4; ++r) dst[(size_t)r * S_] = (u16)rne16(acc[ar][bc][r]);
        }
    }
}

// ---------------------------------------------------------------------------
// K2a/K2b: column softmax stats over t (bf16 logits in).
__global__ __launch_bounds__(256) void k_stats1(const u16* __restrict__ Wb,
                                                float* __restrict__ pmax,
                                                float* __restrict__ psum) {
    const int c  = blockIdx.x & 3;
    const int bh = blockIdx.x >> 2;
    const int b  = bh >> 1;
    const int s  = ((bh & 1) << 8) + threadIdx.x;
    const u16* col = Wb + (size_t)b * T_ * S_ + (size_t)c * 256 * S_ + s;
    float m = -3.0e38f, sum = 0.f;
    for (int t = 0; t < 256; t += 4) {
        float x0 = __uint_as_float((unsigned)col[(size_t)(t + 0) * S_] << 16);
        float x1 = __uint_as_float((unsigned)col[(size_t)(t + 1) * S_] << 16);
        float x2 = __uint_as_float((unsigned)col[(size_t)(t + 2) * S_] << 16);
        float x3 = __uint_as_float((unsigned)col[(size_t)(t + 3) * S_] << 16);
        float nm = fmaxf(fmaxf(fmaxf(fmaxf(m, x0), x1), x2), x3);
        sum = sum * expf(m - nm) + expf(x0 - nm) + expf(x1 - nm)
            + expf(x2 - nm) + expf(x3 - nm);
        m = nm;
    }
    pmax[(size_t)c * B_ * S_ + b * S_ + s] = m;
    psum[(size_t)c * B_ * S_ + b * S_ + s] = sum;
}

__global__ __launch_bounds__(256) void k_stats2(const float* __restrict__ pmax,
                                                const float* __restrict__ psum,
                                                float* __restrict__ cmax,
                                                float* __restrict__ cinv) {
    const int i = blockIdx.x * 256 + threadIdx.x;
    float m0 = pmax[i], m1 = pmax[(size_t)B_ * S_ + i];
    float m2 = pmax[(size_t)2 * B_ * S_ + i], m3 = pmax[(size_t)3 * B_ * S_ + i];
    float m = fmaxf(fmaxf(m0, m1), fmaxf(m2, m3));
    float s = psum[i] * expf(m0 - m)
            + psum[(size_t)B_ * S_ + i] * expf(m1 - m)
            + psum[(size_t)2 * B_ * S_ + i] * expf(m2 - m)
            + psum[(size_t)3 * B_ * S_ + i] * expf(m3 - m);
    cmax[i] = m;
    cinv[i] = 1.0f / s;
}

// ---------------------------------------------------------------------------
// K3: P_hat = exp(softmax(Wb,axis=T)) / 4, bf16.
__global__ __launch_bounds__(256) void k_pack(const u16* __restrict__ Wb,
                                              const float* __restrict__ cmax,
                                              const float* __restrict__ cinv,
                                              u16* __restrict__ P) {
    const size_t total8 = (size_t)B_ * T_ * S_ / 8;
    for (size_t i = (size_t)blockIdx.x * 256 + threadIdx.x; i < total8;
         i += (size_t)gridDim.x * 256) {
        size_t base = i * 8;
        int s = (int)(base & (S_ - 1));
        int b = (int)(base >> 19);
        uint4 xq = *(const uint4*)(Wb + base);
        UNPK(xq, x);
        float4 mA = *(const float4*)(cmax + (size_t)b * S_ + s);
        float4 mB = *(const float4*)(cmax + (size_t)b * S_ + s + 4);
        float4 iA = *(const float4*)(cinv + (size_t)b * S_ + s);
        float4 iB = *(const float4*)(cinv + (size_t)b * S_ + s + 4);
        float w0 = __builtin_amdgcn_exp2f(fmaf(x0, INV_LN2F, -mA.x * INV_LN2F)) * iA.x;
        float w1 = __builtin_amdgcn_exp2f(fmaf(x1, INV_LN2F, -mA.y * INV_LN2F)) * iA.y;
        float w2 = __builtin_amdgcn_exp2f(fmaf(x2, INV_LN2F, -mA.z * INV_LN2F)) * iA.z;
        float w3 = __builtin_amdgcn_exp2f(fmaf(x3, INV_LN2F, -mA.w * INV_LN2F)) * iA.w;
        float w4 = __builtin_amdgcn_exp2f(fmaf(x4, INV_LN2F, -mB.x * INV_LN2F)) * iB.x;
        float w5 = __builtin_amdgcn_exp2f(fmaf(x5, INV_LN2F, -mB.y * INV_LN2F)) * iB.y;
        float w6 = __builtin_amdgcn_exp2f(fmaf(x6, INV_LN2F, -mB.z * INV_LN2F)) * iB.z;
        float w7 = __builtin_amdgcn_exp2f(fmaf(x7, INV_LN2F, -mB.w * INV_LN2F)) * iB.w;
        float p0 = __builtin_amdgcn_exp2f(fmaf(w0, INV_LN2F, -2.0f));
        float p1 = __builtin_amdgcn_exp2f(fmaf(w1, INV_LN2F, -2.0f));
        float p2 = __builtin_amdgcn_exp2f(fmaf(w2, INV_LN2F, -2.0f));
        float p3 = __builtin_amdgcn_exp2f(fmaf(w3, INV_LN2F, -2.0f));
        float p4 = __builtin_amdgcn_exp2f(fmaf(w4, INV_LN2F, -2.0f));
        float p5 = __builtin_amdgcn_exp2f(fmaf(w5, INV_LN2F, -2.0f));
        float p6 = __builtin_amdgcn_exp2f(fmaf(w6, INV_LN2F, -2.0f));
        float p7 = __builtin_amdgcn_exp2f(fmaf(w7, INV_LN2F, -2.0f));
        *(uint4*)(P + base) = pack8f(p0, p1, p2, p3, p4, p5, p6, p7);
    }
}

// ---------------------------------------------------------------------------
// K4: backward DP, linear domain. LDS double-buffered global_load_lds staging,
// explicit vmcnt pipeline, DPP lane shift. 16 chunks of 64 (warm 128).
#define RENORM_B() do {                                                         \
    float mx_ = wave_fmax(fmaxf(fmaxf(fmaxf(m0,m1),fmaxf(m2,m3)),               \
                                fmaxf(fmaxf(m4,m5),fmaxf(m6,m7))));             \
    int eb_ = (__float_as_int(mx_) >> 23) & 255;                                \
    float sc_ = (eb_ > 0) ? __int_as_float((254 - eb_) << 23) : 1.0f;           \
    m0*=sc_; m1*=sc_; m2*=sc_; m3*=sc_; m4*=sc_; m5*=sc_; m6*=sc_; m7*=sc_;     \
} while (0)

#define BSTEPD(tt, jj) do {                                                     \
    uint4 q_ = *(const uint4*)&Pl[buf][jj][l8];                                 \
    UNPK(q_, eP);                                                               \
    float z0=m0*eP0, z1=m1*eP1, z2=m2*eP2, z3=m3*eP3;                           \
    float z4=m4*eP4, z5=m5*eP5, z6=m6*eP6, z7=m7*eP7;                           \
    float rt = fdpp0<0x130>(z0);  /* lane l <- l+1, lane63 -> 0 */              \
    m0=z0+z1; m1=z1+z2; m2=z2+z3; m3=z3+z4;                                     \
    m4=z4+z5; m5=z5+z6; m6=z6+z7; m7=z7+rt;                                     \
    if ((tt) < w0 + 64) {                                                       \
        uint4 st;                                                               \
        asm("v_cvt_pk_bf16_f32 %0, %1, %2" : "=v"(st.x) : "v"(m0), "v"(m1));    \
        asm("v_cvt_pk_bf16_f32 %0, %1, %2" : "=v"(st.y) : "v"(m2), "v"(m3));    \
        asm("v_cvt_pk_bf16_f32 %0, %1, %2" : "=v"(st.z) : "v"(m4), "v"(m5));    \
        asm("v_cvt_pk_bf16_f32 %0, %1, %2" : "=v"(st.w) : "v"(m6), "v"(m7));    \
        *(uint4*)(Bb + (size_t)(tt) * S_ + l8) = st;                            \
    }                                                                           \
} while (0)

__global__ __launch_bounds__(64) void k_beta(const u16* __restrict__ P,
                                             u16* __restrict__ Bt) {
    __shared__ u16 Pl[2][16][S_];
    const int l = threadIdx.x, l8 = l * 8;
    const int b = blockIdx.x >> 4, c = blockIdx.x & 15;
    const int w0 = c * 64;
    const u16* Pb = P  + (size_t)b * T_ * S_;
    u16*      Bb = Bt + (size_t)b * T_ * S_;
    float m0, m1, m2, m3, m4, m5, m6, m7;
    int te = w0 + 191;
    if (te > 1023) te = 1023;
    if (te == 1023) {
        m0 = m1 = m2 = m3 = m4 = m5 = m6 = 0.f;
        m7 = (l == 63) ? 1.f : 0.f;
        if (1023 < w0 + 64) {   // c == 15 stores init row
            uint4 st;
            asm("v_cvt_pk_bf16_f32 %0, %1, %2" : "=v"(st.x) : "v"(m0), "v"(m1));
            asm("v_cvt_pk_bf16_f32 %0, %1, %2" : "=v"(st.y) : "v"(m2), "v"(m3));
            asm("v_cvt_pk_bf16_f32 %0, %1, %2" : "=v"(st.z) : "v"(m4), "v"(m5));
            asm("v_cvt_pk_bf16_f32 %0, %1, %2" : "=v"(st.w) : "v"(m6), "v"(m7));
            *(uint4*)(Bb + (size_t)1023 * S_ + l8) = st;
        }
    } else {
        m0 = m1 = m2 = m3 = m4 = m5 = m6 = m7 = 1.f;
    }
    const int cnt = te - w0;            // 191/127/63, all == 15 mod 16
    const int ng = (cnt + 1) >> 4;      // 12/8/4
#pragma unroll
    for (int r = 0; r < 16; ++r)
        gll16(Pb + (size_t)(te - r) * S_ + l8, &Pl[0][r][0]);
#pragma unroll
    for (int r = 0; r < 16; ++r)
        gll16(Pb + (size_t)(te - 16 - r) * S_ + l8, &Pl[1][r][0]);
    int tt = te - 1;
    int buf = 0;
    for (int g = 0; g < ng - 1; ++g) {
        WAITV(16);
        BSTEPD(tt - 0, 0);  BSTEPD(tt - 1, 1);  BSTEPD(tt - 2, 2);  BSTEPD(tt - 3, 3);
        BSTEPD(tt - 4, 4);  BSTEPD(tt - 5, 5);  BSTEPD(tt - 6, 6);  BSTEPD(tt - 7, 7);
        RENORM_B();
        BSTEPD(tt - 8, 8);  BSTEPD(tt - 9, 9);  BSTEPD(tt - 10, 10); BSTEPD(tt - 11, 11);
        BSTEPD(tt - 12, 12); BSTEPD(tt - 13, 13); BSTEPD(tt - 14, 14); BSTEPD(tt - 15, 15);
        RENORM_B();
        FENCE_LGKM();
        if (g + 2 < ng) {
            const int bs = te - 16 * (g + 2);
#pragma unroll
            for (int r = 0; r < 16; ++r)
                gll16(Pb + (size_t)(bs - r) * S_ + l8, &Pl[buf][r][0]);
        }
        __builtin_amdgcn_sched_barrier(0);
        buf ^= 1;
        tt -= 16;
    }
    WAITV(0);
    BSTEPD(tt - 0, 0);  BSTEPD(tt - 1, 1);  BSTEPD(tt - 2, 2);  BSTEPD(tt - 3, 3);
    BSTEPD(tt - 4, 4);  BSTEPD(tt - 5, 5);  BSTEPD(tt - 6, 6);  BSTEPD(tt - 7, 7);
    RENORM_B();
    BSTEPD(tt - 8, 8);  BSTEPD(tt - 9, 9);  BSTEPD(tt - 10, 10); BSTEPD(tt - 11, 11);
    BSTEPD(tt - 12, 12); BSTEPD(tt - 13, 13); BSTEPD(tt - 14, 14);
}

// ---------------------------------------------------------------------------
// K5: fused mu-forward + Viterbi, linear domain, LDS-staged both streams.
#define RENORM_MI() do {                                                        \
    float mx_ = wave_fmax(fmaxf(fmaxf(fmaxf(m0,m1),fmaxf(m2,m3)),               \
                                fmaxf(fmaxf(m4,m5),fmaxf(m6,m7))));             \
    int eb_ = (__float_as_int(mx_) >> 23) & 255;                                \
    float sc_ = (eb_ > 0) ? __int_as_float((254 - eb_) << 23) : 1.0f;           \
    if (eb_ > 0) ioffM += eb_ - 127;                                            \
    m0*=sc_; m1*=sc_; m2*=sc_; m3*=sc_; m4*=sc_; m5*=sc_; m6*=sc_; m7*=sc_;     \
} while (0)

#define RENORM_VR() do {                                                        \
    float mx_ = wave_fmax(fmaxf(fmaxf(fmaxf(v0,v1),fmaxf(v2,v3)),               \
                                fmaxf(fmaxf(v4,v5),fmaxf(v6,v7))));             \
    int eb_ = (__float_as_int(mx_) >> 23) & 255;                                \
    float sc_ = (eb_ > 0) ? __int_as_float((254 - eb_) << 23) : 0.0f;           \
    float ad_ = (eb_ > 0) ? 0.f : 1.f;                                          \
    v0=fmaf(v0,sc_,ad_); v1=fmaf(v1,sc_,ad_); v2=fmaf(v2,sc_,ad_);              \
    v3=fmaf(v3,sc_,ad_); v4=fmaf(v4,sc_,ad_); v5=fmaf(v5,sc_,ad_);              \
    v6=fmaf(v6,sc_,ad_); v7=fmaf(v7,sc_,ad_);                                   \
} while (0)

#define VSTEPD(TT, jj) do {                                                     \
    uint4 qp_ = *(const uint4*)&Pl[buf][jj][l8];                                \
    uint4 qb_ = *(const uint4*)&Bl[buf][jj][l8];                                \
    UNPK(qp_, eP); UNPK(qb_, eB);                                               \
    float lf = fdpp0<0x138>(m7);  /* lane l <- l-1, lane0 -> 0 */               \
    float n0 = eP0*(m0+lf), n1 = eP1*(m1+m0);                                   \
    float n2 = eP2*(m2+m1), n3 = eP3*(m3+m2);                                   \
    float n4 = eP4*(m4+m3), n5 = eP5*(m5+m4);                                   \
    float n6 = eP6*(m6+m5), n7 = eP7*(m7+m6);                                   \
    float vlf = fdpp0<0x138>(v7);                                               \
    if ((TT) >= w0) {                                                           \
        unsigned cc0=(vlf>v0)?1u:0u, cc1=(v0>v1)?2u:0u, cc2=(v1>v2)?4u:0u,      \
                 cc3=(v2>v3)?8u:0u,  cc4=(v3>v4)?16u:0u, cc5=(v4>v5)?32u:0u,    \
                 cc6=(v5>v6)?64u:0u, cc7=(v6>v7)?128u:0u;                       \
        acc |= ((u64)(cc0|cc1|cc2|cc3|cc4|cc5|cc6|cc7)) << (((TT)&7)*8);        \
        if (((TT)&7) == 7) { mrow[((TT)>>3)*64 + l] = acc; acc = 0ULL; }        \
    }                                                                           \
    float w0v=(n0*eB0)*fmaxf(v0,vlf), w1v=(n1*eB1)*fmaxf(v1,v0);                \
    float w2v=(n2*eB2)*fmaxf(v2,v1),  w3v=(n3*eB3)*fmaxf(v3,v2);                \
    float w4v=(n4*eB4)*fmaxf(v4,v3),  w5v=(n5*eB5)*fmaxf(v5,v4);                \
    float w6v=(n6*eB6)*fmaxf(v6,v5),  w7v=(n7*eB7)*fmaxf(v7,v6);                \
    m0=n0;m1=n1;m2=n2;m3=n3;m4=n4;m5=n5;m6=n6;m7=n7;                            \
    v0=w0v;v1=w1v;v2=w2v;v3=w3v;v4=w4v;v5=w5v;v6=w6v;v7=w7v;                    \
    if ((TT) == wexp) { wex = __shfl(m0, 4 * c); wio = ioffM; }                 \
} while (0)

__global__ __launch_bounds__(64) void k_vit(const u16* __restrict__ P,
                                            const u16* __restrict__ Bt,
                                            u64* __restrict__ mbg,
                                            float* __restrict__ elog,
                                            float* __restrict__ wlg) {
    __shared__ u16 Pl[2][16][S_];
    __shared__ u16 Bl[2][16][S_];
    const int l = threadIdx.x, l8 = l * 8;
    const int b = blockIdx.x >> 4, c = blockIdx.x & 15;
    const int w0 = c * 64, tend = w0 + 63;
    const int t0 = (w0 >= 128) ? (w0 - 128) : 0;
    const int wexp = w0 - 1;
    const u16* Pb  = P  + (size_t)b * T_ * S_;
    const u16* Btb = Bt + (size_t)b * T_ * S_;
    u64* mrow = mbg + (size_t)b * 8192;

    float m0,m1,m2,m3,m4,m5,m6,m7, v0,v1,v2,v3,v4,v5,v6,v7;
    int ioffM = 0;
    float wex = 1.f; int wio = 0;
    {
        uint4 qp = PROW(t0); UNPK(qp, eP);
        uint4 qb = BROW(t0); UNPK(qb, eB);
        if (t0 == 0) {
            m0 = (l == 0) ? eP0 : 0.f;
            m1 = 0.f; m2 = 0.f; m3 = 0.f; m4 = 0.f; m5 = 0.f; m6 = 0.f; m7 = 0.f;
        } else {
            m0 = eP0; m1 = eP1; m2 = eP2; m3 = eP3;
            m4 = eP4; m5 = eP5; m6 = eP6; m7 = eP7;
        }
        v0 = m0*eB0; v1 = m1*eB1; v2 = m2*eB2; v3 = m3*eB3;
        v4 = m4*eB4; v5 = m5*eB5; v6 = m6*eB6; v7 = m7*eB7;
    }
    u64 acc = 0ULL;
    const int cnt = tend - t0;          // 191/127/63
    const int ng = (cnt + 1) >> 4;      // 12/8/4
#pragma unroll
    for (int r = 0; r < 16; ++r) {
        gll16(Pb  + (size_t)(t0 + 1 + r) * S_ + l8, &Pl[0][r][0]);
        gll16(Btb + (size_t)(t0 + 1 + r) * S_ + l8, &Bl[0][r][0]);
    }
#pragma unroll
    for (int r = 0; r < 16; ++r) {
        gll16(Pb  + (size_t)(t0 + 17 + r) * S_ + l8, &Pl[1][r][0]);
        gll16(Btb + (size_t)(t0 + 17 + r) * S_ + l8, &Bl[1][r][0]);
    }
    int t = t0 + 1;
    int buf = 0;
    for (int g = 0; g < ng - 1; ++g) {
        WAITV(32);
        VSTEPD(t + 0, 0);  VSTEPD(t + 1, 1);  VSTEPD(t + 2, 2);  VSTEPD(t + 3, 3);
        VSTEPD(t + 4, 4);  VSTEPD(t + 5, 5);  VSTEPD(t + 6, 6);  VSTEPD(t + 7, 7);
        RENORM_MI();
        RENORM_VR();
        VSTEPD(t + 8, 8);  VSTEPD(t + 9, 9);  VSTEPD(t + 10, 10); VSTEPD(t + 11, 11);
        VSTEPD(t + 12, 12); VSTEPD(t + 13, 13); VSTEPD(t + 14, 14); VSTEPD(t + 15, 15);
        RENORM_MI();
        RENORM_VR();
        FENCE_LGKM();
        if (g + 2 < ng) {
            const int bs = t0 + 1 + 16 * (g + 2);
#pragma unroll
            for (int r = 0; r < 16; ++r) {
                gll16(Pb  + (size_t)(bs + r) * S_ + l8, &Pl[buf][r][0]);
                gll16(Btb + (size_t)(bs + r) * S_ + l8, &Bl[buf][r][0]);
            }
        }
        __builtin_amdgcn_sched_barrier(0);
        buf ^= 1;
        t += 16;
    }
    WAITV(0);
    VSTEPD(t + 0, 0);  VSTEPD(t + 1, 1);  VSTEPD(t + 2, 2);  VSTEPD(t + 3, 3);
    VSTEPD(t + 4, 4);  VSTEPD(t + 5, 5);  VSTEPD(t + 6, 6);  VSTEPD(t + 7, 7);
    RENORM_MI();
    RENORM_VR();
    VSTEPD(t + 8, 8);  VSTEPD(t + 9, 9);  VSTEPD(t + 10, 10); VSTEPD(t + 11, 11);
    VSTEPD(t + 12, 12); VSTEPD(t + 13, 13); VSTEPD(t + 14, 14);

    float eex = (c == 15) ? __shfl(m7, 63) : __shfl(m0, 4 * (c + 1));
    if (l == 0) {
        elog[b * 16 + c] = __builtin_amdgcn_logf(fmaxf(eex, 1e-35f)) + (float)ioffM;
        if (c >= 1)
            wlg[b * 16 + c] = __builtin_amdgcn_logf(fmaxf(wex, 1e-35f)) + (float)wio;
    }
}

// ---------------------------------------------------------------------------
// K6: backtrace. 2 shfls per 8 steps.
__global__ __launch_bounds__(256) void k_btr(const u64* __restrict__ mbg,
                                             int* __restrict__ js) {
    __shared__ u64 mb[128][64];
    const int b = blockIdx.x, tid = threadIdx.x;
    const uint4* src = (const uint4*)(mbg + (size_t)b * 8192);
    uint4* dst = (uint4*)&mb[0][0];
    for (int i = tid; i < 4096; i += 256) dst[i] = src[i];
    __syncthreads();
    if (tid >= 64) return;
    const int l = tid;
    int jj = S_ - 1;
    if (l == 0) js[b * T_ + T_ - 1] = jj;
    u64 wcur = mb[127][l];
    for (int tau = 127; tau >= 0; --tau) {
        u64 wv = wcur;
        if (tau > 0) wcur = mb[tau - 1][l];
        const int hi = jj >> 3;
        u64 whi = __shfl(wv, hi);
        u64 wlo = __shfl(wv, (hi > 0) ? hi - 1 : 0);
        for (int i = 7; i >= 0; --i) {
            int t = tau * 8 + i;
            if (t == 0) break;
            u64 word = ((jj >> 3) == hi) ? whi : wlo;
            int bit = (int)((word >> ((t & 7) * 8 + (jj & 7))) & 1ULL);
            jj -= bit;
            if (l == 0) js[b * T_ + t - 1] = jj;
        }
    }
}

// ---------------------------------------------------------------------------
// K7: one-hot path writer.
__global__ void k_path(const int* __restrict__ js, float* __restrict__ outp) {
    const size_t total4 = (size_t)B_ * T_ * S_ / 4;
    float4* O = (float4*)outp;
    for (size_t i = (size_t)blockIdx.x * blockDim.x + threadIdx.x; i < total4;
         i += (size_t)gridDim.x * blockDim.x) {
        size_t base = i * 4;
        int s = (int)(base & (S_ - 1));
        int row = (int)(base >> 9);
        int jt = js[row];
        float4 o;
        o.x = (s == jt) ? 1.f : 0.f;
        o.y = (s + 1 == jt) ? 1.f : 0.f;
        o.z = (s + 2 == jt) ? 1.f : 0.f;
        o.w = (s + 3 == jt) ? 1.f : 0.f;
        O[i] = o;
    }
}

// ---------------------------------------------------------------------------
// K8: logprobs (mu_N via 16-chunk delta chain).
__global__ __launch_bounds__(256) void k_final(const u16* __restrict__ P,
                                               const int* __restrict__ js,
                                               const float* __restrict__ lp_part,
                                               const int* __restrict__ tlen,
                                               const float* __restrict__ elog,
                                               const float* __restrict__ wlg,
                                               float* __restrict__ out_lp) {
    const int b = blockIdx.x;
    float acc = 0.f;
    for (int t = threadIdx.x; t < T_; t += 256) {
        int jt = js[b * T_ + t];
        unsigned u = P[((size_t)b * T_ + t) * S_ + jt];
        acc += __builtin_amdgcn_logf(__uint_as_float(u << 16));   // log2(P_hat)
    }
    __shared__ float red[256];
    red[threadIdx.x] = acc;
    __syncthreads();
    for (int o = 128; o > 0; o >>= 1) {
        if (threadIdx.x < o) red[threadIdx.x] += red[threadIdx.x + o];
        __syncthreads();
    }
    if (threadIdx.x == 0) {
        float basep = 0.f;
        for (int i = 0; i < 48; ++i) basep += lp_part[b * 48 + i];
        float mu2n = elog[b * 16 + 15];
        for (int cc = 1; cc < 16; ++cc)
            mu2n += elog[b * 16 + cc - 1] - wlg[b * 16 + cc];
        out_lp[b] = basep - HALF_LOG_2PI * ((float)tlen[b] * C_)
                    + LN2F * (red[0] - mu2n);
    }
}

// ---------------------------------------------------------------------------
extern "C" void kernel_launch(void* const* d_in, const int* in_sizes, int n_in,
                              void* d_out, int out_size, void* d_ws, size_t ws_size,
                              hipStream_t stream) {
    const float* eps  = (const float*)d_in[0];
    const float* cond = (const float*)d_in[1];
    const int* tlen   = (const int*)d_in[2];

    float* out_path = (float*)d_out;
    float* out_lp   = out_path + (size_t)B_ * T_ * S_;

    const size_t NBTS = (size_t)B_ * T_ * S_;
    char* w = (char*)d_ws;
    u16*   Wb   = (u16*)w;                            // 34 MB bf16 logits
    u16*   P    = Wb + NBTS;                          // 34 MB bf16 exp(W)/4
    u16*   Bt   = P + NBTS;                           // 34 MB bf16 linear beta
    u16*   Abf  = Bt + NBTS;                          // 25 MB bf16 eps
    u16*   Bbf  = Abf + (size_t)B_ * T_ * C_;         // 13 MB bf16 cond
    u64*   mbg  = (u64*)(Bbf + (size_t)B_ * S_ * C_); // 2 MB move bits
    float* pmax = (float*)(mbg + (size_t)B_ * 8192);
    float* psum = pmax + (size_t)4 * B_ * S_;
    float* cmax = psum + (size_t)4 * B_ * S_;
    float* cinv = cmax + (size_t)B_ * S_;
    float* lp_part = cinv + (size_t)B_ * S_;
    float* elog = lp_part + B_ * 48;                  // B*16
    float* wlg  = elog + B_ * 16;                     // B*16
    int*   js   = (int*)(wlg + B_ * 16);

    k_eps<<<B_ * 48, 256, 0, stream>>>(eps, tlen, lp_part, Abf);
    k_cvt<<<1024, 256, 0, stream>>>(cond, Bbf);
    k_gemm<<<dim3(S_ / 128, T_ / 128, B_), 256, 0, stream>>>(Abf, Bbf, Wb);
    k_stats1<<<B_ * 2 * 4, 256, 0, stream>>>(Wb, pmax, psum);
    k_stats2<<<B_ * S_ / 256, 256, 0, stream>>>(pmax, psum, cmax, cinv);
    k_pack<<<2048, 256, 0, stream>>>(Wb, cmax, cinv, P);
    k_beta<<<B_ * 16, 64, 0, stream>>>(P, Bt);
    k_vit<<<B_ * 16, 64, 0, stream>>>(P, Bt, mbg, elog, wlg);
    k_btr<<<B_, 256, 0, stream>>>(mbg, js);
    k_path<<<4096, 256, 0, stream>>>(js, out_path);
    k_final<<<B_, 256, 0, stream>>>(P, js, lp_part, tlen, elog, wlg, out_lp);
}

// Round 9
// 211.605 us; speedup vs baseline: 8.1513x; 1.1357x over previous
//
#include <hip/hip_runtime.h>
#include <cstdint>
#include <cstddef>

#define B_ 32
#define T_ 1024
#define S_ 512
#define C_ 384
#define HALF_LOG_2PI 0.91893853320467274178f
#define LN2F 0.69314718055994530942f
#define INV_LN2F 1.44269504088896340736f

typedef unsigned short u16;
typedef unsigned long long u64;
typedef __attribute__((ext_vector_type(8))) short bf16x8;
typedef __attribute__((ext_vector_type(4))) float f32x4;

__device__ __forceinline__ unsigned rne16(float f) {   // f32 -> bf16 bits (RNE)
    unsigned b = __float_as_uint(f);
    return (b + 0x7FFFu + ((b >> 16) & 1u)) >> 16;
}
__device__ __forceinline__ uint4 pack8f(float a0, float a1, float a2, float a3,
                                        float a4, float a5, float a6, float a7) {
    uint4 q;
    q.x = rne16(a0) | (rne16(a1) << 16);
    q.y = rne16(a2) | (rne16(a3) << 16);
    q.z = rne16(a4) | (rne16(a5) << 16);
    q.w = rne16(a6) | (rne16(a7) << 16);
    return q;
}
#define UNPK(q, p)                                                              \
    float p##0 = __uint_as_float((q).x << 16),                                  \
          p##1 = __uint_as_float((q).x & 0xFFFF0000u),                          \
          p##2 = __uint_as_float((q).y << 16),                                  \
          p##3 = __uint_as_float((q).y & 0xFFFF0000u),                          \
          p##4 = __uint_as_float((q).z << 16),                                  \
          p##5 = __uint_as_float((q).z & 0xFFFF0000u),                          \
          p##6 = __uint_as_float((q).w << 16),                                  \
          p##7 = __uint_as_float((q).w & 0xFFFF0000u)

#define PROW(t) (*(const uint4*)(Pb  + (size_t)(t) * S_ + l8))
#define BROW(t) (*(const uint4*)(Btb + (size_t)(t) * S_ + l8))

// ---------------------------------------------------------------------------
// DPP helpers: VALU-only cross-lane.
template <int CTRL>
__device__ __forceinline__ float fdpp0(float x) {     // invalid src lanes -> 0
    return __uint_as_float((unsigned)__builtin_amdgcn_update_dpp(
        0, (int)__float_as_uint(x), CTRL, 0xF, 0xF, true));
}
__device__ __forceinline__ float wave_fmax(float x) { // uniform full-wave max
    x = fmaxf(x, fdpp0<0x121>(x));   // row_ror:1
    x = fmaxf(x, fdpp0<0x122>(x));   // row_ror:2
    x = fmaxf(x, fdpp0<0x124>(x));   // row_ror:4
    x = fmaxf(x, fdpp0<0x128>(x));   // row_ror:8
    float a = __uint_as_float((unsigned)__builtin_amdgcn_readlane((int)__float_as_uint(x), 0));
    float b = __uint_as_float((unsigned)__builtin_amdgcn_readlane((int)__float_as_uint(x), 16));
    float c = __uint_as_float((unsigned)__builtin_amdgcn_readlane((int)__float_as_uint(x), 32));
    float d = __uint_as_float((unsigned)__builtin_amdgcn_readlane((int)__float_as_uint(x), 48));
    return fmaxf(fmaxf(a, b), fmaxf(c, d));
}

__device__ __forceinline__ void gll16(const u16* g, u16* l) {
    __builtin_amdgcn_global_load_lds(
        (const __attribute__((address_space(1))) void*)g,
        (__attribute__((address_space(3))) void*)l, 16, 0, 0);
}
#define WAITV(N) do { asm volatile("s_waitcnt vmcnt(" #N ")" ::: "memory");     \
                      __builtin_amdgcn_sched_barrier(0); } while (0)
#define FENCE_LGKM() do { asm volatile("s_waitcnt lgkmcnt(0)" ::: "memory");    \
                          __builtin_amdgcn_sched_barrier(0); } while (0)

// ---------------------------------------------------------------------------
// K0: fused eps->bf16 + eps^2 partials (blocks 0..1535) and cond->bf16 (rest).
__global__ __launch_bounds__(256) void k_pre(const float* __restrict__ eps,
                                             const float* __restrict__ cond,
                                             const int* __restrict__ tlen,
                                             float* __restrict__ lp_part,
                                             u16* __restrict__ Abf,
                                             u16* __restrict__ Bbf) {
    if (blockIdx.x < 1536) {
        const int b = blockIdx.x / 48, chunk = blockIdx.x % 48;
        const int len = tlen[b];
        const float* base = eps + (size_t)b * T_ * C_ + (size_t)chunk * 8192;
        u16* obase = Abf + (size_t)b * T_ * C_ + (size_t)chunk * 8192;
        float acc = 0.f;
        for (int g = threadIdx.x; g < 1024; g += 256) {
            float4 v0 = *(const float4*)(base + g * 8);
            float4 v1 = *(const float4*)(base + g * 8 + 4);
            int t = (chunk * 8192 + g * 8) / C_;
            if (t < len)
                acc += v0.x*v0.x + v0.y*v0.y + v0.z*v0.z + v0.w*v0.w
                     + v1.x*v1.x + v1.y*v1.y + v1.z*v1.z + v1.w*v1.w;
            *(uint4*)(obase + g * 8) = pack8f(v0.x, v0.y, v0.z, v0.w,
                                              v1.x, v1.y, v1.z, v1.w);
        }
        __shared__ float red[256];
        red[threadIdx.x] = acc;
        __syncthreads();
        for (int o = 128; o > 0; o >>= 1) {
            if (threadIdx.x < o) red[threadIdx.x] += red[threadIdx.x + o];
            __syncthreads();
        }
        if (threadIdx.x == 0) lp_part[blockIdx.x] = -0.5f * red[0];
    } else {
        const size_t n8 = (size_t)B_ * S_ * C_ / 8;
        for (size_t i = (size_t)(blockIdx.x - 1536) * 256 + threadIdx.x; i < n8;
             i += (size_t)512 * 256) {
            float4 v0 = *(const float4*)(cond + i * 8);
            float4 v1 = *(const float4*)(cond + i * 8 + 4);
            *(uint4*)(Bbf + i * 8) = pack8f(v0.x, v0.y, v0.z, v0.w,
                                            v1.x, v1.y, v1.z, v1.w);
        }
    }
}

// ---------------------------------------------------------------------------
// K1: bf16 MFMA GEMM -> bf16 logits Wb. 128x128 tile, 4 waves, BK=32.
__global__ __launch_bounds__(256) void k_gemm(const u16* __restrict__ A,
                                              const u16* __restrict__ Bc,
                                              u16* __restrict__ Wb) {
    __shared__ u16 Al[4096];
    __shared__ u16 Bl[4096];
    const int b  = blockIdx.z;
    const int m0 = blockIdx.y * 128;
    const int n0 = blockIdx.x * 128;
    const int tid = threadIdx.x;
    const int lane = tid & 63, wid = tid >> 6;
    const int wy = wid >> 1, wx = wid & 1;
    const int r15 = lane & 15, kg = lane >> 4;
    const u16* Ab = A  + (size_t)b * T_ * C_;
    const u16* Bb = Bc + (size_t)b * S_ * C_;

    f32x4 acc[4][4];
#pragma unroll
    for (int i = 0; i < 4; ++i)
#pragma unroll
        for (int j = 0; j < 4; ++j) acc[i][j] = (f32x4){0.f, 0.f, 0.f, 0.f};

    const int g1 = tid + 256;
    const int row0 = tid >> 2, o0 = tid & 3;
    const int row1 = g1 >> 2,  o1 = g1 & 3;
    const int wb0 = (row0 * 64 + o0 * 16) ^ (((row0 >> 1) & 7) << 4);
    const int wb1 = (row1 * 64 + o1 * 16) ^ (((row1 >> 1) & 7) << 4);
    const int rswz = ((r15 >> 1) & 7) << 4;

    for (int k0 = 0; k0 < C_; k0 += 32) {
        uint4 a0 = *(const uint4*)(Ab + (size_t)(m0 + row0) * C_ + k0 + o0 * 8);
        uint4 a1 = *(const uint4*)(Ab + (size_t)(m0 + row1) * C_ + k0 + o1 * 8);
        uint4 c0 = *(const uint4*)(Bb + (size_t)(n0 + row0) * C_ + k0 + o0 * 8);
        uint4 c1 = *(const uint4*)(Bb + (size_t)(n0 + row1) * C_ + k0 + o1 * 8);
        __syncthreads();
        *(uint4*)((char*)Al + wb0) = a0;
        *(uint4*)((char*)Al + wb1) = a1;
        *(uint4*)((char*)Bl + wb0) = c0;
        *(uint4*)((char*)Bl + wb1) = c1;
        __syncthreads();
        bf16x8 af[4], bfb[4];
#pragma unroll
        for (int ar = 0; ar < 4; ++ar) {
            int row = wy * 64 + ar * 16 + r15;
            af[ar] = *(const bf16x8*)((const char*)Al + ((row * 64 + kg * 16) ^ rswz));
        }
#pragma unroll
        for (int bc = 0; bc < 4; ++bc) {
            int row = wx * 64 + bc * 16 + r15;
            bfb[bc] = *(const bf16x8*)((const char*)Bl + ((row * 64 + kg * 16) ^ rswz));
        }
#pragma unroll
        for (int ar = 0; ar < 4; ++ar)
#pragma unroll
            for (int bc = 0; bc < 4; ++bc)
                acc[ar][bc] = __builtin_amdgcn_mfma_f32_16x16x32_bf16(
                    af[ar], bfb[bc], acc[ar][bc], 0, 0, 0);
    }
#pragma unroll
    for (int ar = 0; ar < 4; ++ar) {
        int t = m0 + wy * 64 + ar * 16 + kg * 4;
#pragma unroll
        for (int bc = 0; bc < 4; ++bc) {
            int s = n0 + wx * 64 + bc * 16 + r15;
            u16* dst = Wb + ((size_t)b * T_ + t) * S_ + s;
#pragma unroll
            for (int r = 0; r < 4; ++r) dst[(size_t)r * S_] = (u16)rne16(acc[ar][bc][r]);
        }
    }
}

// ---------------------------------------------------------------------------
// K2a/K2b: column softmax stats over t (bf16 logits in).
__global__ __launch_bounds__(256) void k_stats1(const u16* __restrict__ Wb,
                                                float* __restrict__ pmax,
                                                float* __restrict__ psum) {
    const int c  = blockIdx.x & 3;
    const int bh = blockIdx.x >> 2;
    const int b  = bh >> 1;
    const int s  = ((bh & 1) << 8) + threadIdx.x;
    const u16* col = Wb + (size_t)b * T_ * S_ + (size_t)c * 256 * S_ + s;
    float m = -3.0e38f, sum = 0.f;
    for (int t = 0; t < 256; t += 4) {
        float x0 = __uint_as_float((unsigned)col[(size_t)(t + 0) * S_] << 16);
        float x1 = __uint_as_float((unsigned)col[(size_t)(t + 1) * S_] << 16);
        float x2 = __uint_as_float((unsigned)col[(size_t)(t + 2) * S_] << 16);
        float x3 = __uint_as_float((unsigned)col[(size_t)(t + 3) * S_] << 16);
        float nm = fmaxf(fmaxf(fmaxf(fmaxf(m, x0), x1), x2), x3);
        sum = sum * expf(m - nm) + expf(x0 - nm) + expf(x1 - nm)
            + expf(x2 - nm) + expf(x3 - nm);
        m = nm;
    }
    pmax[(size_t)c * B_ * S_ + b * S_ + s] = m;
    psum[(size_t)c * B_ * S_ + b * S_ + s] = sum;
}

__global__ __launch_bounds__(256) void k_stats2(const float* __restrict__ pmax,
                                                const float* __restrict__ psum,
                                                float* __restrict__ cmax,
                                                float* __restrict__ cinv) {
    const int i = blockIdx.x * 256 + threadIdx.x;
    float m0 = pmax[i], m1 = pmax[(size_t)B_ * S_ + i];
    float m2 = pmax[(size_t)2 * B_ * S_ + i], m3 = pmax[(size_t)3 * B_ * S_ + i];
    float m = fmaxf(fmaxf(m0, m1), fmaxf(m2, m3));
    float s = psum[i] * expf(m0 - m)
            + psum[(size_t)B_ * S_ + i] * expf(m1 - m)
            + psum[(size_t)2 * B_ * S_ + i] * expf(m2 - m)
            + psum[(size_t)3 * B_ * S_ + i] * expf(m3 - m);
    cmax[i] = m;
    cinv[i] = 1.0f / s;
}

// ---------------------------------------------------------------------------
// K3: P_hat = exp(softmax(Wb,axis=T)) / 4, bf16.
__global__ __launch_bounds__(256) void k_pack(const u16* __restrict__ Wb,
                                              const float* __restrict__ cmax,
                                              const float* __restrict__ cinv,
                                              u16* __restrict__ P) {
    const size_t total8 = (size_t)B_ * T_ * S_ / 8;
    for (size_t i = (size_t)blockIdx.x * 256 + threadIdx.x; i < total8;
         i += (size_t)gridDim.x * 256) {
        size_t base = i * 8;
        int s = (int)(base & (S_ - 1));
        int b = (int)(base >> 19);
        uint4 xq = *(const uint4*)(Wb + base);
        UNPK(xq, x);
        float4 mA = *(const float4*)(cmax + (size_t)b * S_ + s);
        float4 mB = *(const float4*)(cmax + (size_t)b * S_ + s + 4);
        float4 iA = *(const float4*)(cinv + (size_t)b * S_ + s);
        float4 iB = *(const float4*)(cinv + (size_t)b * S_ + s + 4);
        float w0 = __builtin_amdgcn_exp2f(fmaf(x0, INV_LN2F, -mA.x * INV_LN2F)) * iA.x;
        float w1 = __builtin_amdgcn_exp2f(fmaf(x1, INV_LN2F, -mA.y * INV_LN2F)) * iA.y;
        float w2 = __builtin_amdgcn_exp2f(fmaf(x2, INV_LN2F, -mA.z * INV_LN2F)) * iA.z;
        float w3 = __builtin_amdgcn_exp2f(fmaf(x3, INV_LN2F, -mA.w * INV_LN2F)) * iA.w;
        float w4 = __builtin_amdgcn_exp2f(fmaf(x4, INV_LN2F, -mB.x * INV_LN2F)) * iB.x;
        float w5 = __builtin_amdgcn_exp2f(fmaf(x5, INV_LN2F, -mB.y * INV_LN2F)) * iB.y;
        float w6 = __builtin_amdgcn_exp2f(fmaf(x6, INV_LN2F, -mB.z * INV_LN2F)) * iB.z;
        float w7 = __builtin_amdgcn_exp2f(fmaf(x7, INV_LN2F, -mB.w * INV_LN2F)) * iB.w;
        float p0 = __builtin_amdgcn_exp2f(fmaf(w0, INV_LN2F, -2.0f));
        float p1 = __builtin_amdgcn_exp2f(fmaf(w1, INV_LN2F, -2.0f));
        float p2 = __builtin_amdgcn_exp2f(fmaf(w2, INV_LN2F, -2.0f));
        float p3 = __builtin_amdgcn_exp2f(fmaf(w3, INV_LN2F, -2.0f));
        float p4 = __builtin_amdgcn_exp2f(fmaf(w4, INV_LN2F, -2.0f));
        float p5 = __builtin_amdgcn_exp2f(fmaf(w5, INV_LN2F, -2.0f));
        float p6 = __builtin_amdgcn_exp2f(fmaf(w6, INV_LN2F, -2.0f));
        float p7 = __builtin_amdgcn_exp2f(fmaf(w7, INV_LN2F, -2.0f));
        *(uint4*)(P + base) = pack8f(p0, p1, p2, p3, p4, p5, p6, p7);
    }
}

// ---------------------------------------------------------------------------
// K4: backward DP, linear domain. 16 chunks of 64 + 64-step warm-up,
// LDS double-buffered global_load_lds staging, vmcnt pipeline, DPP shift.
#define RENORM_B() do {                                                         \
    float mx_ = wave_fmax(fmaxf(fmaxf(fmaxf(m0,m1),fmaxf(m2,m3)),               \
                                fmaxf(fmaxf(m4,m5),fmaxf(m6,m7))));             \
    int eb_ = (__float_as_int(mx_) >> 23) & 255;                                \
    float sc_ = (eb_ > 0) ? __int_as_float((254 - eb_) << 23) : 1.0f;           \
    m0*=sc_; m1*=sc_; m2*=sc_; m3*=sc_; m4*=sc_; m5*=sc_; m6*=sc_; m7*=sc_;     \
} while (0)

#define BSTEPD(tt, jj) do {                                                     \
    uint4 q_ = *(const uint4*)&Pl[buf][jj][l8];                                 \
    UNPK(q_, eP);                                                               \
    float z0=m0*eP0, z1=m1*eP1, z2=m2*eP2, z3=m3*eP3;                           \
    float z4=m4*eP4, z5=m5*eP5, z6=m6*eP6, z7=m7*eP7;                           \
    float rt = fdpp0<0x130>(z0);  /* lane l <- l+1, lane63 -> 0 */              \
    m0=z0+z1; m1=z1+z2; m2=z2+z3; m3=z3+z4;                                     \
    m4=z4+z5; m5=z5+z6; m6=z6+z7; m7=z7+rt;                                     \
    if ((tt) < w0 + 64) {                                                       \
        uint4 st;                                                               \
        asm("v_cvt_pk_bf16_f32 %0, %1, %2" : "=v"(st.x) : "v"(m0), "v"(m1));    \
        asm("v_cvt_pk_bf16_f32 %0, %1, %2" : "=v"(st.y) : "v"(m2), "v"(m3));    \
        asm("v_cvt_pk_bf16_f32 %0, %1, %2" : "=v"(st.z) : "v"(m4), "v"(m5));    \
        asm("v_cvt_pk_bf16_f32 %0, %1, %2" : "=v"(st.w) : "v"(m6), "v"(m7));    \
        *(uint4*)(Bb + (size_t)(tt) * S_ + l8) = st;                            \
    }                                                                           \
} while (0)

__global__ __launch_bounds__(64) void k_beta(const u16* __restrict__ P,
                                             u16* __restrict__ Bt) {
    __shared__ u16 Pl[2][16][S_];
    const int l = threadIdx.x, l8 = l * 8;
    const int b = blockIdx.x >> 4, c = blockIdx.x & 15;
    const int w0 = c * 64;
    const u16* Pb = P  + (size_t)b * T_ * S_;
    u16*      Bb = Bt + (size_t)b * T_ * S_;
    float m0, m1, m2, m3, m4, m5, m6, m7;
    int te = w0 + 127;
    if (te > 1023) te = 1023;
    if (te == 1023) {    // exact init (c == 14, 15)
        m0 = m1 = m2 = m3 = m4 = m5 = m6 = 0.f;
        m7 = (l == 63) ? 1.f : 0.f;
        if (1023 < w0 + 64) {   // c == 15 stores init row
            uint4 st;
            asm("v_cvt_pk_bf16_f32 %0, %1, %2" : "=v"(st.x) : "v"(m0), "v"(m1));
            asm("v_cvt_pk_bf16_f32 %0, %1, %2" : "=v"(st.y) : "v"(m2), "v"(m3));
            asm("v_cvt_pk_bf16_f32 %0, %1, %2" : "=v"(st.z) : "v"(m4), "v"(m5));
            asm("v_cvt_pk_bf16_f32 %0, %1, %2" : "=v"(st.w) : "v"(m6), "v"(m7));
            *(uint4*)(Bb + (size_t)1023 * S_ + l8) = st;
        }
    } else {
        m0 = m1 = m2 = m3 = m4 = m5 = m6 = m7 = 1.f;
    }
    const int cnt = te - w0;            // 127/63, == 15 mod 16
    const int ng = (cnt + 1) >> 4;      // 8/4
#pragma unroll
    for (int r = 0; r < 16; ++r)
        gll16(Pb + (size_t)(te - r) * S_ + l8, &Pl[0][r][0]);
#pragma unroll
    for (int r = 0; r < 16; ++r)
        gll16(Pb + (size_t)(te - 16 - r) * S_ + l8, &Pl[1][r][0]);
    int tt = te - 1;
    int buf = 0;
    for (int g = 0; g < ng - 1; ++g) {
        WAITV(16);
        BSTEPD(tt - 0, 0);  BSTEPD(tt - 1, 1);  BSTEPD(tt - 2, 2);  BSTEPD(tt - 3, 3);
        BSTEPD(tt - 4, 4);  BSTEPD(tt - 5, 5);  BSTEPD(tt - 6, 6);  BSTEPD(tt - 7, 7);
        RENORM_B();
        BSTEPD(tt - 8, 8);  BSTEPD(tt - 9, 9);  BSTEPD(tt - 10, 10); BSTEPD(tt - 11, 11);
        BSTEPD(tt - 12, 12); BSTEPD(tt - 13, 13); BSTEPD(tt - 14, 14); BSTEPD(tt - 15, 15);
        RENORM_B();
        FENCE_LGKM();
        if (g + 2 < ng) {
            const int bs = te - 16 * (g + 2);
#pragma unroll
            for (int r = 0; r < 16; ++r)
                gll16(Pb + (size_t)(bs - r) * S_ + l8, &Pl[buf][r][0]);
        }
        __builtin_amdgcn_sched_barrier(0);
        buf ^= 1;
        tt -= 16;
    }
    WAITV(0);
    BSTEPD(tt - 0, 0);  BSTEPD(tt - 1, 1);  BSTEPD(tt - 2, 2);  BSTEPD(tt - 3, 3);
    BSTEPD(tt - 4, 4);  BSTEPD(tt - 5, 5);  BSTEPD(tt - 6, 6);  BSTEPD(tt - 7, 7);
    RENORM_B();
    BSTEPD(tt - 8, 8);  BSTEPD(tt - 9, 9);  BSTEPD(tt - 10, 10); BSTEPD(tt - 11, 11);
    BSTEPD(tt - 12, 12); BSTEPD(tt - 13, 13); BSTEPD(tt - 14, 14);
}

// ---------------------------------------------------------------------------
// K5: fused mu-forward + Viterbi, linear domain, 64-step warm-up.
#define RENORM_MI() do {                                                        \
    float mx_ = wave_fmax(fmaxf(fmaxf(fmaxf(m0,m1),fmaxf(m2,m3)),               \
                                fmaxf(fmaxf(m4,m5),fmaxf(m6,m7))));             \
    int eb_ = (__float_as_int(mx_) >> 23) & 255;                                \
    float sc_ = (eb_ > 0) ? __int_as_float((254 - eb_) << 23) : 1.0f;           \
    if (eb_ > 0) ioffM += eb_ - 127;                                            \
    m0*=sc_; m1*=sc_; m2*=sc_; m3*=sc_; m4*=sc_; m5*=sc_; m6*=sc_; m7*=sc_;     \
} while (0)

#define RENORM_VR() do {                                                        \
    float mx_ = wave_fmax(fmaxf(fmaxf(fmaxf(v0,v1),fmaxf(v2,v3)),               \
                                fmaxf(fmaxf(v4,v5),fmaxf(v6,v7))));             \
    int eb_ = (__float_as_int(mx_) >> 23) & 255;                                \
    float sc_ = (eb_ > 0) ? __int_as_float((254 - eb_) << 23) : 0.0f;           \
    float ad_ = (eb_ > 0) ? 0.f : 1.f;                                          \
    v0=fmaf(v0,sc_,ad_); v1=fmaf(v1,sc_,ad_); v2=fmaf(v2,sc_,ad_);              \
    v3=fmaf(v3,sc_,ad_); v4=fmaf(v4,sc_,ad_); v5=fmaf(v5,sc_,ad_);              \
    v6=fmaf(v6,sc_,ad_); v7=fmaf(v7,sc_,ad_);                                   \
} while (0)

#define VSTEPD(TT, jj) do {                                                     \
    uint4 qp_ = *(const uint4*)&Pl[buf][jj][l8];                                \
    uint4 qb_ = *(const uint4*)&Bl[buf][jj][l8];                                \
    UNPK(qp_, eP); UNPK(qb_, eB);                                               \
    float lf = fdpp0<0x138>(m7);  /* lane l <- l-1, lane0 -> 0 */               \
    float n0 = eP0*(m0+lf), n1 = eP1*(m1+m0);                                   \
    float n2 = eP2*(m2+m1), n3 = eP3*(m3+m2);                                   \
    float n4 = eP4*(m4+m3), n5 = eP5*(m5+m4);                                   \
    float n6 = eP6*(m6+m5), n7 = eP7*(m7+m6);                                   \
    float vlf = fdpp0<0x138>(v7);                                               \
    if ((TT) >= w0) {                                                           \
        unsigned cc0=(vlf>v0)?1u:0u, cc1=(v0>v1)?2u:0u, cc2=(v1>v2)?4u:0u,      \
                 cc3=(v2>v3)?8u:0u,  cc4=(v3>v4)?16u:0u, cc5=(v4>v5)?32u:0u,    \
                 cc6=(v5>v6)?64u:0u, cc7=(v6>v7)?128u:0u;                       \
        acc |= ((u64)(cc0|cc1|cc2|cc3|cc4|cc5|cc6|cc7)) << (((TT)&7)*8);        \
        if (((TT)&7) == 7) { mrow[((TT)>>3)*64 + l] = acc; acc = 0ULL; }        \
    }                                                                           \
    float w0v=(n0*eB0)*fmaxf(v0,vlf), w1v=(n1*eB1)*fmaxf(v1,v0);                \
    float w2v=(n2*eB2)*fmaxf(v2,v1),  w3v=(n3*eB3)*fmaxf(v3,v2);                \
    float w4v=(n4*eB4)*fmaxf(v4,v3),  w5v=(n5*eB5)*fmaxf(v5,v4);                \
    float w6v=(n6*eB6)*fmaxf(v6,v5),  w7v=(n7*eB7)*fmaxf(v7,v6);                \
    m0=n0;m1=n1;m2=n2;m3=n3;m4=n4;m5=n5;m6=n6;m7=n7;                            \
    v0=w0v;v1=w1v;v2=w2v;v3=w3v;v4=w4v;v5=w5v;v6=w6v;v7=w7v;                    \
    if ((TT) == wexp) { wex = __shfl(m0, 4 * c); wio = ioffM; }                 \
} while (0)

__global__ __launch_bounds__(64) void k_vit(const u16* __restrict__ P,
                                            const u16* __restrict__ Bt,
                                            u64* __restrict__ mbg,
                                            float* __restrict__ elog,
                                            float* __restrict__ wlg) {
    __shared__ u16 Pl[2][16][S_];
    __shared__ u16 Bl[2][16][S_];
    const int l = threadIdx.x, l8 = l * 8;
    const int b = blockIdx.x >> 4, c = blockIdx.x & 15;
    const int w0 = c * 64, tend = w0 + 63;
    const int t0 = (w0 >= 64) ? (w0 - 64) : 0;
    const int wexp = w0 - 1;
    const u16* Pb  = P  + (size_t)b * T_ * S_;
    const u16* Btb = Bt + (size_t)b * T_ * S_;
    u64* mrow = mbg + (size_t)b * 8192;

    float m0,m1,m2,m3,m4,m5,m6,m7, v0,v1,v2,v3,v4,v5,v6,v7;
    int ioffM = 0;
    float wex = 1.f; int wio = 0;
    {
        uint4 qp = PROW(t0); UNPK(qp, eP);
        uint4 qb = BROW(t0); UNPK(qb, eB);
        if (t0 == 0) {   // exact init (c == 0, 1)
            m0 = (l == 0) ? eP0 : 0.f;
            m1 = 0.f; m2 = 0.f; m3 = 0.f; m4 = 0.f; m5 = 0.f; m6 = 0.f; m7 = 0.f;
        } else {
            m0 = eP0; m1 = eP1; m2 = eP2; m3 = eP3;
            m4 = eP4; m5 = eP5; m6 = eP6; m7 = eP7;
        }
        v0 = m0*eB0; v1 = m1*eB1; v2 = m2*eB2; v3 = m3*eB3;
        v4 = m4*eB4; v5 = m5*eB5; v6 = m6*eB6; v7 = m7*eB7;
    }
    u64 acc = 0ULL;
    const int cnt = tend - t0;          // 127/63
    const int ng = (cnt + 1) >> 4;      // 8/4
#pragma unroll
    for (int r = 0; r < 16; ++r) {
        gll16(Pb  + (size_t)(t0 + 1 + r) * S_ + l8, &Pl[0][r][0]);
        gll16(Btb + (size_t)(t0 + 1 + r) * S_ + l8, &Bl[0][r][0]);
    }
#pragma unroll
    for (int r = 0; r < 16; ++r) {
        gll16(Pb  + (size_t)(t0 + 17 + r) * S_ + l8, &Pl[1][r][0]);
        gll16(Btb + (size_t)(t0 + 17 + r) * S_ + l8, &Bl[1][r][0]);
    }
    int t = t0 + 1;
    int buf = 0;
    for (int g = 0; g < ng - 1; ++g) {
        WAITV(32);
        VSTEPD(t + 0, 0);  VSTEPD(t + 1, 1);  VSTEPD(t + 2, 2);  VSTEPD(t + 3, 3);
        VSTEPD(t + 4, 4);  VSTEPD(t + 5, 5);  VSTEPD(t + 6, 6);  VSTEPD(t + 7, 7);
        RENORM_MI();
        RENORM_VR();
        VSTEPD(t + 8, 8);  VSTEPD(t + 9, 9);  VSTEPD(t + 10, 10); VSTEPD(t + 11, 11);
        VSTEPD(t + 12, 12); VSTEPD(t + 13, 13); VSTEPD(t + 14, 14); VSTEPD(t + 15, 15);
        RENORM_MI();
        RENORM_VR();
        FENCE_LGKM();
        if (g + 2 < ng) {
            const int bs = t0 + 1 + 16 * (g + 2);
#pragma unroll
            for (int r = 0; r < 16; ++r) {
                gll16(Pb  + (size_t)(bs + r) * S_ + l8, &Pl[buf][r][0]);
                gll16(Btb + (size_t)(bs + r) * S_ + l8, &Bl[buf][r][0]);
            }
        }
        __builtin_amdgcn_sched_barrier(0);
        buf ^= 1;
        t += 16;
    }
    WAITV(0);
    VSTEPD(t + 0, 0);  VSTEPD(t + 1, 1);  VSTEPD(t + 2, 2);  VSTEPD(t + 3, 3);
    VSTEPD(t + 4, 4);  VSTEPD(t + 5, 5);  VSTEPD(t + 6, 6);  VSTEPD(t + 7, 7);
    RENORM_MI();
    RENORM_VR();
    VSTEPD(t + 8, 8);  VSTEPD(t + 9, 9);  VSTEPD(t + 10, 10); VSTEPD(t + 11, 11);
    VSTEPD(t + 12, 12); VSTEPD(t + 13, 13); VSTEPD(t + 14, 14);

    float eex = (c == 15) ? __shfl(m7, 63) : __shfl(m0, 4 * (c + 1));
    if (l == 0) {
        elog[b * 16 + c] = __builtin_amdgcn_logf(fmaxf(eex, 1e-35f)) + (float)ioffM;
        if (c >= 1)
            wlg[b * 16 + c] = __builtin_amdgcn_logf(fmaxf(wex, 1e-35f)) + (float)wio;
    }
}

// ---------------------------------------------------------------------------
// K6: backtrace. 2 shfls per 8 steps.
__global__ __launch_bounds__(256) void k_btr(const u64* __restrict__ mbg,
                                             int* __restrict__ js) {
    __shared__ u64 mb[128][64];
    const int b = blockIdx.x, tid = threadIdx.x;
    const uint4* src = (const uint4*)(mbg + (size_t)b * 8192);
    uint4* dst = (uint4*)&mb[0][0];
    for (int i = tid; i < 4096; i += 256) dst[i] = src[i];
    __syncthreads();
    if (tid >= 64) return;
    const int l = tid;
    int jj = S_ - 1;
    if (l == 0) js[b * T_ + T_ - 1] = jj;
    u64 wcur = mb[127][l];
    for (int tau = 127; tau >= 0; --tau) {
        u64 wv = wcur;
        if (tau > 0) wcur = mb[tau - 1][l];
        const int hi = jj >> 3;
        u64 whi = __shfl(wv, hi);
        u64 wlo = __shfl(wv, (hi > 0) ? hi - 1 : 0);
        for (int i = 7; i >= 0; --i) {
            int t = tau * 8 + i;
            if (t == 0) break;
            u64 word = ((jj >> 3) == hi) ? whi : wlo;
            int bit = (int)((word >> ((t & 7) * 8 + (jj & 7))) & 1ULL);
            jj -= bit;
            if (l == 0) js[b * T_ + t - 1] = jj;
        }
    }
}

// ---------------------------------------------------------------------------
// K7: fused one-hot path writer (blocks 0..4095) + logprobs (blocks 4096..4127).
__global__ __launch_bounds__(256) void k_out(const int* __restrict__ js,
                                             const u16* __restrict__ P,
                                             const float* __restrict__ lp_part,
                                             const int* __restrict__ tlen,
                                             const float* __restrict__ elog,
                                             const float* __restrict__ wlg,
                                             float* __restrict__ outp,
                                             float* __restrict__ out_lp) {
    if (blockIdx.x < 4096) {
        const size_t total4 = (size_t)B_ * T_ * S_ / 4;
        float4* O = (float4*)outp;
        for (size_t i = (size_t)blockIdx.x * 256 + threadIdx.x; i < total4;
             i += (size_t)4096 * 256) {
            size_t base = i * 4;
            int s = (int)(base & (S_ - 1));
            int row = (int)(base >> 9);
            int jt = js[row];
            float4 o;
            o.x = (s == jt) ? 1.f : 0.f;
            o.y = (s + 1 == jt) ? 1.f : 0.f;
            o.z = (s + 2 == jt) ? 1.f : 0.f;
            o.w = (s + 3 == jt) ? 1.f : 0.f;
            O[i] = o;
        }
    } else {
        const int b = blockIdx.x - 4096;
        float acc = 0.f;
        for (int t = threadIdx.x; t < T_; t += 256) {
            int jt = js[b * T_ + t];
            unsigned u = P[((size_t)b * T_ + t) * S_ + jt];
            acc += __builtin_amdgcn_logf(__uint_as_float(u << 16));
        }
        __shared__ float red[256];
        red[threadIdx.x] = acc;
        __syncthreads();
        for (int o = 128; o > 0; o >>= 1) {
            if (threadIdx.x < o) red[threadIdx.x] += red[threadIdx.x + o];
            __syncthreads();
        }
        if (threadIdx.x == 0) {
            float basep = 0.f;
            for (int i = 0; i < 48; ++i) basep += lp_part[b * 48 + i];
            float mu2n = elog[b * 16 + 15];
            for (int cc = 1; cc < 16; ++cc)
                mu2n += elog[b * 16 + cc - 1] - wlg[b * 16 + cc];
            out_lp[b] = basep - HALF_LOG_2PI * ((float)tlen[b] * C_)
                        + LN2F * (red[0] - mu2n);
        }
    }
}

// ---------------------------------------------------------------------------
extern "C" void kernel_launch(void* const* d_in, const int* in_sizes, int n_in,
                              void* d_out, int out_size, void* d_ws, size_t ws_size,
                              hipStream_t stream) {
    const float* eps  = (const float*)d_in[0];
    const float* cond = (const float*)d_in[1];
    const int* tlen   = (const int*)d_in[2];

    float* out_path = (float*)d_out;
    float* out_lp   = out_path + (size_t)B_ * T_ * S_;

    const size_t NBTS = (size_t)B_ * T_ * S_;
    char* w = (char*)d_ws;
    u16*   Wb   = (u16*)w;                            // 34 MB bf16 logits
    u16*   P    = Wb + NBTS;                          // 34 MB bf16 exp(W)/4
    u16*   Bt   = P + NBTS;                           // 34 MB bf16 linear beta
    u16*   Abf  = Bt + NBTS;                          // 25 MB bf16 eps
    u16*   Bbf  = Abf + (size_t)B_ * T_ * C_;         // 13 MB bf16 cond
    u64*   mbg  = (u64*)(Bbf + (size_t)B_ * S_ * C_); // 2 MB move bits
    float* pmax = (float*)(mbg + (size_t)B_ * 8192);
    float* psum = pmax + (size_t)4 * B_ * S_;
    float* cmax = psum + (size_t)4 * B_ * S_;
    float* cinv = cmax + (size_t)B_ * S_;
    float* lp_part = cinv + (size_t)B_ * S_;
    float* elog = lp_part + B_ * 48;                  // B*16
    float* wlg  = elog + B_ * 16;                     // B*16
    int*   js   = (int*)(wlg + B_ * 16);

    k_pre<<<2048, 256, 0, stream>>>(eps, cond, tlen, lp_part, Abf, Bbf);
    k_gemm<<<dim3(S_ / 128, T_ / 128, B_), 256, 0, stream>>>(Abf, Bbf, Wb);
    k_stats1<<<B_ * 2 * 4, 256, 0, stream>>>(Wb, pmax, psum);
    k_stats2<<<B_ * S_ / 256, 256, 0, stream>>>(pmax, psum, cmax, cinv);
    k_pack<<<2048, 256, 0, stream>>>(Wb, cmax, cinv, P);
    k_beta<<<B_ * 16, 64, 0, stream>>>(P, Bt);
    k_vit<<<B_ * 16, 64, 0, stream>>>(P, Bt, mbg, elog, wlg);
    k_btr<<<B_, 256, 0, stream>>>(mbg, js);
    k_out<<<4096 + B_, 256, 0, stream>>>(js, P, lp_part, tlen, elog, wlg,
                                         out_path, out_lp);
}

// Round 10
// 194.871 us; speedup vs baseline: 8.8513x; 1.0859x over previous
//
#include <hip/hip_runtime.h>
#include <cstdint>
#include <cstddef>

#define B_ 32
#define T_ 1024
#define S_ 512
#define C_ 384
#define HALF_LOG_2PI 0.91893853320467274178f
#define LN2F 0.69314718055994530942f
#define INV_LN2F 1.44269504088896340736f

typedef unsigned short u16;
typedef unsigned long long u64;
typedef __attribute__((ext_vector_type(8))) short bf16x8;
typedef __attribute__((ext_vector_type(4))) float f32x4;

__device__ __forceinline__ unsigned rne16(float f) {   // f32 -> bf16 bits (RNE)
    unsigned b = __float_as_uint(f);
    return (b + 0x7FFFu + ((b >> 16) & 1u)) >> 16;
}
__device__ __forceinline__ uint4 pack8f(float a0, float a1, float a2, float a3,
                                        float a4, float a5, float a6, float a7) {
    uint4 q;
    q.x = rne16(a0) | (rne16(a1) << 16);
    q.y = rne16(a2) | (rne16(a3) << 16);
    q.z = rne16(a4) | (rne16(a5) << 16);
    q.w = rne16(a6) | (rne16(a7) << 16);
    return q;
}
#define UNPK(q, p)                                                              \
    float p##0 = __uint_as_float((q).x << 16),                                  \
          p##1 = __uint_as_float((q).x & 0xFFFF0000u),                          \
          p##2 = __uint_as_float((q).y << 16),                                  \
          p##3 = __uint_as_float((q).y & 0xFFFF0000u),                          \
          p##4 = __uint_as_float((q).z << 16),                                  \
          p##5 = __uint_as_float((q).z & 0xFFFF0000u),                          \
          p##6 = __uint_as_float((q).w << 16),                                  \
          p##7 = __uint_as_float((q).w & 0xFFFF0000u)

#define PROW(t) (*(const uint4*)(Pb  + (size_t)(t) * S_ + l8))
#define BROW(t) (*(const uint4*)(Btb + (size_t)(t) * S_ + l8))

// ---------------------------------------------------------------------------
// DPP helpers: VALU-only cross-lane.
template <int CTRL>
__device__ __forceinline__ float fdpp0(float x) {     // invalid src lanes -> 0
    return __uint_as_float((unsigned)__builtin_amdgcn_update_dpp(
        0, (int)__float_as_uint(x), CTRL, 0xF, 0xF, true));
}
__device__ __forceinline__ float wave_fmax(float x) { // uniform full-wave max
    x = fmaxf(x, fdpp0<0x121>(x));   // row_ror:1
    x = fmaxf(x, fdpp0<0x122>(x));   // row_ror:2
    x = fmaxf(x, fdpp0<0x124>(x));   // row_ror:4
    x = fmaxf(x, fdpp0<0x128>(x));   // row_ror:8
    float a = __uint_as_float((unsigned)__builtin_amdgcn_readlane((int)__float_as_uint(x), 0));
    float b = __uint_as_float((unsigned)__builtin_amdgcn_readlane((int)__float_as_uint(x), 16));
    float c = __uint_as_float((unsigned)__builtin_amdgcn_readlane((int)__float_as_uint(x), 32));
    float d = __uint_as_float((unsigned)__builtin_amdgcn_readlane((int)__float_as_uint(x), 48));
    return fmaxf(fmaxf(a, b), fmaxf(c, d));
}

__device__ __forceinline__ void gll16(const u16* g, u16* l) {
    __builtin_amdgcn_global_load_lds(
        (const __attribute__((address_space(1))) void*)g,
        (__attribute__((address_space(3))) void*)l, 16, 0, 0);
}
#define WAITV(N) do { asm volatile("s_waitcnt vmcnt(" #N ")" ::: "memory");     \
                      __builtin_amdgcn_sched_barrier(0); } while (0)
#define FENCE_LGKM() do { asm volatile("s_waitcnt lgkmcnt(0)" ::: "memory");    \
                          __builtin_amdgcn_sched_barrier(0); } while (0)

// ---------------------------------------------------------------------------
// K0: fused eps->bf16 + eps^2 partials (blocks 0..1535) and cond->bf16 (rest).
__global__ __launch_bounds__(256) void k_pre(const float* __restrict__ eps,
                                             const float* __restrict__ cond,
                                             const int* __restrict__ tlen,
                                             float* __restrict__ lp_part,
                                             u16* __restrict__ Abf,
                                             u16* __restrict__ Bbf) {
    if (blockIdx.x < 1536) {
        const int b = blockIdx.x / 48, chunk = blockIdx.x % 48;
        const int len = tlen[b];
        const float* base = eps + (size_t)b * T_ * C_ + (size_t)chunk * 8192;
        u16* obase = Abf + (size_t)b * T_ * C_ + (size_t)chunk * 8192;
        float acc = 0.f;
        for (int g = threadIdx.x; g < 1024; g += 256) {
            float4 v0 = *(const float4*)(base + g * 8);
            float4 v1 = *(const float4*)(base + g * 8 + 4);
            int t = (chunk * 8192 + g * 8) / C_;
            if (t < len)
                acc += v0.x*v0.x + v0.y*v0.y + v0.z*v0.z + v0.w*v0.w
                     + v1.x*v1.x + v1.y*v1.y + v1.z*v1.z + v1.w*v1.w;
            *(uint4*)(obase + g * 8) = pack8f(v0.x, v0.y, v0.z, v0.w,
                                              v1.x, v1.y, v1.z, v1.w);
        }
        __shared__ float red[256];
        red[threadIdx.x] = acc;
        __syncthreads();
        for (int o = 128; o > 0; o >>= 1) {
            if (threadIdx.x < o) red[threadIdx.x] += red[threadIdx.x + o];
            __syncthreads();
        }
        if (threadIdx.x == 0) lp_part[blockIdx.x] = -0.5f * red[0];
    } else {
        const size_t n8 = (size_t)B_ * S_ * C_ / 8;
        for (size_t i = (size_t)(blockIdx.x - 1536) * 256 + threadIdx.x; i < n8;
             i += (size_t)512 * 256) {
            float4 v0 = *(const float4*)(cond + i * 8);
            float4 v1 = *(const float4*)(cond + i * 8 + 4);
            *(uint4*)(Bbf + i * 8) = pack8f(v0.x, v0.y, v0.z, v0.w,
                                            v1.x, v1.y, v1.z, v1.w);
        }
    }
}

// ---------------------------------------------------------------------------
// K1: bf16 MFMA GEMM -> bf16 logits Wb. 128x128 tile, 4 waves, BK=32.
__global__ __launch_bounds__(256) void k_gemm(const u16* __restrict__ A,
                                              const u16* __restrict__ Bc,
                                              u16* __restrict__ Wb) {
    __shared__ u16 Al[4096];
    __shared__ u16 Bl[4096];
    const int b  = blockIdx.z;
    const int m0 = blockIdx.y * 128;
    const int n0 = blockIdx.x * 128;
    const int tid = threadIdx.x;
    const int lane = tid & 63, wid = tid >> 6;
    const int wy = wid >> 1, wx = wid & 1;
    const int r15 = lane & 15, kg = lane >> 4;
    const u16* Ab = A  + (size_t)b * T_ * C_;
    const u16* Bb = Bc + (size_t)b * S_ * C_;

    f32x4 acc[4][4];
#pragma unroll
    for (int i = 0; i < 4; ++i)
#pragma unroll
        for (int j = 0; j < 4; ++j) acc[i][j] = (f32x4){0.f, 0.f, 0.f, 0.f};

    const int g1 = tid + 256;
    const int row0 = tid >> 2, o0 = tid & 3;
    const int row1 = g1 >> 2,  o1 = g1 & 3;
    const int wb0 = (row0 * 64 + o0 * 16) ^ (((row0 >> 1) & 7) << 4);
    const int wb1 = (row1 * 64 + o1 * 16) ^ (((row1 >> 1) & 7) << 4);
    const int rswz = ((r15 >> 1) & 7) << 4;

    for (int k0 = 0; k0 < C_; k0 += 32) {
        uint4 a0 = *(const uint4*)(Ab + (size_t)(m0 + row0) * C_ + k0 + o0 * 8);
        uint4 a1 = *(const uint4*)(Ab + (size_t)(m0 + row1) * C_ + k0 + o1 * 8);
        uint4 c0 = *(const uint4*)(Bb + (size_t)(n0 + row0) * C_ + k0 + o0 * 8);
        uint4 c1 = *(const uint4*)(Bb + (size_t)(n0 + row1) * C_ + k0 + o1 * 8);
        __syncthreads();
        *(uint4*)((char*)Al + wb0) = a0;
        *(uint4*)((char*)Al + wb1) = a1;
        *(uint4*)((char*)Bl + wb0) = c0;
        *(uint4*)((char*)Bl + wb1) = c1;
        __syncthreads();
        bf16x8 af[4], bfb[4];
#pragma unroll
        for (int ar = 0; ar < 4; ++ar) {
            int row = wy * 64 + ar * 16 + r15;
            af[ar] = *(const bf16x8*)((const char*)Al + ((row * 64 + kg * 16) ^ rswz));
        }
#pragma unroll
        for (int bc = 0; bc < 4; ++bc) {
            int row = wx * 64 + bc * 16 + r15;
            bfb[bc] = *(const bf16x8*)((const char*)Bl + ((row * 64 + kg * 16) ^ rswz));
        }
#pragma unroll
        for (int ar = 0; ar < 4; ++ar)
#pragma unroll
            for (int bc = 0; bc < 4; ++bc)
                acc[ar][bc] = __builtin_amdgcn_mfma_f32_16x16x32_bf16(
                    af[ar], bfb[bc], acc[ar][bc], 0, 0, 0);
    }
#pragma unroll
    for (int ar = 0; ar < 4; ++ar) {
        int t = m0 + wy * 64 + ar * 16 + kg * 4;
#pragma unroll
        for (int bc = 0; bc < 4; ++bc) {
            int s = n0 + wx * 64 + bc * 16 + r15;
            u16* dst = Wb + ((size_t)b * T_ + t) * S_ + s;
#pragma unroll
            for (int r = 0; r < 4; ++r) dst[(size_t)r * S_] = (u16)rne16(acc[ar][bc][r]);
        }
    }
}

// ---------------------------------------------------------------------------
// K2a: column stats over 256-row chunk. 4 waves, 8 cols/lane, uint4 row loads.
#define COLU(i, xa, xb, xc, xd) do {                                            \
    float nm = fmaxf(fmaxf(fmaxf(m[i], xa), xb), fmaxf(xc, xd));                \
    s[i] = s[i] * __builtin_amdgcn_exp2f((m[i] - nm) * INV_LN2F)                \
         + __builtin_amdgcn_exp2f((xa - nm) * INV_LN2F)                         \
         + __builtin_amdgcn_exp2f((xb - nm) * INV_LN2F)                         \
         + __builtin_amdgcn_exp2f((xc - nm) * INV_LN2F)                         \
         + __builtin_amdgcn_exp2f((xd - nm) * INV_LN2F);                        \
    m[i] = nm;                                                                  \
} while (0)

__global__ __launch_bounds__(256) void k_stats1(const u16* __restrict__ Wb,
                                                float* __restrict__ pmax,
                                                float* __restrict__ psum) {
    __shared__ float smax[4][S_];
    __shared__ float ssum[4][S_];
    const int c = blockIdx.x & 3;
    const int b = blockIdx.x >> 2;
    const int w = threadIdx.x >> 6, l = threadIdx.x & 63;
    const u16* base = Wb + (size_t)b * T_ * S_ + (size_t)(c * 256 + w * 64) * S_ + l * 8;
    float m[8], s[8];
#pragma unroll
    for (int i = 0; i < 8; ++i) { m[i] = -3.0e38f; s[i] = 0.f; }
    for (int t = 0; t < 64; t += 4) {
        uint4 q0 = *(const uint4*)(base + (size_t)(t + 0) * S_);
        uint4 q1 = *(const uint4*)(base + (size_t)(t + 1) * S_);
        uint4 q2 = *(const uint4*)(base + (size_t)(t + 2) * S_);
        uint4 q3 = *(const uint4*)(base + (size_t)(t + 3) * S_);
        UNPK(q0, xa); UNPK(q1, xb); UNPK(q2, xc); UNPK(q3, xd);
        COLU(0, xa0, xb0, xc0, xd0);
        COLU(1, xa1, xb1, xc1, xd1);
        COLU(2, xa2, xb2, xc2, xd2);
        COLU(3, xa3, xb3, xc3, xd3);
        COLU(4, xa4, xb4, xc4, xd4);
        COLU(5, xa5, xb5, xc5, xd5);
        COLU(6, xa6, xb6, xc6, xd6);
        COLU(7, xa7, xb7, xc7, xd7);
    }
#pragma unroll
    for (int i = 0; i < 8; ++i) {
        smax[w][l * 8 + i] = m[i];
        ssum[w][l * 8 + i] = s[i];
    }
    __syncthreads();
    for (int col = threadIdx.x; col < S_; col += 256) {
        float m0 = smax[0][col], m1 = smax[1][col];
        float m2 = smax[2][col], m3 = smax[3][col];
        float nm = fmaxf(fmaxf(m0, m1), fmaxf(m2, m3));
        float ss = ssum[0][col] * __builtin_amdgcn_exp2f((m0 - nm) * INV_LN2F)
                 + ssum[1][col] * __builtin_amdgcn_exp2f((m1 - nm) * INV_LN2F)
                 + ssum[2][col] * __builtin_amdgcn_exp2f((m2 - nm) * INV_LN2F)
                 + ssum[3][col] * __builtin_amdgcn_exp2f((m3 - nm) * INV_LN2F);
        pmax[(size_t)c * B_ * S_ + b * S_ + col] = nm;
        psum[(size_t)c * B_ * S_ + b * S_ + col] = ss;
    }
}

__global__ __launch_bounds__(256) void k_stats2(const float* __restrict__ pmax,
                                                const float* __restrict__ psum,
                                                float* __restrict__ cmax,
                                                float* __restrict__ cinv) {
    const int i = blockIdx.x * 256 + threadIdx.x;
    float m0 = pmax[i], m1 = pmax[(size_t)B_ * S_ + i];
    float m2 = pmax[(size_t)2 * B_ * S_ + i], m3 = pmax[(size_t)3 * B_ * S_ + i];
    float m = fmaxf(fmaxf(m0, m1), fmaxf(m2, m3));
    float s = psum[i] * expf(m0 - m)
            + psum[(size_t)B_ * S_ + i] * expf(m1 - m)
            + psum[(size_t)2 * B_ * S_ + i] * expf(m2 - m)
            + psum[(size_t)3 * B_ * S_ + i] * expf(m3 - m);
    cmax[i] = m;
    cinv[i] = 1.0f / s;
}

// ---------------------------------------------------------------------------
// K3: P_hat = exp(softmax(Wb,axis=T)) / 4, bf16.
__global__ __launch_bounds__(256) void k_pack(const u16* __restrict__ Wb,
                                              const float* __restrict__ cmax,
                                              const float* __restrict__ cinv,
                                              u16* __restrict__ P) {
    const size_t total8 = (size_t)B_ * T_ * S_ / 8;
    for (size_t i = (size_t)blockIdx.x * 256 + threadIdx.x; i < total8;
         i += (size_t)gridDim.x * 256) {
        size_t base = i * 8;
        int s = (int)(base & (S_ - 1));
        int b = (int)(base >> 19);
        uint4 xq = *(const uint4*)(Wb + base);
        UNPK(xq, x);
        float4 mA = *(const float4*)(cmax + (size_t)b * S_ + s);
        float4 mB = *(const float4*)(cmax + (size_t)b * S_ + s + 4);
        float4 iA = *(const float4*)(cinv + (size_t)b * S_ + s);
        float4 iB = *(const float4*)(cinv + (size_t)b * S_ + s + 4);
        float w0 = __builtin_amdgcn_exp2f(fmaf(x0, INV_LN2F, -mA.x * INV_LN2F)) * iA.x;
        float w1 = __builtin_amdgcn_exp2f(fmaf(x1, INV_LN2F, -mA.y * INV_LN2F)) * iA.y;
        float w2 = __builtin_amdgcn_exp2f(fmaf(x2, INV_LN2F, -mA.z * INV_LN2F)) * iA.z;
        float w3 = __builtin_amdgcn_exp2f(fmaf(x3, INV_LN2F, -mA.w * INV_LN2F)) * iA.w;
        float w4 = __builtin_amdgcn_exp2f(fmaf(x4, INV_LN2F, -mB.x * INV_LN2F)) * iB.x;
        float w5 = __builtin_amdgcn_exp2f(fmaf(x5, INV_LN2F, -mB.y * INV_LN2F)) * iB.y;
        float w6 = __builtin_amdgcn_exp2f(fmaf(x6, INV_LN2F, -mB.z * INV_LN2F)) * iB.z;
        float w7 = __builtin_amdgcn_exp2f(fmaf(x7, INV_LN2F, -mB.w * INV_LN2F)) * iB.w;
        float p0 = __builtin_amdgcn_exp2f(fmaf(w0, INV_LN2F, -2.0f));
        float p1 = __builtin_amdgcn_exp2f(fmaf(w1, INV_LN2F, -2.0f));
        float p2 = __builtin_amdgcn_exp2f(fmaf(w2, INV_LN2F, -2.0f));
        float p3 = __builtin_amdgcn_exp2f(fmaf(w3, INV_LN2F, -2.0f));
        float p4 = __builtin_amdgcn_exp2f(fmaf(w4, INV_LN2F, -2.0f));
        float p5 = __builtin_amdgcn_exp2f(fmaf(w5, INV_LN2F, -2.0f));
        float p6 = __builtin_amdgcn_exp2f(fmaf(w6, INV_LN2F, -2.0f));
        float p7 = __builtin_amdgcn_exp2f(fmaf(w7, INV_LN2F, -2.0f));
        *(uint4*)(P + base) = pack8f(p0, p1, p2, p3, p4, p5, p6, p7);
    }
}

// ---------------------------------------------------------------------------
// K4: backward DP, linear domain. 32 chunks of 32 + 64-step warm-up, GROUP=8
// LDS double-buffered staging, vmcnt pipeline, DPP shift, XCD co-location.
#define RENORM_B() do {                                                         \
    float mx_ = wave_fmax(fmaxf(fmaxf(fmaxf(m0,m1),fmaxf(m2,m3)),               \
                                fmaxf(fmaxf(m4,m5),fmaxf(m6,m7))));             \
    int eb_ = (__float_as_int(mx_) >> 23) & 255;                                \
    float sc_ = (eb_ > 0) ? __int_as_float((254 - eb_) << 23) : 1.0f;           \
    m0*=sc_; m1*=sc_; m2*=sc_; m3*=sc_; m4*=sc_; m5*=sc_; m6*=sc_; m7*=sc_;     \
} while (0)

#define BSTEPD(tt, jj) do {                                                     \
    uint4 q_ = *(const uint4*)&Pl[buf][jj][l8];                                 \
    UNPK(q_, eP);                                                               \
    float z0=m0*eP0, z1=m1*eP1, z2=m2*eP2, z3=m3*eP3;                           \
    float z4=m4*eP4, z5=m5*eP5, z6=m6*eP6, z7=m7*eP7;                           \
    float rt = fdpp0<0x130>(z0);  /* lane l <- l+1, lane63 -> 0 */              \
    m0=z0+z1; m1=z1+z2; m2=z2+z3; m3=z3+z4;                                     \
    m4=z4+z5; m5=z5+z6; m6=z6+z7; m7=z7+rt;                                     \
    if ((tt) < w0 + 32) {                                                       \
        uint4 st;                                                               \
        asm("v_cvt_pk_bf16_f32 %0, %1, %2" : "=v"(st.x) : "v"(m0), "v"(m1));    \
        asm("v_cvt_pk_bf16_f32 %0, %1, %2" : "=v"(st.y) : "v"(m2), "v"(m3));    \
        asm("v_cvt_pk_bf16_f32 %0, %1, %2" : "=v"(st.z) : "v"(m4), "v"(m5));    \
        asm("v_cvt_pk_bf16_f32 %0, %1, %2" : "=v"(st.w) : "v"(m6), "v"(m7));    \
        *(uint4*)(Bb + (size_t)(tt) * S_ + l8) = st;                            \
    }                                                                           \
} while (0)

__global__ __launch_bounds__(64) void k_beta(const u16* __restrict__ P,
                                             u16* __restrict__ Bt) {
    __shared__ u16 Pl[2][8][S_];        // 16 KB
    const int l = threadIdx.x, l8 = l * 8;
    const int xcd = blockIdx.x & 7;
    const int idx = blockIdx.x >> 3;
    const int c = idx & 31;
    const int b = ((idx >> 5) << 3) + xcd;   // all chunks of b on one XCD
    const int w0 = c * 32;
    const u16* Pb = P  + (size_t)b * T_ * S_;
    u16*      Bb = Bt + (size_t)b * T_ * S_;
    float m0, m1, m2, m3, m4, m5, m6, m7;
    int te = w0 + 95;
    if (te > 1023) te = 1023;
    if (te == 1023) {    // exact init (c >= 29)
        m0 = m1 = m2 = m3 = m4 = m5 = m6 = 0.f;
        m7 = (l == 63) ? 1.f : 0.f;
        if (1023 < w0 + 32) {   // c == 31 stores init row
            uint4 st;
            asm("v_cvt_pk_bf16_f32 %0, %1, %2" : "=v"(st.x) : "v"(m0), "v"(m1));
            asm("v_cvt_pk_bf16_f32 %0, %1, %2" : "=v"(st.y) : "v"(m2), "v"(m3));
            asm("v_cvt_pk_bf16_f32 %0, %1, %2" : "=v"(st.z) : "v"(m4), "v"(m5));
            asm("v_cvt_pk_bf16_f32 %0, %1, %2" : "=v"(st.w) : "v"(m6), "v"(m7));
            *(uint4*)(Bb + (size_t)1023 * S_ + l8) = st;
        }
    } else {
        m0 = m1 = m2 = m3 = m4 = m5 = m6 = m7 = 1.f;
    }
    const int cnt = te - w0;            // 95/63/31, == 7 mod 8
    const int ng = (cnt + 1) >> 3;      // 12/8/4
#pragma unroll
    for (int r = 0; r < 8; ++r)
        gll16(Pb + (size_t)(te - r) * S_ + l8, &Pl[0][r][0]);
#pragma unroll
    for (int r = 0; r < 8; ++r)
        gll16(Pb + (size_t)(te - 8 - r) * S_ + l8, &Pl[1][r][0]);
    int tt = te - 1;
    int buf = 0;
    for (int g = 0; g < ng - 1; ++g) {
        WAITV(8);
        BSTEPD(tt - 0, 0);  BSTEPD(tt - 1, 1);  BSTEPD(tt - 2, 2);  BSTEPD(tt - 3, 3);
        BSTEPD(tt - 4, 4);  BSTEPD(tt - 5, 5);  BSTEPD(tt - 6, 6);  BSTEPD(tt - 7, 7);
        RENORM_B();
        FENCE_LGKM();
        if (g + 2 < ng) {
            const int bs = te - 8 * (g + 2);
#pragma unroll
            for (int r = 0; r < 8; ++r)
                gll16(Pb + (size_t)(bs - r) * S_ + l8, &Pl[buf][r][0]);
        }
        __builtin_amdgcn_sched_barrier(0);
        buf ^= 1;
        tt -= 8;
    }
    WAITV(0);
    BSTEPD(tt - 0, 0);  BSTEPD(tt - 1, 1);  BSTEPD(tt - 2, 2);  BSTEPD(tt - 3, 3);
    BSTEPD(tt - 4, 4);  BSTEPD(tt - 5, 5);  BSTEPD(tt - 6, 6);
}

// ---------------------------------------------------------------------------
// K5: fused mu-forward + Viterbi, linear domain, 32 chunks of 32, 64 warm-up.
#define RENORM_MI() do {                                                        \
    float mx_ = wave_fmax(fmaxf(fmaxf(fmaxf(m0,m1),fmaxf(m2,m3)),               \
                                fmaxf(fmaxf(m4,m5),fmaxf(m6,m7))));             \
    int eb_ = (__float_as_int(mx_) >> 23) & 255;                                \
    float sc_ = (eb_ > 0) ? __int_as_float((254 - eb_) << 23) : 1.0f;           \
    if (eb_ > 0) ioffM += eb_ - 127;                                            \
    m0*=sc_; m1*=sc_; m2*=sc_; m3*=sc_; m4*=sc_; m5*=sc_; m6*=sc_; m7*=sc_;     \
} while (0)

#define RENORM_VR() do {                                                        \
    float mx_ = wave_fmax(fmaxf(fmaxf(fmaxf(v0,v1),fmaxf(v2,v3)),               \
                                fmaxf(fmaxf(v4,v5),fmaxf(v6,v7))));             \
    int eb_ = (__float_as_int(mx_) >> 23) & 255;                                \
    float sc_ = (eb_ > 0) ? __int_as_float((254 - eb_) << 23) : 0.0f;           \
    float ad_ = (eb_ > 0) ? 0.f : 1.f;                                          \
    v0=fmaf(v0,sc_,ad_); v1=fmaf(v1,sc_,ad_); v2=fmaf(v2,sc_,ad_);              \
    v3=fmaf(v3,sc_,ad_); v4=fmaf(v4,sc_,ad_); v5=fmaf(v5,sc_,ad_);              \
    v6=fmaf(v6,sc_,ad_); v7=fmaf(v7,sc_,ad_);                                   \
} while (0)

#define VSTEPD(TT, jj) do {                                                     \
    uint4 qp_ = *(const uint4*)&Pl[buf][jj][l8];                                \
    uint4 qb_ = *(const uint4*)&Bl[buf][jj][l8];                                \
    UNPK(qp_, eP); UNPK(qb_, eB);                                               \
    float lf = fdpp0<0x138>(m7);  /* lane l <- l-1, lane0 -> 0 */               \
    float n0 = eP0*(m0+lf), n1 = eP1*(m1+m0);                                   \
    float n2 = eP2*(m2+m1), n3 = eP3*(m3+m2);                                   \
    float n4 = eP4*(m4+m3), n5 = eP5*(m5+m4);                                   \
    float n6 = eP6*(m6+m5), n7 = eP7*(m7+m6);                                   \
    float vlf = fdpp0<0x138>(v7);                                               \
    if ((TT) >= w0) {                                                           \
        unsigned cc0=(vlf>v0)?1u:0u, cc1=(v0>v1)?2u:0u, cc2=(v1>v2)?4u:0u,      \
                 cc3=(v2>v3)?8u:0u,  cc4=(v3>v4)?16u:0u, cc5=(v4>v5)?32u:0u,    \
                 cc6=(v5>v6)?64u:0u, cc7=(v6>v7)?128u:0u;                       \
        acc |= ((u64)(cc0|cc1|cc2|cc3|cc4|cc5|cc6|cc7)) << (((TT)&7)*8);        \
        if (((TT)&7) == 7) { mrow[((TT)>>3)*64 + l] = acc; acc = 0ULL; }        \
    }                                                                           \
    float w0v=(n0*eB0)*fmaxf(v0,vlf), w1v=(n1*eB1)*fmaxf(v1,v0);                \
    float w2v=(n2*eB2)*fmaxf(v2,v1),  w3v=(n3*eB3)*fmaxf(v3,v2);                \
    float w4v=(n4*eB4)*fmaxf(v4,v3),  w5v=(n5*eB5)*fmaxf(v5,v4);                \
    float w6v=(n6*eB6)*fmaxf(v6,v5),  w7v=(n7*eB7)*fmaxf(v7,v6);                \
    m0=n0;m1=n1;m2=n2;m3=n3;m4=n4;m5=n5;m6=n6;m7=n7;                            \
    v0=w0v;v1=w1v;v2=w2v;v3=w3v;v4=w4v;v5=w5v;v6=w6v;v7=w7v;                    \
    if ((TT) == wexp) { wex = __shfl(m0, 2 * c); wio = ioffM; }                 \
} while (0)

__global__ __launch_bounds__(64) void k_vit(const u16* __restrict__ P,
                                            const u16* __restrict__ Bt,
                                            u64* __restrict__ mbg,
                                            float* __restrict__ elog,
                                            float* __restrict__ wlg) {
    __shared__ u16 Pl[2][8][S_];        // 16 KB
    __shared__ u16 Bl[2][8][S_];        // 16 KB
    const int l = threadIdx.x, l8 = l * 8;
    const int xcd = blockIdx.x & 7;
    const int idx = blockIdx.x >> 3;
    const int c = idx & 31;
    const int b = ((idx >> 5) << 3) + xcd;
    const int w0 = c * 32, tend = w0 + 31;
    const int t0 = (w0 >= 64) ? (w0 - 64) : 0;
    const int wexp = w0 - 1;
    const u16* Pb  = P  + (size_t)b * T_ * S_;
    const u16* Btb = Bt + (size_t)b * T_ * S_;
    u64* mrow = mbg + (size_t)b * 8192;

    float m0,m1,m2,m3,m4,m5,m6,m7, v0,v1,v2,v3,v4,v5,v6,v7;
    int ioffM = 0;
    float wex = 1.f; int wio = 0;
    {
        uint4 qp = PROW(t0); UNPK(qp, eP);
        uint4 qb = BROW(t0); UNPK(qb, eB);
        if (t0 == 0) {   // exact init (c == 0, 1)
            m0 = (l == 0) ? eP0 : 0.f;
            m1 = 0.f; m2 = 0.f; m3 = 0.f; m4 = 0.f; m5 = 0.f; m6 = 0.f; m7 = 0.f;
        } else {
            m0 = eP0; m1 = eP1; m2 = eP2; m3 = eP3;
            m4 = eP4; m5 = eP5; m6 = eP6; m7 = eP7;
        }
        v0 = m0*eB0; v1 = m1*eB1; v2 = m2*eB2; v3 = m3*eB3;
        v4 = m4*eB4; v5 = m5*eB5; v6 = m6*eB6; v7 = m7*eB7;
    }
    u64 acc = 0ULL;
    const int cnt = tend - t0;          // 95/63/31
    const int ng = (cnt + 1) >> 3;      // 12/8/4
#pragma unroll
    for (int r = 0; r < 8; ++r) {
        gll16(Pb  + (size_t)(t0 + 1 + r) * S_ + l8, &Pl[0][r][0]);
        gll16(Btb + (size_t)(t0 + 1 + r) * S_ + l8, &Bl[0][r][0]);
    }
#pragma unroll
    for (int r = 0; r < 8; ++r) {
        gll16(Pb  + (size_t)(t0 + 9 + r) * S_ + l8, &Pl[1][r][0]);
        gll16(Btb + (size_t)(t0 + 9 + r) * S_ + l8, &Bl[1][r][0]);
    }
    int t = t0 + 1;
    int buf = 0;
    for (int g = 0; g < ng - 1; ++g) {
        WAITV(16);
        VSTEPD(t + 0, 0);  VSTEPD(t + 1, 1);  VSTEPD(t + 2, 2);  VSTEPD(t + 3, 3);
        VSTEPD(t + 4, 4);  VSTEPD(t + 5, 5);  VSTEPD(t + 6, 6);  VSTEPD(t + 7, 7);
        RENORM_MI();
        RENORM_VR();
        FENCE_LGKM();
        if (g + 2 < ng) {
            const int bs = t0 + 1 + 8 * (g + 2);
#pragma unroll
            for (int r = 0; r < 8; ++r) {
                gll16(Pb  + (size_t)(bs + r) * S_ + l8, &Pl[buf][r][0]);
                gll16(Btb + (size_t)(bs + r) * S_ + l8, &Bl[buf][r][0]);
            }
        }
        __builtin_amdgcn_sched_barrier(0);
        buf ^= 1;
        t += 8;
    }
    WAITV(0);
    VSTEPD(t + 0, 0);  VSTEPD(t + 1, 1);  VSTEPD(t + 2, 2);  VSTEPD(t + 3, 3);
    VSTEPD(t + 4, 4);  VSTEPD(t + 5, 5);  VSTEPD(t + 6, 6);

    float eex = (c == 31) ? __shfl(m7, 63) : __shfl(m0, 2 * (c + 1));
    if (l == 0) {
        elog[b * 32 + c] = __builtin_amdgcn_logf(fmaxf(eex, 1e-35f)) + (float)ioffM;
        if (c >= 1)
            wlg[b * 32 + c] = __builtin_amdgcn_logf(fmaxf(wex, 1e-35f)) + (float)wio;
    }
}

// ---------------------------------------------------------------------------
// K6: backtrace. 2 shfls per 8 steps.
__global__ __launch_bounds__(256) void k_btr(const u64* __restrict__ mbg,
                                             int* __restrict__ js) {
    __shared__ u64 mb[128][64];
    const int b = blockIdx.x, tid = threadIdx.x;
    const uint4* src = (const uint4*)(mbg + (size_t)b * 8192);
    uint4* dst = (uint4*)&mb[0][0];
    for (int i = tid; i < 4096; i += 256) dst[i] = src[i];
    __syncthreads();
    if (tid >= 64) return;
    const int l = tid;
    int jj = S_ - 1;
    if (l == 0) js[b * T_ + T_ - 1] = jj;
    u64 wcur = mb[127][l];
    for (int tau = 127; tau >= 0; --tau) {
        u64 wv = wcur;
        if (tau > 0) wcur = mb[tau - 1][l];
        const int hi = jj >> 3;
        u64 whi = __shfl(wv, hi);
        u64 wlo = __shfl(wv, (hi > 0) ? hi - 1 : 0);
        for (int i = 7; i >= 0; --i) {
            int t = tau * 8 + i;
            if (t == 0) break;
            u64 word = ((jj >> 3) == hi) ? whi : wlo;
            int bit = (int)((word >> ((t & 7) * 8 + (jj & 7))) & 1ULL);
            jj -= bit;
            if (l == 0) js[b * T_ + t - 1] = jj;
        }
    }
}

// ---------------------------------------------------------------------------
// K7: fused one-hot path writer (blocks 0..4095) + logprobs (blocks 4096..4127).
__global__ __launch_bounds__(256) void k_out(const int* __restrict__ js,
                                             const u16* __restrict__ P,
                                             const float* __restrict__ lp_part,
                                             const int* __restrict__ tlen,
                                             const float* __restrict__ elog,
                                             const float* __restrict__ wlg,
                                             float* __restrict__ outp,
                                             float* __restrict__ out_lp) {
    if (blockIdx.x < 4096) {
        const size_t total4 = (size_t)B_ * T_ * S_ / 4;
        float4* O = (float4*)outp;
        for (size_t i = (size_t)blockIdx.x * 256 + threadIdx.x; i < total4;
             i += (size_t)4096 * 256) {
            size_t base = i * 4;
            int s = (int)(base & (S_ - 1));
            int row = (int)(base >> 9);
            int jt = js[row];
            float4 o;
            o.x = (s == jt) ? 1.f : 0.f;
            o.y = (s + 1 == jt) ? 1.f : 0.f;
            o.z = (s + 2 == jt) ? 1.f : 0.f;
            o.w = (s + 3 == jt) ? 1.f : 0.f;
            O[i] = o;
        }
    } else {
        const int b = blockIdx.x - 4096;
        float acc = 0.f;
        for (int t = threadIdx.x; t < T_; t += 256) {
            int jt = js[b * T_ + t];
            unsigned u = P[((size_t)b * T_ + t) * S_ + jt];
            acc += __builtin_amdgcn_logf(__uint_as_float(u << 16));
        }
        __shared__ float red[256];
        red[threadIdx.x] = acc;
        __syncthreads();
        for (int o = 128; o > 0; o >>= 1) {
            if (threadIdx.x < o) red[threadIdx.x] += red[threadIdx.x + o];
            __syncthreads();
        }
        if (threadIdx.x == 0) {
            float basep = 0.f;
            for (int i = 0; i < 48; ++i) basep += lp_part[b * 48 + i];
            float mu2n = elog[b * 32 + 31];
            for (int cc = 1; cc < 32; ++cc)
                mu2n += elog[b * 32 + cc - 1] - wlg[b * 32 + cc];
            out_lp[b] = basep - HALF_LOG_2PI * ((float)tlen[b] * C_)
                        + LN2F * (red[0] - mu2n);
        }
    }
}

// ---------------------------------------------------------------------------
extern "C" void kernel_launch(void* const* d_in, const int* in_sizes, int n_in,
                              void* d_out, int out_size, void* d_ws, size_t ws_size,
                              hipStream_t stream) {
    const float* eps  = (const float*)d_in[0];
    const float* cond = (const float*)d_in[1];
    const int* tlen   = (const int*)d_in[2];

    float* out_path = (float*)d_out;
    float* out_lp   = out_path + (size_t)B_ * T_ * S_;

    const size_t NBTS = (size_t)B_ * T_ * S_;
    char* w = (char*)d_ws;
    u16*   Wb   = (u16*)w;                            // 34 MB bf16 logits
    u16*   P    = Wb + NBTS;                          // 34 MB bf16 exp(W)/4
    u16*   Bt   = P + NBTS;                           // 34 MB bf16 linear beta
    u16*   Abf  = Bt + NBTS;                          // 25 MB bf16 eps
    u16*   Bbf  = Abf + (size_t)B_ * T_ * C_;         // 13 MB bf16 cond
    u64*   mbg  = (u64*)(Bbf + (size_t)B_ * S_ * C_); // 2 MB move bits
    float* pmax = (float*)(mbg + (size_t)B_ * 8192);
    float* psum = pmax + (size_t)4 * B_ * S_;
    float* cmax = psum + (size_t)4 * B_ * S_;
    float* cinv = cmax + (size_t)B_ * S_;
    float* lp_part = cinv + (size_t)B_ * S_;
    float* elog = lp_part + B_ * 48;                  // B*32
    float* wlg  = elog + B_ * 32;                     // B*32
    int*   js   = (int*)(wlg + B_ * 32);

    k_pre<<<2048, 256, 0, stream>>>(eps, cond, tlen, lp_part, Abf, Bbf);
    k_gemm<<<dim3(S_ / 128, T_ / 128, B_), 256, 0, stream>>>(Abf, Bbf, Wb);
    k_stats1<<<B_ * 4, 256, 0, stream>>>(Wb, pmax, psum);
    k_stats2<<<B_ * S_ / 256, 256, 0, stream>>>(pmax, psum, cmax, cinv);
    k_pack<<<2048, 256, 0, stream>>>(Wb, cmax, cinv, P);
    k_beta<<<B_ * 32, 64, 0, stream>>>(P, Bt);
    k_vit<<<B_ * 32, 64, 0, stream>>>(P, Bt, mbg, elog, wlg);
    k_btr<<<B_, 256, 0, stream>>>(mbg, js);
    k_out<<<4096 + B_, 256, 0, stream>>>(js, P, lp_part, tlen, elog, wlg,
                                         out_path, out_lp);
}

// Round 11
// 158.933 us; speedup vs baseline: 10.8528x; 1.2261x over previous
//
#include <hip/hip_runtime.h>
#include <cstdint>
#include <cstddef>

#define B_ 32
#define T_ 1024
#define S_ 512
#define C_ 384
#define HALF_LOG_2PI 0.91893853320467274178f
#define LN2F 0.69314718055994530942f
#define INV_LN2F 1.44269504088896340736f

typedef unsigned short u16;
typedef unsigned long long u64;
typedef __attribute__((ext_vector_type(8))) short bf16x8;
typedef __attribute__((ext_vector_type(4))) float f32x4;

__device__ __forceinline__ unsigned rne16(float f) {   // f32 -> bf16 bits (RNE)
    unsigned b = __float_as_uint(f);
    return (b + 0x7FFFu + ((b >> 16) & 1u)) >> 16;
}
__device__ __forceinline__ uint4 pack8f(float a0, float a1, float a2, float a3,
                                        float a4, float a5, float a6, float a7) {
    uint4 q;
    q.x = rne16(a0) | (rne16(a1) << 16);
    q.y = rne16(a2) | (rne16(a3) << 16);
    q.z = rne16(a4) | (rne16(a5) << 16);
    q.w = rne16(a6) | (rne16(a7) << 16);
    return q;
}
#define UNPK(q, p)                                                              \
    float p##0 = __uint_as_float((q).x << 16),                                  \
          p##1 = __uint_as_float((q).x & 0xFFFF0000u),                          \
          p##2 = __uint_as_float((q).y << 16),                                  \
          p##3 = __uint_as_float((q).y & 0xFFFF0000u),                          \
          p##4 = __uint_as_float((q).z << 16),                                  \
          p##5 = __uint_as_float((q).z & 0xFFFF0000u),                          \
          p##6 = __uint_as_float((q).w << 16),                                  \
          p##7 = __uint_as_float((q).w & 0xFFFF0000u)

#define PROW(t) (*(const uint4*)(Pb  + (size_t)(t) * S_ + l8))
#define BROW(t) (*(const uint4*)(Btb + (size_t)(t) * S_ + l8))

// ---------------------------------------------------------------------------
// DPP helpers: VALU-only cross-lane.
template <int CTRL>
__device__ __forceinline__ float fdpp0(float x) {     // invalid src lanes -> 0
    return __uint_as_float((unsigned)__builtin_amdgcn_update_dpp(
        0, (int)__float_as_uint(x), CTRL, 0xF, 0xF, true));
}
__device__ __forceinline__ float wave_fmax(float x) { // uniform full-wave max
    x = fmaxf(x, fdpp0<0x121>(x));   // row_ror:1
    x = fmaxf(x, fdpp0<0x122>(x));   // row_ror:2
    x = fmaxf(x, fdpp0<0x124>(x));   // row_ror:4
    x = fmaxf(x, fdpp0<0x128>(x));   // row_ror:8
    float a = __uint_as_float((unsigned)__builtin_amdgcn_readlane((int)__float_as_uint(x), 0));
    float b = __uint_as_float((unsigned)__builtin_amdgcn_readlane((int)__float_as_uint(x), 16));
    float c = __uint_as_float((unsigned)__builtin_amdgcn_readlane((int)__float_as_uint(x), 32));
    float d = __uint_as_float((unsigned)__builtin_amdgcn_readlane((int)__float_as_uint(x), 48));
    return fmaxf(fmaxf(a, b), fmaxf(c, d));
}

__device__ __forceinline__ void gll16(const u16* g, u16* l) {
    __builtin_amdgcn_global_load_lds(
        (const __attribute__((address_space(1))) void*)g,
        (__attribute__((address_space(3))) void*)l, 16, 0, 0);
}
#define WAITV(N) do { asm volatile("s_waitcnt vmcnt(" #N ")" ::: "memory");     \
                      __builtin_amdgcn_sched_barrier(0); } while (0)
#define FENCE_LGKM() do { asm volatile("s_waitcnt lgkmcnt(0)" ::: "memory");    \
                          __builtin_amdgcn_sched_barrier(0); } while (0)

// ---------------------------------------------------------------------------
// K0: fused eps->bf16 + eps^2 partials (blocks 0..1535) and cond->bf16 (rest).
__global__ __launch_bounds__(256) void k_pre(const float* __restrict__ eps,
                                             const float* __restrict__ cond,
                                             const int* __restrict__ tlen,
                                             float* __restrict__ lp_part,
                                             u16* __restrict__ Abf,
                                             u16* __restrict__ Bbf) {
    if (blockIdx.x < 1536) {
        const int b = blockIdx.x / 48, chunk = blockIdx.x % 48;
        const int len = tlen[b];
        const float* base = eps + (size_t)b * T_ * C_ + (size_t)chunk * 8192;
        u16* obase = Abf + (size_t)b * T_ * C_ + (size_t)chunk * 8192;
        float acc = 0.f;
        for (int g = threadIdx.x; g < 1024; g += 256) {
            float4 v0 = *(const float4*)(base + g * 8);
            float4 v1 = *(const float4*)(base + g * 8 + 4);
            int t = (chunk * 8192 + g * 8) / C_;
            if (t < len)
                acc += v0.x*v0.x + v0.y*v0.y + v0.z*v0.z + v0.w*v0.w
                     + v1.x*v1.x + v1.y*v1.y + v1.z*v1.z + v1.w*v1.w;
            *(uint4*)(obase + g * 8) = pack8f(v0.x, v0.y, v0.z, v0.w,
                                              v1.x, v1.y, v1.z, v1.w);
        }
        __shared__ float red[256];
        red[threadIdx.x] = acc;
        __syncthreads();
        for (int o = 128; o > 0; o >>= 1) {
            if (threadIdx.x < o) red[threadIdx.x] += red[threadIdx.x + o];
            __syncthreads();
        }
        if (threadIdx.x == 0) lp_part[blockIdx.x] = -0.5f * red[0];
    } else {
        const size_t n8 = (size_t)B_ * S_ * C_ / 8;
        for (size_t i = (size_t)(blockIdx.x - 1536) * 256 + threadIdx.x; i < n8;
             i += (size_t)512 * 256) {
            float4 v0 = *(const float4*)(cond + i * 8);
            float4 v1 = *(const float4*)(cond + i * 8 + 4);
            *(uint4*)(Bbf + i * 8) = pack8f(v0.x, v0.y, v0.z, v0.w,
                                            v1.x, v1.y, v1.z, v1.w);
        }
    }
}

// ---------------------------------------------------------------------------
// K1: bf16 MFMA GEMM -> bf16 logits Wb. 128x128 tile, 4 waves, BK=32.
__global__ __launch_bounds__(256) void k_gemm(const u16* __restrict__ A,
                                              const u16* __restrict__ Bc,
                                              u16* __restrict__ Wb) {
    __shared__ u16 Al[4096];
    __shared__ u16 Bl[4096];
    const int b  = blockIdx.z;
    const int m0 = blockIdx.y * 128;
    const int n0 = blockIdx.x * 128;
    const int tid = threadIdx.x;
    const int lane = tid & 63, wid = tid >> 6;
    const int wy = wid >> 1, wx = wid & 1;
    const int r15 = lane & 15, kg = lane >> 4;
    const u16* Ab = A  + (size_t)b * T_ * C_;
    const u16* Bb = Bc + (size_t)b * S_ * C_;

    f32x4 acc[4][4];
#pragma unroll
    for (int i = 0; i < 4; ++i)
#pragma unroll
        for (int j = 0; j < 4; ++j) acc[i][j] = (f32x4){0.f, 0.f, 0.f, 0.f};

    const int g1 = tid + 256;
    const int row0 = tid >> 2, o0 = tid & 3;
    const int row1 = g1 >> 2,  o1 = g1 & 3;
    const int wb0 = (row0 * 64 + o0 * 16) ^ (((row0 >> 1) & 7) << 4);
    const int wb1 = (row1 * 64 + o1 * 16) ^ (((row1 >> 1) & 7) << 4);
    const int rswz = ((r15 >> 1) & 7) << 4;

    for (int k0 = 0; k0 < C_; k0 += 32) {
        uint4 a0 = *(const uint4*)(Ab + (size_t)(m0 + row0) * C_ + k0 + o0 * 8);
        uint4 a1 = *(const uint4*)(Ab + (size_t)(m0 + row1) * C_ + k0 + o1 * 8);
        uint4 c0 = *(const uint4*)(Bb + (size_t)(n0 + row0) * C_ + k0 + o0 * 8);
        uint4 c1 = *(const uint4*)(Bb + (size_t)(n0 + row1) * C_ + k0 + o1 * 8);
        __syncthreads();
        *(uint4*)((char*)Al + wb0) = a0;
        *(uint4*)((char*)Al + wb1) = a1;
        *(uint4*)((char*)Bl + wb0) = c0;
        *(uint4*)((char*)Bl + wb1) = c1;
        __syncthreads();
        bf16x8 af[4], bfb[4];
#pragma unroll
        for (int ar = 0; ar < 4; ++ar) {
            int row = wy * 64 + ar * 16 + r15;
            af[ar] = *(const bf16x8*)((const char*)Al + ((row * 64 + kg * 16) ^ rswz));
        }
#pragma unroll
        for (int bc = 0; bc < 4; ++bc) {
            int row = wx * 64 + bc * 16 + r15;
            bfb[bc] = *(const bf16x8*)((const char*)Bl + ((row * 64 + kg * 16) ^ rswz));
        }
#pragma unroll
        for (int ar = 0; ar < 4; ++ar)
#pragma unroll
            for (int bc = 0; bc < 4; ++bc)
                acc[ar][bc] = __builtin_amdgcn_mfma_f32_16x16x32_bf16(
                    af[ar], bfb[bc], acc[ar][bc], 0, 0, 0);
    }
#pragma unroll
    for (int ar = 0; ar < 4; ++ar) {
        int t = m0 + wy * 64 + ar * 16 + kg * 4;
#pragma unroll
        for (int bc = 0; bc < 4; ++bc) {
            int s = n0 + wx * 64 + bc * 16 + r15;
            u16* dst = Wb + ((size_t)b * T_ + t) * S_ + s;
#pragma unroll
            for (int r = 0; r < 4; ++r) dst[(size_t)r * S_] = (u16)rne16(acc[ar][bc][r]);
        }
    }
}

// ---------------------------------------------------------------------------
// K2a: column stats over 256-row chunk. 4 waves, 8 cols/lane, uint4 row loads.
#define COLU(i, xa, xb, xc, xd) do {                                            \
    float nm = fmaxf(fmaxf(fmaxf(m[i], xa), xb), fmaxf(xc, xd));                \
    s[i] = s[i] * __builtin_amdgcn_exp2f((m[i] - nm) * INV_LN2F)                \
         + __builtin_amdgcn_exp2f((xa - nm) * INV_LN2F)                         \
         + __builtin_amdgcn_exp2f((xb - nm) * INV_LN2F)                         \
         + __builtin_amdgcn_exp2f((xc - nm) * INV_LN2F)                         \
         + __builtin_amdgcn_exp2f((xd - nm) * INV_LN2F);                        \
    m[i] = nm;                                                                  \
} while (0)

__global__ __launch_bounds__(256) void k_stats1(const u16* __restrict__ Wb,
                                                float* __restrict__ pmax,
                                                float* __restrict__ psum) {
    __shared__ float smax[4][S_];
    __shared__ float ssum[4][S_];
    const int c = blockIdx.x & 3;
    const int b = blockIdx.x >> 2;
    const int w = threadIdx.x >> 6, l = threadIdx.x & 63;
    const u16* base = Wb + (size_t)b * T_ * S_ + (size_t)(c * 256 + w * 64) * S_ + l * 8;
    float m[8], s[8];
#pragma unroll
    for (int i = 0; i < 8; ++i) { m[i] = -3.0e38f; s[i] = 0.f; }
    for (int t = 0; t < 64; t += 4) {
        uint4 q0 = *(const uint4*)(base + (size_t)(t + 0) * S_);
        uint4 q1 = *(const uint4*)(base + (size_t)(t + 1) * S_);
        uint4 q2 = *(const uint4*)(base + (size_t)(t + 2) * S_);
        uint4 q3 = *(const uint4*)(base + (size_t)(t + 3) * S_);
        UNPK(q0, xa); UNPK(q1, xb); UNPK(q2, xc); UNPK(q3, xd);
        COLU(0, xa0, xb0, xc0, xd0);
        COLU(1, xa1, xb1, xc1, xd1);
        COLU(2, xa2, xb2, xc2, xd2);
        COLU(3, xa3, xb3, xc3, xd3);
        COLU(4, xa4, xb4, xc4, xd4);
        COLU(5, xa5, xb5, xc5, xd5);
        COLU(6, xa6, xb6, xc6, xd6);
        COLU(7, xa7, xb7, xc7, xd7);
    }
#pragma unroll
    for (int i = 0; i < 8; ++i) {
        smax[w][l * 8 + i] = m[i];
        ssum[w][l * 8 + i] = s[i];
    }
    __syncthreads();
    for (int col = threadIdx.x; col < S_; col += 256) {
        float m0 = smax[0][col], m1 = smax[1][col];
        float m2 = smax[2][col], m3 = smax[3][col];
        float nm = fmaxf(fmaxf(m0, m1), fmaxf(m2, m3));
        float ss = ssum[0][col] * __builtin_amdgcn_exp2f((m0 - nm) * INV_LN2F)
                 + ssum[1][col] * __builtin_amdgcn_exp2f((m1 - nm) * INV_LN2F)
                 + ssum[2][col] * __builtin_amdgcn_exp2f((m2 - nm) * INV_LN2F)
                 + ssum[3][col] * __builtin_amdgcn_exp2f((m3 - nm) * INV_LN2F);
        pmax[(size_t)c * B_ * S_ + b * S_ + col] = nm;
        psum[(size_t)c * B_ * S_ + b * S_ + col] = ss;
    }
}

__global__ __launch_bounds__(256) void k_stats2(const float* __restrict__ pmax,
                                                const float* __restrict__ psum,
                                                float* __restrict__ cmax,
                                                float* __restrict__ cinv) {
    const int i = blockIdx.x * 256 + threadIdx.x;
    float m0 = pmax[i], m1 = pmax[(size_t)B_ * S_ + i];
    float m2 = pmax[(size_t)2 * B_ * S_ + i], m3 = pmax[(size_t)3 * B_ * S_ + i];
    float m = fmaxf(fmaxf(m0, m1), fmaxf(m2, m3));
    float s = psum[i] * expf(m0 - m)
            + psum[(size_t)B_ * S_ + i] * expf(m1 - m)
            + psum[(size_t)2 * B_ * S_ + i] * expf(m2 - m)
            + psum[(size_t)3 * B_ * S_ + i] * expf(m3 - m);
    cmax[i] = m;
    cinv[i] = 1.0f / s;
}

// ---------------------------------------------------------------------------
// K3: P_hat = exp(softmax(Wb,axis=T)) / 4, bf16.
__global__ __launch_bounds__(256) void k_pack(const u16* __restrict__ Wb,
                                              const float* __restrict__ cmax,
                                              const float* __restrict__ cinv,
                                              u16* __restrict__ P) {
    const size_t total8 = (size_t)B_ * T_ * S_ / 8;
    for (size_t i = (size_t)blockIdx.x * 256 + threadIdx.x; i < total8;
         i += (size_t)gridDim.x * 256) {
        size_t base = i * 8;
        int s = (int)(base & (S_ - 1));
        int b = (int)(base >> 19);
        uint4 xq = *(const uint4*)(Wb + base);
        UNPK(xq, x);
        float4 mA = *(const float4*)(cmax + (size_t)b * S_ + s);
        float4 mB = *(const float4*)(cmax + (size_t)b * S_ + s + 4);
        float4 iA = *(const float4*)(cinv + (size_t)b * S_ + s);
        float4 iB = *(const float4*)(cinv + (size_t)b * S_ + s + 4);
        float w0 = __builtin_amdgcn_exp2f(fmaf(x0, INV_LN2F, -mA.x * INV_LN2F)) * iA.x;
        float w1 = __builtin_amdgcn_exp2f(fmaf(x1, INV_LN2F, -mA.y * INV_LN2F)) * iA.y;
        float w2 = __builtin_amdgcn_exp2f(fmaf(x2, INV_LN2F, -mA.z * INV_LN2F)) * iA.z;
        float w3 = __builtin_amdgcn_exp2f(fmaf(x3, INV_LN2F, -mA.w * INV_LN2F)) * iA.w;
        float w4 = __builtin_amdgcn_exp2f(fmaf(x4, INV_LN2F, -mB.x * INV_LN2F)) * iB.x;
        float w5 = __builtin_amdgcn_exp2f(fmaf(x5, INV_LN2F, -mB.y * INV_LN2F)) * iB.y;
        float w6 = __builtin_amdgcn_exp2f(fmaf(x6, INV_LN2F, -mB.z * INV_LN2F)) * iB.z;
        float w7 = __builtin_amdgcn_exp2f(fmaf(x7, INV_LN2F, -mB.w * INV_LN2F)) * iB.w;
        float p0 = __builtin_amdgcn_exp2f(fmaf(w0, INV_LN2F, -2.0f));
        float p1 = __builtin_amdgcn_exp2f(fmaf(w1, INV_LN2F, -2.0f));
        float p2 = __builtin_amdgcn_exp2f(fmaf(w2, INV_LN2F, -2.0f));
        float p3 = __builtin_amdgcn_exp2f(fmaf(w3, INV_LN2F, -2.0f));
        float p4 = __builtin_amdgcn_exp2f(fmaf(w4, INV_LN2F, -2.0f));
        float p5 = __builtin_amdgcn_exp2f(fmaf(w5, INV_LN2F, -2.0f));
        float p6 = __builtin_amdgcn_exp2f(fmaf(w6, INV_LN2F, -2.0f));
        float p7 = __builtin_amdgcn_exp2f(fmaf(w7, INV_LN2F, -2.0f));
        *(uint4*)(P + base) = pack8f(p0, p1, p2, p3, p4, p5, p6, p7);
    }
}

// ---------------------------------------------------------------------------
// K4: backward DP, linear domain. 32 chunks of 32 + 32-step warm-up, GROUP=8
// LDS double-buffered staging, vmcnt pipeline, DPP shift, XCD co-location.
#define RENORM_B() do {                                                         \
    float mx_ = wave_fmax(fmaxf(fmaxf(fmaxf(m0,m1),fmaxf(m2,m3)),               \
                                fmaxf(fmaxf(m4,m5),fmaxf(m6,m7))));             \
    int eb_ = (__float_as_int(mx_) >> 23) & 255;                                \
    float sc_ = (eb_ > 0) ? __int_as_float((254 - eb_) << 23) : 1.0f;           \
    m0*=sc_; m1*=sc_; m2*=sc_; m3*=sc_; m4*=sc_; m5*=sc_; m6*=sc_; m7*=sc_;     \
} while (0)

#define BSTEPD(tt, jj) do {                                                     \
    uint4 q_ = *(const uint4*)&Pl[buf][jj][l8];                                 \
    UNPK(q_, eP);                                                               \
    float z0=m0*eP0, z1=m1*eP1, z2=m2*eP2, z3=m3*eP3;                           \
    float z4=m4*eP4, z5=m5*eP5, z6=m6*eP6, z7=m7*eP7;                           \
    float rt = fdpp0<0x130>(z0);  /* lane l <- l+1, lane63 -> 0 */              \
    m0=z0+z1; m1=z1+z2; m2=z2+z3; m3=z3+z4;                                     \
    m4=z4+z5; m5=z5+z6; m6=z6+z7; m7=z7+rt;                                     \
    if ((tt) < w0 + 32) {                                                       \
        uint4 st;                                                               \
        asm("v_cvt_pk_bf16_f32 %0, %1, %2" : "=v"(st.x) : "v"(m0), "v"(m1));    \
        asm("v_cvt_pk_bf16_f32 %0, %1, %2" : "=v"(st.y) : "v"(m2), "v"(m3));    \
        asm("v_cvt_pk_bf16_f32 %0, %1, %2" : "=v"(st.z) : "v"(m4), "v"(m5));    \
        asm("v_cvt_pk_bf16_f32 %0, %1, %2" : "=v"(st.w) : "v"(m6), "v"(m7));    \
        *(uint4*)(Bb + (size_t)(tt) * S_ + l8) = st;                            \
    }                                                                           \
} while (0)

__global__ __launch_bounds__(64) void k_beta(const u16* __restrict__ P,
                                             u16* __restrict__ Bt) {
    __shared__ u16 Pl[2][8][S_];        // 16 KB
    const int l = threadIdx.x, l8 = l * 8;
    const int xcd = blockIdx.x & 7;
    const int idx = blockIdx.x >> 3;
    const int c = idx & 31;
    const int b = ((idx >> 5) << 3) + xcd;   // all chunks of b on one XCD
    const int w0 = c * 32;
    const u16* Pb = P  + (size_t)b * T_ * S_;
    u16*      Bb = Bt + (size_t)b * T_ * S_;
    float m0, m1, m2, m3, m4, m5, m6, m7;
    int te = w0 + 63;
    if (te > 1023) te = 1023;
    if (te == 1023) {    // exact init (c == 30, 31)
        m0 = m1 = m2 = m3 = m4 = m5 = m6 = 0.f;
        m7 = (l == 63) ? 1.f : 0.f;
        if (1023 < w0 + 32) {   // c == 31 stores init row
            uint4 st;
            asm("v_cvt_pk_bf16_f32 %0, %1, %2" : "=v"(st.x) : "v"(m0), "v"(m1));
            asm("v_cvt_pk_bf16_f32 %0, %1, %2" : "=v"(st.y) : "v"(m2), "v"(m3));
            asm("v_cvt_pk_bf16_f32 %0, %1, %2" : "=v"(st.z) : "v"(m4), "v"(m5));
            asm("v_cvt_pk_bf16_f32 %0, %1, %2" : "=v"(st.w) : "v"(m6), "v"(m7));
            *(uint4*)(Bb + (size_t)1023 * S_ + l8) = st;
        }
    } else {
        m0 = m1 = m2 = m3 = m4 = m5 = m6 = m7 = 1.f;
    }
    const int cnt = te - w0;            // 63/31, == 7 mod 8
    const int ng = (cnt + 1) >> 3;      // 8/4
#pragma unroll
    for (int r = 0; r < 8; ++r)
        gll16(Pb + (size_t)(te - r) * S_ + l8, &Pl[0][r][0]);
#pragma unroll
    for (int r = 0; r < 8; ++r)
        gll16(Pb + (size_t)(te - 8 - r) * S_ + l8, &Pl[1][r][0]);
    int tt = te - 1;
    int buf = 0;
    for (int g = 0; g < ng - 1; ++g) {
        WAITV(8);
        BSTEPD(tt - 0, 0);  BSTEPD(tt - 1, 1);  BSTEPD(tt - 2, 2);  BSTEPD(tt - 3, 3);
        BSTEPD(tt - 4, 4);  BSTEPD(tt - 5, 5);  BSTEPD(tt - 6, 6);  BSTEPD(tt - 7, 7);
        RENORM_B();
        FENCE_LGKM();
        if (g + 2 < ng) {
            const int bs = te - 8 * (g + 2);
#pragma unroll
            for (int r = 0; r < 8; ++r)
                gll16(Pb + (size_t)(bs - r) * S_ + l8, &Pl[buf][r][0]);
        }
        __builtin_amdgcn_sched_barrier(0);
        buf ^= 1;
        tt -= 8;
    }
    WAITV(0);
    BSTEPD(tt - 0, 0);  BSTEPD(tt - 1, 1);  BSTEPD(tt - 2, 2);  BSTEPD(tt - 3, 3);
    BSTEPD(tt - 4, 4);  BSTEPD(tt - 5, 5);  BSTEPD(tt - 6, 6);
}

// ---------------------------------------------------------------------------
// K5: fused mu-forward + Viterbi, linear domain, 32 chunks of 32, 32 warm-up.
#define RENORM_MI() do {                                                        \
    float mx_ = wave_fmax(fmaxf(fmaxf(fmaxf(m0,m1),fmaxf(m2,m3)),               \
                                fmaxf(fmaxf(m4,m5),fmaxf(m6,m7))));             \
    int eb_ = (__float_as_int(mx_) >> 23) & 255;                                \
    float sc_ = (eb_ > 0) ? __int_as_float((254 - eb_) << 23) : 1.0f;           \
    if (eb_ > 0) ioffM += eb_ - 127;                                            \
    m0*=sc_; m1*=sc_; m2*=sc_; m3*=sc_; m4*=sc_; m5*=sc_; m6*=sc_; m7*=sc_;     \
} while (0)

#define RENORM_VR() do {                                                        \
    float mx_ = wave_fmax(fmaxf(fmaxf(fmaxf(v0,v1),fmaxf(v2,v3)),               \
                                fmaxf(fmaxf(v4,v5),fmaxf(v6,v7))));             \
    int eb_ = (__float_as_int(mx_) >> 23) & 255;                                \
    float sc_ = (eb_ > 0) ? __int_as_float((254 - eb_) << 23) : 0.0f;           \
    float ad_ = (eb_ > 0) ? 0.f : 1.f;                                          \
    v0=fmaf(v0,sc_,ad_); v1=fmaf(v1,sc_,ad_); v2=fmaf(v2,sc_,ad_);              \
    v3=fmaf(v3,sc_,ad_); v4=fmaf(v4,sc_,ad_); v5=fmaf(v5,sc_,ad_);              \
    v6=fmaf(v6,sc_,ad_); v7=fmaf(v7,sc_,ad_);                                   \
} while (0)

#define VSTEPD(TT, jj) do {                                                     \
    uint4 qp_ = *(const uint4*)&Pl[buf][jj][l8];                                \
    uint4 qb_ = *(const uint4*)&Bl[buf][jj][l8];                                \
    UNPK(qp_, eP); UNPK(qb_, eB);                                               \
    float lf = fdpp0<0x138>(m7);  /* lane l <- l-1, lane0 -> 0 */               \
    float n0 = eP0*(m0+lf), n1 = eP1*(m1+m0);                                   \
    float n2 = eP2*(m2+m1), n3 = eP3*(m3+m2);                                   \
    float n4 = eP4*(m4+m3), n5 = eP5*(m5+m4);                                   \
    float n6 = eP6*(m6+m5), n7 = eP7*(m7+m6);                                   \
    float vlf = fdpp0<0x138>(v7);                                               \
    if ((TT) >= w0) {                                                           \
        unsigned cc0=(vlf>v0)?1u:0u, cc1=(v0>v1)?2u:0u, cc2=(v1>v2)?4u:0u,      \
                 cc3=(v2>v3)?8u:0u,  cc4=(v3>v4)?16u:0u, cc5=(v4>v5)?32u:0u,    \
                 cc6=(v5>v6)?64u:0u, cc7=(v6>v7)?128u:0u;                       \
        acc |= ((u64)(cc0|cc1|cc2|cc3|cc4|cc5|cc6|cc7)) << (((TT)&7)*8);        \
        if (((TT)&7) == 7) { mrow[((TT)>>3)*64 + l] = acc; acc = 0ULL; }        \
    }                                                                           \
    float w0v=(n0*eB0)*fmaxf(v0,vlf), w1v=(n1*eB1)*fmaxf(v1,v0);                \
    float w2v=(n2*eB2)*fmaxf(v2,v1),  w3v=(n3*eB3)*fmaxf(v3,v2);                \
    float w4v=(n4*eB4)*fmaxf(v4,v3),  w5v=(n5*eB5)*fmaxf(v5,v4);                \
    float w6v=(n6*eB6)*fmaxf(v6,v5),  w7v=(n7*eB7)*fmaxf(v7,v6);                \
    m0=n0;m1=n1;m2=n2;m3=n3;m4=n4;m5=n5;m6=n6;m7=n7;                            \
    v0=w0v;v1=w1v;v2=w2v;v3=w3v;v4=w4v;v5=w5v;v6=w6v;v7=w7v;                    \
    if ((TT) == wexp) { wex = __shfl(m0, 2 * c); wio = ioffM; }                 \
} while (0)

__global__ __launch_bounds__(64) void k_vit(const u16* __restrict__ P,
                                            const u16* __restrict__ Bt,
                                            u64* __restrict__ mbg,
                                            float* __restrict__ elog,
                                            float* __restrict__ wlg) {
    __shared__ u16 Pl[2][8][S_];        // 16 KB
    __shared__ u16 Bl[2][8][S_];        // 16 KB
    const int l = threadIdx.x, l8 = l * 8;
    const int xcd = blockIdx.x & 7;
    const int idx = blockIdx.x >> 3;
    const int c = idx & 31;
    const int b = ((idx >> 5) << 3) + xcd;
    const int w0 = c * 32, tend = w0 + 31;
    const int t0 = (w0 >= 32) ? (w0 - 32) : 0;
    const int wexp = w0 - 1;
    const u16* Pb  = P  + (size_t)b * T_ * S_;
    const u16* Btb = Bt + (size_t)b * T_ * S_;
    u64* mrow = mbg + (size_t)b * 8192;

    float m0,m1,m2,m3,m4,m5,m6,m7, v0,v1,v2,v3,v4,v5,v6,v7;
    int ioffM = 0;
    float wex = 1.f; int wio = 0;
    {
        uint4 qp = PROW(t0); UNPK(qp, eP);
        uint4 qb = BROW(t0); UNPK(qb, eB);
        if (t0 == 0) {   // exact init (c == 0, 1)
            m0 = (l == 0) ? eP0 : 0.f;
            m1 = 0.f; m2 = 0.f; m3 = 0.f; m4 = 0.f; m5 = 0.f; m6 = 0.f; m7 = 0.f;
        } else {
            m0 = eP0; m1 = eP1; m2 = eP2; m3 = eP3;
            m4 = eP4; m5 = eP5; m6 = eP6; m7 = eP7;
        }
        v0 = m0*eB0; v1 = m1*eB1; v2 = m2*eB2; v3 = m3*eB3;
        v4 = m4*eB4; v5 = m5*eB5; v6 = m6*eB6; v7 = m7*eB7;
    }
    u64 acc = 0ULL;
    const int cnt = tend - t0;          // 63/31
    const int ng = (cnt + 1) >> 3;      // 8/4
#pragma unroll
    for (int r = 0; r < 8; ++r) {
        gll16(Pb  + (size_t)(t0 + 1 + r) * S_ + l8, &Pl[0][r][0]);
        gll16(Btb + (size_t)(t0 + 1 + r) * S_ + l8, &Bl[0][r][0]);
    }
#pragma unroll
    for (int r = 0; r < 8; ++r) {
        gll16(Pb  + (size_t)(t0 + 9 + r) * S_ + l8, &Pl[1][r][0]);
        gll16(Btb + (size_t)(t0 + 9 + r) * S_ + l8, &Bl[1][r][0]);
    }
    int t = t0 + 1;
    int buf = 0;
    for (int g = 0; g < ng - 1; ++g) {
        WAITV(16);
        VSTEPD(t + 0, 0);  VSTEPD(t + 1, 1);  VSTEPD(t + 2, 2);  VSTEPD(t + 3, 3);
        VSTEPD(t + 4, 4);  VSTEPD(t + 5, 5);  VSTEPD(t + 6, 6);  VSTEPD(t + 7, 7);
        RENORM_MI();
        RENORM_VR();
        FENCE_LGKM();
        if (g + 2 < ng) {
            const int bs = t0 + 1 + 8 * (g + 2);
#pragma unroll
            for (int r = 0; r < 8; ++r) {
                gll16(Pb  + (size_t)(bs + r) * S_ + l8, &Pl[buf][r][0]);
                gll16(Btb + (size_t)(bs + r) * S_ + l8, &Bl[buf][r][0]);
            }
        }
        __builtin_amdgcn_sched_barrier(0);
        buf ^= 1;
        t += 8;
    }
    WAITV(0);
    VSTEPD(t + 0, 0);  VSTEPD(t + 1, 1);  VSTEPD(t + 2, 2);  VSTEPD(t + 3, 3);
    VSTEPD(t + 4, 4);  VSTEPD(t + 5, 5);  VSTEPD(t + 6, 6);

    float eex = (c == 31) ? __shfl(m7, 63) : __shfl(m0, 2 * (c + 1));
    if (l == 0) {
        elog[b * 32 + c] = __builtin_amdgcn_logf(fmaxf(eex, 1e-35f)) + (float)ioffM;
        if (c >= 1)
            wlg[b * 32 + c] = __builtin_amdgcn_logf(fmaxf(wex, 1e-35f)) + (float)wio;
    }
}

// ---------------------------------------------------------------------------
// K6a: per-(b,chunk) backtrace maps. Thread j traces its column through the
// chunk's 32 transitions (t = 32c+31 .. 32c), giving column at t = 32c-1.
__global__ __launch_bounds__(512) void k_map(const u64* __restrict__ mbg,
                                             u16* __restrict__ map) {
    __shared__ u64 mb[4][64];   // 2 KB: taus 4c..4c+3
    const int b = blockIdx.x >> 5, c = blockIdx.x & 31;
    const int tid = threadIdx.x;
    const u64* src = mbg + (size_t)b * 8192 + (size_t)(4 * c) * 64;
    if (tid < 128) ((uint4*)&mb[0][0])[tid] = ((const uint4*)src)[tid];
    __syncthreads();
    int jj = tid;
    const int kmin = (c == 0) ? 1 : 0;
    for (int k = 31; k >= kmin; --k) {
        u64 word = mb[k >> 3][jj >> 3];
        jj -= (int)((word >> ((k & 7) * 8 + (jj & 7))) & 1ULL);
    }
    map[((size_t)b * 32 + c) * 512 + tid] = (u16)jj;
}

// K6b: compose maps (lane 0, 31 serial lookups) then 32 lanes re-trace their
// chunks in parallel from LDS-resident move bits, writing js.
__global__ __launch_bounds__(256) void k_btr2(const u64* __restrict__ mbg,
                                              const u16* __restrict__ map,
                                              int* __restrict__ js) {
    __shared__ u64 mb[128][64];   // 64 KB
    __shared__ u16 cent[32];
    const int b = blockIdx.x, tid = threadIdx.x;
    const uint4* src = (const uint4*)(mbg + (size_t)b * 8192);
    uint4* dst = (uint4*)&mb[0][0];
    for (int i = tid; i < 4096; i += 256) dst[i] = src[i];
    if (tid == 0) {
        int jj = 511;
        cent[31] = 511;
        for (int c = 31; c >= 1; --c) {
            jj = (int)map[((size_t)b * 32 + c) * 512 + jj];
            cent[c - 1] = (u16)jj;
        }
    }
    __syncthreads();
    if (tid < 32) {
        const int c = tid;
        int jj = (int)cent[c];
        js[b * T_ + 32 * c + 31] = jj;
        const int kmin = (c == 0) ? 1 : 0;
        for (int k = 31; k >= kmin; --k) {
            const int t = 32 * c + k;
            u64 word = mb[t >> 3][jj >> 3];
            jj -= (int)((word >> ((t & 7) * 8 + (jj & 7))) & 1ULL);
            js[b * T_ + t - 1] = jj;
        }
    }
}

// ---------------------------------------------------------------------------
// K7: fused one-hot path writer (blocks 0..4095) + logprobs (blocks 4096..4127).
__global__ __launch_bounds__(256) void k_out(const int* __restrict__ js,
                                             const u16* __restrict__ P,
                                             const float* __restrict__ lp_part,
                                             const int* __restrict__ tlen,
                                             const float* __restrict__ elog,
                                             const float* __restrict__ wlg,
                                             float* __restrict__ outp,
                                             float* __restrict__ out_lp) {
    if (blockIdx.x < 4096) {
        const size_t total4 = (size_t)B_ * T_ * S_ / 4;
        float4* O = (float4*)outp;
        for (size_t i = (size_t)blockIdx.x * 256 + threadIdx.x; i < total4;
             i += (size_t)4096 * 256) {
            size_t base = i * 4;
            int s = (int)(base & (S_ - 1));
            int row = (int)(base >> 9);
            int jt = js[row];
            float4 o;
            o.x = (s == jt) ? 1.f : 0.f;
            o.y = (s + 1 == jt) ? 1.f : 0.f;
            o.z = (s + 2 == jt) ? 1.f : 0.f;
            o.w = (s + 3 == jt) ? 1.f : 0.f;
            O[i] = o;
        }
    } else {
        const int b = blockIdx.x - 4096;
        float acc = 0.f;
        for (int t = threadIdx.x; t < T_; t += 256) {
            int jt = js[b * T_ + t];
            unsigned u = P[((size_t)b * T_ + t) * S_ + jt];
            acc += __builtin_amdgcn_logf(__uint_as_float(u << 16));
        }
        __shared__ float red[256];
        red[threadIdx.x] = acc;
        __syncthreads();
        for (int o = 128; o > 0; o >>= 1) {
            if (threadIdx.x < o) red[threadIdx.x] += red[threadIdx.x + o];
            __syncthreads();
        }
        if (threadIdx.x == 0) {
            float basep = 0.f;
            for (int i = 0; i < 48; ++i) basep += lp_part[b * 48 + i];
            float mu2n = elog[b * 32 + 31];
            for (int cc = 1; cc < 32; ++cc)
                mu2n += elog[b * 32 + cc - 1] - wlg[b * 32 + cc];
            out_lp[b] = basep - HALF_LOG_2PI * ((float)tlen[b] * C_)
                        + LN2F * (red[0] - mu2n);
        }
    }
}

// ---------------------------------------------------------------------------
extern "C" void kernel_launch(void* const* d_in, const int* in_sizes, int n_in,
                              void* d_out, int out_size, void* d_ws, size_t ws_size,
                              hipStream_t stream) {
    const float* eps  = (const float*)d_in[0];
    const float* cond = (const float*)d_in[1];
    const int* tlen   = (const int*)d_in[2];

    float* out_path = (float*)d_out;
    float* out_lp   = out_path + (size_t)B_ * T_ * S_;

    const size_t NBTS = (size_t)B_ * T_ * S_;
    char* w = (char*)d_ws;
    u16*   Wb   = (u16*)w;                            // 34 MB bf16 logits
    u16*   P    = Wb + NBTS;                          // 34 MB bf16 exp(W)/4
    u16*   Bt   = P + NBTS;                           // 34 MB bf16 linear beta
    u16*   Abf  = Bt + NBTS;                          // 25 MB bf16 eps
    u16*   Bbf  = Abf + (size_t)B_ * T_ * C_;         // 13 MB bf16 cond
    u64*   mbg  = (u64*)(Bbf + (size_t)B_ * S_ * C_); // 2 MB move bits
    float* pmax = (float*)(mbg + (size_t)B_ * 8192);
    float* psum = pmax + (size_t)4 * B_ * S_;
    float* cmax = psum + (size_t)4 * B_ * S_;
    float* cinv = cmax + (size_t)B_ * S_;
    float* lp_part = cinv + (size_t)B_ * S_;
    float* elog = lp_part + B_ * 48;                  // B*32
    float* wlg  = elog + B_ * 32;                     // B*32
    int*   js   = (int*)(wlg + B_ * 32);              // B*T
    u16*   map  = (u16*)(js + B_ * T_);               // 1 MB backtrace maps

    k_pre<<<2048, 256, 0, stream>>>(eps, cond, tlen, lp_part, Abf, Bbf);
    k_gemm<<<dim3(S_ / 128, T_ / 128, B_), 256, 0, stream>>>(Abf, Bbf, Wb);
    k_stats1<<<B_ * 4, 256, 0, stream>>>(Wb, pmax, psum);
    k_stats2<<<B_ * S_ / 256, 256, 0, stream>>>(pmax, psum, cmax, cinv);
    k_pack<<<2048, 256, 0, stream>>>(Wb, cmax, cinv, P);
    k_beta<<<B_ * 32, 64, 0, stream>>>(P, Bt);
    k_vit<<<B_ * 32, 64, 0, stream>>>(P, Bt, mbg, elog, wlg);
    k_map<<<B_ * 32, 512, 0, stream>>>(mbg, map);
    k_btr2<<<B_, 256, 0, stream>>>(mbg, map, js);
    k_out<<<4096 + B_, 256, 0, stream>>>(js, P, lp_part, tlen, elog, wlg,
                                         out_path, out_lp);
}